// Round 1
// baseline (4522.747 us; speedup 1.0000x reference)
//
#include <hip/hip_runtime.h>
#include <hip/hip_bf16.h>
#include <math.h>

#define N_NODES 50000
#define N_EDGES 25000
#define NNZ     600000
#define D       128
#define H       256

// ---------------------------------------------------------------- degrees
__global__ void count_degrees(const int* __restrict__ v_idx,
                              const int* __restrict__ e_idx,
                              int* __restrict__ vcnt, int* __restrict__ ecnt) {
    int i = blockIdx.x * blockDim.x + threadIdx.x;
    if (i < NNZ) {
        atomicAdd(&vcnt[v_idx[i]], 1);
        atomicAdd(&ecnt[e_idx[i]], 1);
    }
}

__global__ void make_recip(const int* __restrict__ cnt, float* __restrict__ recip, int n) {
    int i = blockIdx.x * blockDim.x + threadIdx.x;
    if (i < n) {
        int c = cnt[i];
        recip[i] = 1.0f / (float)(c > 0 ? c : 1);
    }
}

// ---------------------------------------------------------------- GEMM
// C[M,N] = relu(A[M,K] @ W[N,K]^T + bias[N] (+ extra[M,N]*recipv[M]))
// Tile: 64x64, BK=32, 256 threads, 4x4 micro-tile per thread.
#define TM 64
#define TN 64
#define BK 32

__launch_bounds__(256)
__global__ void gemm_relu(const float* __restrict__ A,
                          const float* __restrict__ W,
                          const float* __restrict__ bias,
                          float* __restrict__ C,
                          int M, int N, int K,
                          const float* __restrict__ extra,
                          const float* __restrict__ recipv) {
    __shared__ float As[BK][TM];
    __shared__ float Bs[BK][TN];

    const int tid = threadIdx.x;
    const int tx  = tid & 15;   // 0..15  -> 4 cols each
    const int ty  = tid >> 4;   // 0..15  -> 4 rows each
    const int rowBase = blockIdx.x * TM;
    const int colBase = blockIdx.y * TN;

    float acc[4][4] = {};

    for (int k0 = 0; k0 < K; k0 += BK) {
        // A tile: 64 rows x 32 k = 512 float4s, 2 per thread
        #pragma unroll
        for (int r = 0; r < 2; ++r) {
            int idx = tid + r * 256;      // 0..511
            int row = idx >> 3;           // 0..63
            int kk  = (idx & 7) << 2;     // 0,4,...,28
            float4 av = make_float4(0.f, 0.f, 0.f, 0.f);
            int grow = rowBase + row;
            if (grow < M)
                av = *(const float4*)(A + (size_t)grow * K + k0 + kk);
            As[kk + 0][row] = av.x;
            As[kk + 1][row] = av.y;
            As[kk + 2][row] = av.z;
            As[kk + 3][row] = av.w;
        }
        // B tile: 64 cols x 32 k (N is a multiple of 64 -> no guard)
        #pragma unroll
        for (int r = 0; r < 2; ++r) {
            int idx = tid + r * 256;
            int col = idx >> 3;
            int kk  = (idx & 7) << 2;
            float4 wv = *(const float4*)(W + (size_t)(colBase + col) * K + k0 + kk);
            Bs[kk + 0][col] = wv.x;
            Bs[kk + 1][col] = wv.y;
            Bs[kk + 2][col] = wv.z;
            Bs[kk + 3][col] = wv.w;
        }
        __syncthreads();

        #pragma unroll
        for (int k = 0; k < BK; ++k) {
            float4 a4 = *(const float4*)&As[k][ty << 2];
            float4 b4 = *(const float4*)&Bs[k][tx << 2];
            float a[4] = {a4.x, a4.y, a4.z, a4.w};
            float b[4] = {b4.x, b4.y, b4.z, b4.w};
            #pragma unroll
            for (int i = 0; i < 4; ++i)
                #pragma unroll
                for (int j = 0; j < 4; ++j)
                    acc[i][j] = fmaf(a[i], b[j], acc[i][j]);
        }
        __syncthreads();
    }

    const int gcol = colBase + (tx << 2);
    float4 bb = *(const float4*)(bias + gcol);
    #pragma unroll
    for (int i = 0; i < 4; ++i) {
        int grow = rowBase + (ty << 2) + i;
        if (grow >= M) continue;
        float4 v = make_float4(acc[i][0] + bb.x, acc[i][1] + bb.y,
                               acc[i][2] + bb.z, acc[i][3] + bb.w);
        if (extra) {
            float rv = recipv[grow];
            float4 ex = *(const float4*)(extra + (size_t)grow * N + gcol);
            v.x = fmaf(ex.x, rv, v.x);
            v.y = fmaf(ex.y, rv, v.y);
            v.z = fmaf(ex.z, rv, v.z);
            v.w = fmaf(ex.w, rv, v.w);
        }
        v.x = fmaxf(v.x, 0.f);
        v.y = fmaxf(v.y, 0.f);
        v.z = fmaxf(v.z, 0.f);
        v.w = fmaxf(v.w, 0.f);
        *(float4*)(C + (size_t)grow * N + gcol) = v;
    }
}

// ---------------------------------------------------------------- scatters
// 32 threads per nnz entry; each thread moves 4 floats (float4 read, 4 atomics).
__global__ void scatter_edges(const float* __restrict__ m2,
                              const int* __restrict__ v_idx,
                              const int* __restrict__ e_idx,
                              float* __restrict__ e_acc) {
    long long t = (long long)blockIdx.x * blockDim.x + threadIdx.x;
    int i  = (int)(t >> 5);
    int d4 = ((int)t & 31) << 2;
    if (i < NNZ) {
        int v = v_idx[i];
        int e = e_idx[i];
        float4 val = *(const float4*)(m2 + (size_t)v * D + d4);
        float* dst = e_acc + (size_t)e * D + d4;
        atomicAdd(dst + 0, val.x);
        atomicAdd(dst + 1, val.y);
        atomicAdd(dst + 2, val.z);
        atomicAdd(dst + 3, val.w);
    }
}

__global__ void scatter_nodes(const float* __restrict__ e_acc,
                              const float* __restrict__ erecip,
                              const int* __restrict__ v_idx,
                              const int* __restrict__ e_idx,
                              float* __restrict__ v_acc) {
    long long t = (long long)blockIdx.x * blockDim.x + threadIdx.x;
    int i  = (int)(t >> 5);
    int d4 = ((int)t & 31) << 2;
    if (i < NNZ) {
        int v = v_idx[i];
        int e = e_idx[i];
        float re = erecip[e];
        float4 val = *(const float4*)(e_acc + (size_t)e * D + d4);
        float* dst = v_acc + (size_t)v * D + d4;
        atomicAdd(dst + 0, val.x * re);
        atomicAdd(dst + 1, val.y * re);
        atomicAdd(dst + 2, val.z * re);
        atomicAdd(dst + 3, val.w * re);
    }
}

// ---------------------------------------------------------------- head
// one wave (64 lanes) per node: a = h @ Wa^T + ba; out = log_softmax(a)
__global__ void head_kernel(const float* __restrict__ h,
                            const float* __restrict__ Wa,
                            const float* __restrict__ ba,
                            float* __restrict__ out) {
    int wid  = (int)(((long long)blockIdx.x * blockDim.x + threadIdx.x) >> 6);
    int lane = threadIdx.x & 63;
    if (wid >= N_NODES) return;

    float2 h2 = *(const float2*)(h + (size_t)wid * D + lane * 2);
    float a[4];
    #pragma unroll
    for (int j = 0; j < 4; ++j) {
        float2 w2 = *(const float2*)(Wa + j * D + lane * 2);
        float p = h2.x * w2.x + h2.y * w2.y;
        #pragma unroll
        for (int s = 32; s > 0; s >>= 1)
            p += __shfl_xor(p, s, 64);
        a[j] = p + ba[j];
    }
    float mx = fmaxf(fmaxf(a[0], a[1]), fmaxf(a[2], a[3]));
    float se = expf(a[0] - mx) + expf(a[1] - mx) + expf(a[2] - mx) + expf(a[3] - mx);
    float lse = mx + logf(se);
    if (lane < 4)
        out[(size_t)wid * 4 + lane] = a[lane] - lse;
}

// ---------------------------------------------------------------- launch
extern "C" void kernel_launch(void* const* d_in, const int* in_sizes, int n_in,
                              void* d_out, int out_size, void* d_ws, size_t ws_size,
                              hipStream_t stream) {
    const float* x     = (const float*)d_in[0];
    const int*   v_idx = (const int*)d_in[1];
    const int*   e_idx = (const int*)d_in[2];
    const float* W1    = (const float*)d_in[3];
    const float* b1    = (const float*)d_in[4];
    const float* W2    = (const float*)d_in[5];
    const float* b2    = (const float*)d_in[6];
    const float* Wu    = (const float*)d_in[7];
    const float* bu    = (const float*)d_in[8];
    const float* Wa    = (const float*)d_in[9];
    const float* ba    = (const float*)d_in[10];
    float* out = (float*)d_out;

    char* ws = (char*)d_ws;
    float* bufY  = (float*)ws; ws += (size_t)N_NODES * D * 4;   // h after iter 0
    float* bufX  = (float*)ws; ws += (size_t)N_NODES * D * 4;   // m2 / final h
    float* m1    = (float*)ws; ws += (size_t)N_NODES * H * 4;   // m1; first half aliased as v_acc
    float* e_acc = (float*)ws; ws += (size_t)N_EDGES * D * 4;
    int*   ecnt  = (int*)ws;   ws += (size_t)N_EDGES * 4;
    int*   vcnt  = (int*)ws;   ws += (size_t)N_NODES * 4;
    float* erecip= (float*)ws; ws += (size_t)N_EDGES * 4;
    float* vrecip= (float*)ws; ws += (size_t)N_NODES * 4;
    float* v_acc = m1;  // alias: m1 is dead once GEMM2 has consumed it

    // degrees (once per call)
    hipMemsetAsync(ecnt, 0, (size_t)(N_EDGES + N_NODES) * 4, stream);
    count_degrees<<<(NNZ + 255) / 256, 256, 0, stream>>>(v_idx, e_idx, vcnt, ecnt);
    make_recip<<<(N_EDGES + 255) / 256, 256, 0, stream>>>(ecnt, erecip, N_EDGES);
    make_recip<<<(N_NODES + 255) / 256, 256, 0, stream>>>(vcnt, vrecip, N_NODES);

    const int gridM = (N_NODES + TM - 1) / TM;  // 782
    const int scatterBlocks = (NNZ * 32 + 255) / 256;

    const float* h = x;
    for (int depth = 0; depth < 2; ++depth) {
        // m1 = relu(h @ W1^T + b1)          [N, H]
        gemm_relu<<<dim3(gridM, H / TN), 256, 0, stream>>>(
            h, W1, b1, m1, N_NODES, H, D, nullptr, nullptr);
        // m2 = relu(m1 @ W2^T + b2)         [N, D]
        gemm_relu<<<dim3(gridM, D / TN), 256, 0, stream>>>(
            m1, W2, b2, bufX, N_NODES, D, H, nullptr, nullptr);
        // e_acc = segment_sum(m2[v_idx] -> e_idx)
        hipMemsetAsync(e_acc, 0, (size_t)N_EDGES * D * 4, stream);
        scatter_edges<<<scatterBlocks, 256, 0, stream>>>(bufX, v_idx, e_idx, e_acc);
        // v_acc = segment_sum((e_acc/edeg)[e_idx] -> v_idx)
        hipMemsetAsync(v_acc, 0, (size_t)N_NODES * D * 4, stream);
        scatter_nodes<<<scatterBlocks, 256, 0, stream>>>(e_acc, erecip, v_idx, e_idx, v_acc);
        // h' = relu(h @ Wu^T + bu + v_acc * vrecip)
        float* hn = (depth == 0) ? bufY : bufX;
        gemm_relu<<<dim3(gridM, D / TN), 256, 0, stream>>>(
            h, Wu, bu, hn, N_NODES, D, D, v_acc, vrecip);
        h = hn;
    }

    // head: out = log_softmax(h @ Wa^T + ba)
    head_kernel<<<(N_NODES * 64 + 255) / 256, 256, 0, stream>>>(h, Wa, ba, out);
}

// Round 2
// 874.154 us; speedup vs baseline: 5.1739x; 5.1739x over previous
//
#include <hip/hip_runtime.h>
#include <hip/hip_bf16.h>
#include <math.h>

#define N_NODES 50000
#define N_EDGES 25000
#define NNZ     600000
#define D       128
#define H       256

// ---------------------------------------------------------------- degrees
__global__ void count_degrees(const int* __restrict__ v_idx,
                              const int* __restrict__ e_idx,
                              int* __restrict__ vcnt, int* __restrict__ ecnt) {
    int i = blockIdx.x * blockDim.x + threadIdx.x;
    if (i < NNZ) {
        atomicAdd(&vcnt[v_idx[i]], 1);
        atomicAdd(&ecnt[e_idx[i]], 1);
    }
}

__global__ void make_recip(const int* __restrict__ cnt, float* __restrict__ recip, int n) {
    int i = blockIdx.x * blockDim.x + threadIdx.x;
    if (i < n) {
        int c = cnt[i];
        recip[i] = 1.0f / (float)(c > 0 ? c : 1);
    }
}

// single-block exclusive scan (n up to ~64k), writes off[0..n]
__global__ void exclusive_scan(const int* __restrict__ cnt, int* __restrict__ off, int n) {
    __shared__ int s[1024];
    __shared__ int carry_s;
    if (threadIdx.x == 0) carry_s = 0;
    __syncthreads();
    for (int base = 0; base < n; base += 1024) {
        int i = base + threadIdx.x;
        int v = (i < n) ? cnt[i] : 0;
        s[threadIdx.x] = v;
        __syncthreads();
        for (int d = 1; d < 1024; d <<= 1) {
            int t = (threadIdx.x >= d) ? s[threadIdx.x - d] : 0;
            __syncthreads();
            s[threadIdx.x] += t;
            __syncthreads();
        }
        int carry = carry_s;
        if (i < n) off[i] = carry + s[threadIdx.x] - v;
        __syncthreads();                       // everyone read carry_s
        if (threadIdx.x == 1023) carry_s = carry + s[1023];
        __syncthreads();
    }
    if (threadIdx.x == 0) off[n] = carry_s;
}

__global__ void copy_int(const int* __restrict__ src, int* __restrict__ dst, int n) {
    int i = blockIdx.x * blockDim.x + threadIdx.x;
    if (i < n) dst[i] = src[i];
}

// fill CSR adjacency: edge -> member vertices, vertex -> member edges
__global__ void fill_csr(const int* __restrict__ v_idx, const int* __restrict__ e_idx,
                         int* __restrict__ ecur, int* __restrict__ vcur,
                         int* __restrict__ e_vert, int* __restrict__ v_edge) {
    int i = blockIdx.x * blockDim.x + threadIdx.x;
    if (i < NNZ) {
        int v = v_idx[i];
        int e = e_idx[i];
        int pe = atomicAdd(&ecur[e], 1);
        e_vert[pe] = v;
        int pv = atomicAdd(&vcur[v], 1);
        v_edge[pv] = e;
    }
}

// ---------------------------------------------------------------- gathers
// one wave per segment; each lane owns 2 of the 128 features.
// out[seg] = recip[seg] * sum_{p in [off[seg],off[seg+1])} src[list[p]]
__global__ void gather_rows(const float* __restrict__ src,
                            const int* __restrict__ off,
                            const int* __restrict__ list,
                            const float* __restrict__ recip,
                            float* __restrict__ out, int nseg) {
    int seg  = (int)(((long long)blockIdx.x * blockDim.x + threadIdx.x) >> 6);
    int lane = threadIdx.x & 63;
    if (seg >= nseg) return;
    int s = off[seg];
    int e = off[seg + 1];
    float ax = 0.f, ay = 0.f;
    for (int base = s; base < e; base += 64) {
        int navail = e - base;
        int idx = (lane < navail) ? list[base + lane] : 0;   // coalesced chunk
        int cnt = navail < 64 ? navail : 64;
        for (int j = 0; j < cnt; ++j) {
            int r = __shfl(idx, j, 64);
            float2 t = *(const float2*)(src + (size_t)r * D + lane * 2);
            ax += t.x;
            ay += t.y;
        }
    }
    float rc = recip[seg];
    *(float2*)(out + (size_t)seg * D + lane * 2) = make_float2(ax * rc, ay * rc);
}

// ---------------------------------------------------------------- GEMM
// C[M,N] = relu(A[M,K] @ W[N,K]^T + bias[N] (+ extra[M,N]))
#define TM 64
#define TN 64
#define BK 32

__launch_bounds__(256)
__global__ void gemm_relu(const float* __restrict__ A,
                          const float* __restrict__ W,
                          const float* __restrict__ bias,
                          float* __restrict__ C,
                          int M, int N, int K,
                          const float* __restrict__ extra) {
    __shared__ float As[BK][TM];
    __shared__ float Bs[BK][TN];

    const int tid = threadIdx.x;
    const int tx  = tid & 15;
    const int ty  = tid >> 4;
    const int rowBase = blockIdx.x * TM;
    const int colBase = blockIdx.y * TN;

    float acc[4][4] = {};

    for (int k0 = 0; k0 < K; k0 += BK) {
        #pragma unroll
        for (int r = 0; r < 2; ++r) {
            int idx = tid + r * 256;
            int row = idx >> 3;
            int kk  = (idx & 7) << 2;
            float4 av = make_float4(0.f, 0.f, 0.f, 0.f);
            int grow = rowBase + row;
            if (grow < M)
                av = *(const float4*)(A + (size_t)grow * K + k0 + kk);
            As[kk + 0][row] = av.x;
            As[kk + 1][row] = av.y;
            As[kk + 2][row] = av.z;
            As[kk + 3][row] = av.w;
        }
        #pragma unroll
        for (int r = 0; r < 2; ++r) {
            int idx = tid + r * 256;
            int col = idx >> 3;
            int kk  = (idx & 7) << 2;
            float4 wv = *(const float4*)(W + (size_t)(colBase + col) * K + k0 + kk);
            Bs[kk + 0][col] = wv.x;
            Bs[kk + 1][col] = wv.y;
            Bs[kk + 2][col] = wv.z;
            Bs[kk + 3][col] = wv.w;
        }
        __syncthreads();

        #pragma unroll
        for (int k = 0; k < BK; ++k) {
            float4 a4 = *(const float4*)&As[k][ty << 2];
            float4 b4 = *(const float4*)&Bs[k][tx << 2];
            float a[4] = {a4.x, a4.y, a4.z, a4.w};
            float b[4] = {b4.x, b4.y, b4.z, b4.w};
            #pragma unroll
            for (int i = 0; i < 4; ++i)
                #pragma unroll
                for (int j = 0; j < 4; ++j)
                    acc[i][j] = fmaf(a[i], b[j], acc[i][j]);
        }
        __syncthreads();
    }

    const int gcol = colBase + (tx << 2);
    float4 bb = *(const float4*)(bias + gcol);
    #pragma unroll
    for (int i = 0; i < 4; ++i) {
        int grow = rowBase + (ty << 2) + i;
        if (grow >= M) continue;
        float4 v = make_float4(acc[i][0] + bb.x, acc[i][1] + bb.y,
                               acc[i][2] + bb.z, acc[i][3] + bb.w);
        if (extra) {
            float4 ex = *(const float4*)(extra + (size_t)grow * N + gcol);
            v.x += ex.x; v.y += ex.y; v.z += ex.z; v.w += ex.w;
        }
        v.x = fmaxf(v.x, 0.f);
        v.y = fmaxf(v.y, 0.f);
        v.z = fmaxf(v.z, 0.f);
        v.w = fmaxf(v.w, 0.f);
        *(float4*)(C + (size_t)grow * N + gcol) = v;
    }
}

// ---------------------------------------------------------------- head
__global__ void head_kernel(const float* __restrict__ h,
                            const float* __restrict__ Wa,
                            const float* __restrict__ ba,
                            float* __restrict__ out) {
    int wid  = (int)(((long long)blockIdx.x * blockDim.x + threadIdx.x) >> 6);
    int lane = threadIdx.x & 63;
    if (wid >= N_NODES) return;

    float2 h2 = *(const float2*)(h + (size_t)wid * D + lane * 2);
    float a[4];
    #pragma unroll
    for (int j = 0; j < 4; ++j) {
        float2 w2 = *(const float2*)(Wa + j * D + lane * 2);
        float p = h2.x * w2.x + h2.y * w2.y;
        #pragma unroll
        for (int s = 32; s > 0; s >>= 1)
            p += __shfl_xor(p, s, 64);
        a[j] = p + ba[j];
    }
    float mx = fmaxf(fmaxf(a[0], a[1]), fmaxf(a[2], a[3]));
    float se = expf(a[0] - mx) + expf(a[1] - mx) + expf(a[2] - mx) + expf(a[3] - mx);
    float lse = mx + logf(se);
    if (lane < 4)
        out[(size_t)wid * 4 + lane] = a[lane] - lse;
}

// ---------------------------------------------------------------- launch
extern "C" void kernel_launch(void* const* d_in, const int* in_sizes, int n_in,
                              void* d_out, int out_size, void* d_ws, size_t ws_size,
                              hipStream_t stream) {
    const float* x     = (const float*)d_in[0];
    const int*   v_idx = (const int*)d_in[1];
    const int*   e_idx = (const int*)d_in[2];
    const float* W1    = (const float*)d_in[3];
    const float* b1    = (const float*)d_in[4];
    const float* W2    = (const float*)d_in[5];
    const float* b2    = (const float*)d_in[6];
    const float* Wu    = (const float*)d_in[7];
    const float* bu    = (const float*)d_in[8];
    const float* Wa    = (const float*)d_in[9];
    const float* ba    = (const float*)d_in[10];
    float* out = (float*)d_out;

    char* ws = (char*)d_ws;
    float* bufY   = (float*)ws; ws += (size_t)N_NODES * D * 4;
    float* bufX   = (float*)ws; ws += (size_t)N_NODES * D * 4;
    float* m1     = (float*)ws; ws += (size_t)N_NODES * H * 4;
    float* e_feat = (float*)ws; ws += (size_t)N_EDGES * D * 4;
    int*   e_vert = (int*)ws;   ws += (size_t)NNZ * 4;
    int*   v_edge = (int*)ws;   ws += (size_t)NNZ * 4;
    int*   ecnt   = (int*)ws;   ws += (size_t)N_EDGES * 4;   // reused as cursor
    int*   vcnt   = (int*)ws;   ws += (size_t)N_NODES * 4;   // reused as cursor
    int*   e_off  = (int*)ws;   ws += (size_t)(N_EDGES + 1) * 4;
    int*   v_off  = (int*)ws;   ws += (size_t)(N_NODES + 1) * 4;
    float* erecip = (float*)ws; ws += (size_t)N_EDGES * 4;
    float* vrecip = (float*)ws; ws += (size_t)N_NODES * 4;
    float* v_agg  = m1;  // alias: m1 dead once GEMM2 has consumed it

    // ---- build CSR (same work every call) ----
    hipMemsetAsync(ecnt, 0, (size_t)(N_EDGES + N_NODES) * 4, stream);
    count_degrees<<<(NNZ + 255) / 256, 256, 0, stream>>>(v_idx, e_idx, vcnt, ecnt);
    make_recip<<<(N_EDGES + 255) / 256, 256, 0, stream>>>(ecnt, erecip, N_EDGES);
    make_recip<<<(N_NODES + 255) / 256, 256, 0, stream>>>(vcnt, vrecip, N_NODES);
    exclusive_scan<<<1, 1024, 0, stream>>>(ecnt, e_off, N_EDGES);
    exclusive_scan<<<1, 1024, 0, stream>>>(vcnt, v_off, N_NODES);
    copy_int<<<(N_EDGES + 255) / 256, 256, 0, stream>>>(e_off, ecnt, N_EDGES);
    copy_int<<<(N_NODES + 255) / 256, 256, 0, stream>>>(v_off, vcnt, N_NODES);
    fill_csr<<<(NNZ + 255) / 256, 256, 0, stream>>>(v_idx, e_idx, ecnt, vcnt, e_vert, v_edge);

    const int gridM = (N_NODES + TM - 1) / TM;

    const float* h = x;
    for (int depth = 0; depth < 2; ++depth) {
        gemm_relu<<<dim3(gridM, H / TN), 256, 0, stream>>>(
            h, W1, b1, m1, N_NODES, H, D, nullptr);
        gemm_relu<<<dim3(gridM, D / TN), 256, 0, stream>>>(
            m1, W2, b2, bufX, N_NODES, D, H, nullptr);
        // e_feat[e] = erecip[e] * sum_{v in e} m2[v]
        gather_rows<<<(N_EDGES * 64 + 255) / 256, 256, 0, stream>>>(
            bufX, e_off, e_vert, erecip, e_feat, N_EDGES);
        // v_agg[v] = vrecip[v] * sum_{e in v} e_feat[e]
        gather_rows<<<(N_NODES * 64 + 255) / 256, 256, 0, stream>>>(
            e_feat, v_off, v_edge, vrecip, v_agg, N_NODES);
        float* hn = (depth == 0) ? bufY : bufX;
        gemm_relu<<<dim3(gridM, D / TN), 256, 0, stream>>>(
            h, Wu, bu, hn, N_NODES, D, D, v_agg);
        h = hn;
    }

    head_kernel<<<(N_NODES * 64 + 255) / 256, 256, 0, stream>>>(h, Wa, ba, out);
}

// Round 3
// 597.152 us; speedup vs baseline: 7.5739x; 1.4639x over previous
//
#include <hip/hip_runtime.h>
#include <hip/hip_bf16.h>
#include <math.h>

#define N_NODES 50000
#define N_EDGES 25000
#define NNZ     600000
#define D       128
#define H       256

typedef short short8 __attribute__((ext_vector_type(8)));
typedef float floatx4 __attribute__((ext_vector_type(4)));

__device__ inline ushort f2bf(float f) {              // RNE fp32 -> bf16
    uint u = __float_as_uint(f);
    u += 0x7FFF + ((u >> 16) & 1);
    return (ushort)(u >> 16);
}
__device__ inline float bflo(uint u) { return __uint_as_float(u << 16); }
__device__ inline float bfhi(uint u) { return __uint_as_float(u & 0xffff0000u); }

// ---------------------------------------------------------------- convert
__global__ void f32_to_bf16_vec(const float* __restrict__ src, ushort* __restrict__ dst, int n4) {
    int i = blockIdx.x * blockDim.x + threadIdx.x;
    if (i < n4) {
        float4 v = ((const float4*)src)[i];
        ushort4 o;
        o.x = f2bf(v.x); o.y = f2bf(v.y); o.z = f2bf(v.z); o.w = f2bf(v.w);
        ((ushort4*)dst)[i] = o;
    }
}

// ---------------------------------------------------------------- degrees
__global__ void count_degrees(const int* __restrict__ v_idx,
                              const int* __restrict__ e_idx,
                              int* __restrict__ vcnt, int* __restrict__ ecnt) {
    int i = blockIdx.x * blockDim.x + threadIdx.x;
    if (i < NNZ) {
        atomicAdd(&vcnt[v_idx[i]], 1);
        atomicAdd(&ecnt[e_idx[i]], 1);
    }
}

__global__ void make_recip(const int* __restrict__ cnt, float* __restrict__ recip, int n) {
    int i = blockIdx.x * blockDim.x + threadIdx.x;
    if (i < n) {
        int c = cnt[i];
        recip[i] = 1.0f / (float)(c > 0 ? c : 1);
    }
}

// ---------------------------------------------------------------- 3-phase scan
// phase1: each block scans 2048 elements -> local exclusive scan + block sum
__global__ void scan_phase1(const int* __restrict__ cnt, int* __restrict__ local,
                            int* __restrict__ bsum, int n) {
    __shared__ int sh[256];
    int base = blockIdx.x * 2048;
    int o = base + threadIdx.x * 8;
    int items[8];
    int t = 0;
    #pragma unroll
    for (int j = 0; j < 8; ++j) {
        items[j] = (o + j < n) ? cnt[o + j] : 0;
        t += items[j];
    }
    sh[threadIdx.x] = t;
    __syncthreads();
    for (int d = 1; d < 256; d <<= 1) {
        int v = (threadIdx.x >= d) ? sh[threadIdx.x - d] : 0;
        __syncthreads();
        if (threadIdx.x >= d) sh[threadIdx.x] += v;
        __syncthreads();
    }
    int run = sh[threadIdx.x] - t;   // exclusive prefix for this thread
    #pragma unroll
    for (int j = 0; j < 8; ++j) {
        if (o + j < n) local[o + j] = run;
        run += items[j];
    }
    if (threadIdx.x == 255) bsum[blockIdx.x] = sh[255];
}

// phase2: one wave scans <=64 block sums in-place to exclusive, writes total at [nb]
__global__ void scan_phase2(int* __restrict__ bsum, int nb) {
    int lane = threadIdx.x;
    int v = (lane < nb) ? bsum[lane] : 0;
    int orig = v;
    #pragma unroll
    for (int d = 1; d < 64; d <<= 1) {
        int u = __shfl_up(v, d, 64);
        if (lane >= d) v += u;
    }
    if (lane < nb) bsum[lane] = v - orig;      // exclusive
    if (lane == nb - 1) bsum[nb] = v;          // total
}

// phase3: off[i] = cur[i] = local[i] + bsum[block]; off[n] = total
__global__ void scan_phase3(const int* __restrict__ local, const int* __restrict__ bsum,
                            int* __restrict__ off, int* __restrict__ cur, int n, int nb) {
    int i = blockIdx.x * blockDim.x + threadIdx.x;
    if (i < n) {
        int v = local[i] + bsum[i >> 11];
        off[i] = v;
        cur[i] = v;
    }
    if (i == 0) off[n] = bsum[nb];
}

// ---------------------------------------------------------------- CSR fill
__global__ void fill_csr(const int* __restrict__ v_idx, const int* __restrict__ e_idx,
                         int* __restrict__ ecur, int* __restrict__ vcur,
                         int* __restrict__ e_vert, int* __restrict__ v_edge) {
    int i = blockIdx.x * blockDim.x + threadIdx.x;
    if (i < NNZ) {
        int v = v_idx[i];
        int e = e_idx[i];
        int pe = atomicAdd(&ecur[e], 1);
        e_vert[pe] = v;
        int pv = atomicAdd(&vcur[v], 1);
        v_edge[pv] = e;
    }
}

// ---------------------------------------------------------------- gather (bf16 rows)
// one wave per segment; each lane owns 2 of the 128 features.
__global__ void gather_rows(const ushort* __restrict__ src,
                            const int* __restrict__ off,
                            const int* __restrict__ list,
                            const float* __restrict__ recip,
                            ushort* __restrict__ out, int nseg) {
    int seg  = (int)(((long long)blockIdx.x * blockDim.x + threadIdx.x) >> 6);
    int lane = threadIdx.x & 63;
    if (seg >= nseg) return;
    int s = off[seg];
    int e = off[seg + 1];
    float ax = 0.f, ay = 0.f;
    for (int base = s; base < e; base += 64) {
        int navail = e - base;
        int idx = (lane < navail) ? list[base + lane] : 0;
        int cnt = navail < 64 ? navail : 64;
        for (int j = 0; j < cnt; ++j) {
            int r = __shfl(idx, j, 64);
            uint t = *(const uint*)(src + (size_t)r * D + lane * 2);
            ax += bflo(t);
            ay += bfhi(t);
        }
    }
    float rc = recip[seg];
    uint o = ((uint)f2bf(ay * rc) << 16) | (uint)f2bf(ax * rc);
    *(uint*)(out + (size_t)seg * D + lane * 2) = o;
}

// ---------------------------------------------------------------- bf16 MFMA GEMM
// C[M,N] = relu_bf16(A[M,K] @ W[N,K]^T + bias[N] (+ extra[M,N]))
// 64x64 tile, BK=32, 256 threads = 4 waves; wave w owns rows [w*16,w*16+16).
__launch_bounds__(256)
__global__ void gemm_bf16(const ushort* __restrict__ A, const ushort* __restrict__ W,
                          const float* __restrict__ bias, const ushort* __restrict__ extra,
                          ushort* __restrict__ C, int M, int N, int K) {
    __shared__ union {
        struct { ushort A[64][40]; ushort B[64][40]; } ab;   // +8 pad breaks bank aliasing
        float Cs[64][68];
    } sm;

    const int tid = threadIdx.x;
    const int rowBase = blockIdx.x * 64;
    const int colBase = blockIdx.y * 64;
    const int w = tid >> 6, lane = tid & 63;
    const int quad = lane >> 4, mrow = lane & 15;

    floatx4 acc[4] = {{0,0,0,0},{0,0,0,0},{0,0,0,0},{0,0,0,0}};

    const int lrow = tid >> 2;            // 0..63
    const int lkc  = (tid & 3) << 3;      // 0,8,16,24
    const int grow = rowBase + lrow;

    for (int k0 = 0; k0 < K; k0 += 32) {
        uint4 av = make_uint4(0, 0, 0, 0);
        if (grow < M) av = *(const uint4*)(A + (size_t)grow * K + k0 + lkc);
        uint4 wv = *(const uint4*)(W + (size_t)(colBase + lrow) * K + k0 + lkc);
        __syncthreads();
        *(uint4*)&sm.ab.A[lrow][lkc] = av;
        *(uint4*)&sm.ab.B[lrow][lkc] = wv;
        __syncthreads();
        short8 af = *(const short8*)&sm.ab.A[w * 16 + mrow][quad * 8];
        #pragma unroll
        for (int t = 0; t < 4; ++t) {
            short8 bfr = *(const short8*)&sm.ab.B[t * 16 + mrow][quad * 8];
            acc[t] = __builtin_amdgcn_mfma_f32_16x16x32_bf16(af, bfr, acc[t], 0, 0, 0);
        }
    }

    __syncthreads();
    #pragma unroll
    for (int t = 0; t < 4; ++t)
        #pragma unroll
        for (int r = 0; r < 4; ++r)
            sm.Cs[w * 16 + quad * 4 + r][t * 16 + mrow] = acc[t][r];
    __syncthreads();

    const int orow  = tid >> 2;
    const int c0    = (tid & 3) << 4;     // 16 cols per thread
    const int growo = rowBase + orow;
    if (growo < M) {
        const int gcol = colBase + c0;
        float bj[16];
        #pragma unroll
        for (int j4 = 0; j4 < 4; ++j4)
            *(float4*)&bj[j4 * 4] = *(const float4*)(bias + gcol + j4 * 4);
        float ex[16];
        #pragma unroll
        for (int j = 0; j < 16; ++j) ex[j] = 0.f;
        if (extra) {
            const ushort* ep = extra + (size_t)growo * N + gcol;
            uint4 e0 = *(const uint4*)ep;
            uint4 e1 = *(const uint4*)(ep + 8);
            uint eu[8] = {e0.x, e0.y, e0.z, e0.w, e1.x, e1.y, e1.z, e1.w};
            #pragma unroll
            for (int q = 0; q < 8; ++q) {
                ex[q * 2 + 0] = bflo(eu[q]);
                ex[q * 2 + 1] = bfhi(eu[q]);
            }
        }
        union { ushort u16[16]; uint4 u4[2]; } ov;
        #pragma unroll
        for (int j = 0; j < 16; ++j) {
            float v = sm.Cs[orow][c0 + j] + bj[j] + ex[j];
            ov.u16[j] = f2bf(fmaxf(v, 0.f));
        }
        ushort* cp = C + (size_t)growo * N + gcol;
        *(uint4*)cp = ov.u4[0];
        *(uint4*)(cp + 8) = ov.u4[1];
    }
}

// ---------------------------------------------------------------- head
// one wave per node: a = h @ Wa^T + ba; out = log_softmax(a)  (h bf16, out fp32)
__global__ void head_kernel(const ushort* __restrict__ h,
                            const float* __restrict__ Wa,
                            const float* __restrict__ ba,
                            float* __restrict__ out) {
    int wid  = (int)(((long long)blockIdx.x * blockDim.x + threadIdx.x) >> 6);
    int lane = threadIdx.x & 63;
    if (wid >= N_NODES) return;

    uint h2 = *(const uint*)(h + (size_t)wid * D + lane * 2);
    float hx = bflo(h2), hy = bfhi(h2);
    float a[4];
    #pragma unroll
    for (int j = 0; j < 4; ++j) {
        float2 w2 = *(const float2*)(Wa + j * D + lane * 2);
        float p = hx * w2.x + hy * w2.y;
        #pragma unroll
        for (int s = 32; s > 0; s >>= 1)
            p += __shfl_xor(p, s, 64);
        a[j] = p + ba[j];
    }
    float mx = fmaxf(fmaxf(a[0], a[1]), fmaxf(a[2], a[3]));
    float se = expf(a[0] - mx) + expf(a[1] - mx) + expf(a[2] - mx) + expf(a[3] - mx);
    float lse = mx + logf(se);
    if (lane < 4)
        out[(size_t)wid * 4 + lane] = a[lane] - lse;
}

// ---------------------------------------------------------------- launch
extern "C" void kernel_launch(void* const* d_in, const int* in_sizes, int n_in,
                              void* d_out, int out_size, void* d_ws, size_t ws_size,
                              hipStream_t stream) {
    const float* x     = (const float*)d_in[0];
    const int*   v_idx = (const int*)d_in[1];
    const int*   e_idx = (const int*)d_in[2];
    const float* W1    = (const float*)d_in[3];
    const float* b1    = (const float*)d_in[4];
    const float* W2    = (const float*)d_in[5];
    const float* b2    = (const float*)d_in[6];
    const float* Wu    = (const float*)d_in[7];
    const float* bu    = (const float*)d_in[8];
    const float* Wa    = (const float*)d_in[9];
    const float* ba    = (const float*)d_in[10];
    float* out = (float*)d_out;

    char* wsp = (char*)d_ws;
    auto alloc = [&](size_t bytes) -> char* {
        char* p = wsp;
        wsp += (bytes + 255) & ~(size_t)255;
        return p;
    };

    ushort* xb     = (ushort*)alloc((size_t)N_NODES * D * 2);
    ushort* bufY   = (ushort*)alloc((size_t)N_NODES * D * 2);
    ushort* bufX   = (ushort*)alloc((size_t)N_NODES * D * 2);
    ushort* m1     = (ushort*)alloc((size_t)N_NODES * H * 2);
    ushort* e_feat = (ushort*)alloc((size_t)N_EDGES * D * 2);
    ushort* W1b    = (ushort*)alloc((size_t)H * D * 2);
    ushort* W2b    = (ushort*)alloc((size_t)D * H * 2);
    ushort* Wub    = (ushort*)alloc((size_t)D * D * 2);
    int*    e_vert = (int*)alloc((size_t)NNZ * 4);
    int*    v_edge = (int*)alloc((size_t)NNZ * 4);
    int*    ecnt   = (int*)alloc((size_t)(N_EDGES + N_NODES) * 4);   // one memset covers both
    int*    vcnt   = ecnt + N_EDGES;
    int*    e_off  = (int*)alloc((size_t)(N_EDGES + 16) * 4);
    int*    v_off  = (int*)alloc((size_t)(N_NODES + 16) * 4);
    float*  erecip = (float*)alloc((size_t)N_EDGES * 4);
    float*  vrecip = (float*)alloc((size_t)N_NODES * 4);
    int*    localE = (int*)alloc((size_t)N_EDGES * 4);
    int*    localV = (int*)alloc((size_t)N_NODES * 4);
    int*    bsumE  = (int*)alloc(80 * 4);
    int*    bsumV  = (int*)alloc(80 * 4);
    ushort* v_agg  = m1;   // alias: m1 dead once GEMM2 has consumed it

    const int nbE = (N_EDGES + 2047) / 2048;   // 13
    const int nbV = (N_NODES + 2047) / 2048;   // 25

    // ---- weight/feature conversion ----
    f32_to_bf16_vec<<<(N_NODES * D / 4 + 255) / 256, 256, 0, stream>>>(x, xb, N_NODES * D / 4);
    f32_to_bf16_vec<<<(H * D / 4 + 255) / 256, 256, 0, stream>>>(W1, W1b, H * D / 4);
    f32_to_bf16_vec<<<(D * H / 4 + 255) / 256, 256, 0, stream>>>(W2, W2b, D * H / 4);
    f32_to_bf16_vec<<<(D * D / 4 + 255) / 256, 256, 0, stream>>>(Wu, Wub, D * D / 4);

    // ---- CSR build ----
    hipMemsetAsync(ecnt, 0, (size_t)(N_EDGES + N_NODES) * 4, stream);
    count_degrees<<<(NNZ + 255) / 256, 256, 0, stream>>>(v_idx, e_idx, vcnt, ecnt);
    make_recip<<<(N_EDGES + 255) / 256, 256, 0, stream>>>(ecnt, erecip, N_EDGES);
    make_recip<<<(N_NODES + 255) / 256, 256, 0, stream>>>(vcnt, vrecip, N_NODES);
    scan_phase1<<<nbE, 256, 0, stream>>>(ecnt, localE, bsumE, N_EDGES);
    scan_phase1<<<nbV, 256, 0, stream>>>(vcnt, localV, bsumV, N_NODES);
    scan_phase2<<<1, 64, 0, stream>>>(bsumE, nbE);
    scan_phase2<<<1, 64, 0, stream>>>(bsumV, nbV);
    scan_phase3<<<(N_EDGES + 255) / 256, 256, 0, stream>>>(localE, bsumE, e_off, ecnt, N_EDGES, nbE);
    scan_phase3<<<(N_NODES + 255) / 256, 256, 0, stream>>>(localV, bsumV, v_off, vcnt, N_NODES, nbV);
    fill_csr<<<(NNZ + 255) / 256, 256, 0, stream>>>(v_idx, e_idx, ecnt, vcnt, e_vert, v_edge);

    const int gridM = (N_NODES + 63) / 64;   // 782

    const ushort* h = xb;
    for (int depth = 0; depth < 2; ++depth) {
        gemm_bf16<<<dim3(gridM, H / 64), 256, 0, stream>>>(
            h, W1b, b1, nullptr, m1, N_NODES, H, D);
        gemm_bf16<<<dim3(gridM, D / 64), 256, 0, stream>>>(
            m1, W2b, b2, nullptr, bufX, N_NODES, D, H);
        gather_rows<<<(N_EDGES * 64 + 255) / 256, 256, 0, stream>>>(
            bufX, e_off, e_vert, erecip, e_feat, N_EDGES);
        gather_rows<<<(N_NODES * 64 + 255) / 256, 256, 0, stream>>>(
            e_feat, v_off, v_edge, vrecip, v_agg, N_NODES);
        ushort* hn = (depth == 0) ? bufY : bufX;
        gemm_bf16<<<dim3(gridM, D / 64), 256, 0, stream>>>(
            h, Wub, bu, v_agg, hn, N_NODES, D, D);
        h = hn;
    }

    head_kernel<<<(N_NODES * 64 + 255) / 256, 256, 0, stream>>>(h, Wa, ba, out);
}

// Round 4
// 524.735 us; speedup vs baseline: 8.6191x; 1.1380x over previous
//
#include <hip/hip_runtime.h>
#include <hip/hip_bf16.h>
#include <math.h>

#define N_NODES 50000
#define N_EDGES 25000
#define NNZ     600000
#define D       128
#define H       256

typedef short short8 __attribute__((ext_vector_type(8)));
typedef float floatx4 __attribute__((ext_vector_type(4)));

__device__ inline ushort f2bf(float f) {              // RNE fp32 -> bf16
    uint u = __float_as_uint(f);
    u += 0x7FFF + ((u >> 16) & 1);
    return (ushort)(u >> 16);
}
__device__ inline float bflo(uint u) { return __uint_as_float(u << 16); }
__device__ inline float bfhi(uint u) { return __uint_as_float(u & 0xffff0000u); }

// ---------------------------------------------------------------- convert
__global__ void f32_to_bf16_vec(const float* __restrict__ src, ushort* __restrict__ dst, int n4) {
    int i = blockIdx.x * blockDim.x + threadIdx.x;
    if (i < n4) {
        float4 v = ((const float4*)src)[i];
        ushort4 o;
        o.x = f2bf(v.x); o.y = f2bf(v.y); o.z = f2bf(v.z); o.w = f2bf(v.w);
        ((ushort4*)dst)[i] = o;
    }
}

// ---------------------------------------------------------------- degrees
__global__ void count_degrees(const int* __restrict__ v_idx,
                              const int* __restrict__ e_idx,
                              int* __restrict__ vcnt, int* __restrict__ ecnt) {
    int i = blockIdx.x * blockDim.x + threadIdx.x;
    if (i < NNZ) {
        atomicAdd(&vcnt[v_idx[i]], 1);
        atomicAdd(&ecnt[e_idx[i]], 1);
    }
}

__global__ void make_recip(const int* __restrict__ cnt, float* __restrict__ recip, int n) {
    int i = blockIdx.x * blockDim.x + threadIdx.x;
    if (i < n) {
        int c = cnt[i];
        recip[i] = 1.0f / (float)(c > 0 ? c : 1);
    }
}

// ---------------------------------------------------------------- 3-phase scan
__global__ void scan_phase1(const int* __restrict__ cnt, int* __restrict__ local,
                            int* __restrict__ bsum, int n) {
    __shared__ int sh[256];
    int base = blockIdx.x * 2048;
    int o = base + threadIdx.x * 8;
    int items[8];
    int t = 0;
    #pragma unroll
    for (int j = 0; j < 8; ++j) {
        items[j] = (o + j < n) ? cnt[o + j] : 0;
        t += items[j];
    }
    sh[threadIdx.x] = t;
    __syncthreads();
    for (int d = 1; d < 256; d <<= 1) {
        int v = (threadIdx.x >= d) ? sh[threadIdx.x - d] : 0;
        __syncthreads();
        if (threadIdx.x >= d) sh[threadIdx.x] += v;
        __syncthreads();
    }
    int run = sh[threadIdx.x] - t;
    #pragma unroll
    for (int j = 0; j < 8; ++j) {
        if (o + j < n) local[o + j] = run;
        run += items[j];
    }
    if (threadIdx.x == 255) bsum[blockIdx.x] = sh[255];
}

__global__ void scan_phase2(int* __restrict__ bsum, int nb) {
    int lane = threadIdx.x;
    int v = (lane < nb) ? bsum[lane] : 0;
    int orig = v;
    #pragma unroll
    for (int d = 1; d < 64; d <<= 1) {
        int u = __shfl_up(v, d, 64);
        if (lane >= d) v += u;
    }
    if (lane < nb) bsum[lane] = v - orig;
    if (lane == nb - 1) bsum[nb] = v;
}

__global__ void scan_phase3(const int* __restrict__ local, const int* __restrict__ bsum,
                            int* __restrict__ off, int* __restrict__ cur, int n, int nb) {
    int i = blockIdx.x * blockDim.x + threadIdx.x;
    if (i < n) {
        int v = local[i] + bsum[i >> 11];
        off[i] = v;
        cur[i] = v;
    }
    if (i == 0) off[n] = bsum[nb];
}

// ---------------------------------------------------------------- CSR fill
__global__ void fill_csr(const int* __restrict__ v_idx, const int* __restrict__ e_idx,
                         int* __restrict__ ecur, int* __restrict__ vcur,
                         int* __restrict__ e_vert, int* __restrict__ v_edge) {
    int i = blockIdx.x * blockDim.x + threadIdx.x;
    if (i < NNZ) {
        int v = v_idx[i];
        int e = e_idx[i];
        int pe = atomicAdd(&ecur[e], 1);
        __builtin_nontemporal_store(v, &e_vert[pe]);
        int pv = atomicAdd(&vcur[v], 1);
        __builtin_nontemporal_store(e, &v_edge[pv]);
    }
}

// ---------------------------------------------------------------- gather (bf16 rows)
// one wave per segment; lane owns 2 of 128 features. Neighbor indices are
// wave-uniform scalar loads (no shfl); 8-wide unroll -> 8 outstanding loads.
__global__ void gather_rows(const ushort* __restrict__ src,
                            const int* __restrict__ off,
                            const int* __restrict__ list,
                            const float* __restrict__ recip,
                            ushort* __restrict__ out, int nseg) {
    int seg  = (int)(((long long)blockIdx.x * blockDim.x + threadIdx.x) >> 6);
    int lane = threadIdx.x & 63;
    if (seg >= nseg) return;
    int s = __builtin_amdgcn_readfirstlane(off[seg]);
    int e = __builtin_amdgcn_readfirstlane(off[seg + 1]);
    const ushort* sp = src + lane * 2;
    float ax = 0.f, ay = 0.f;
    int p = s;
    for (; p + 8 <= e; p += 8) {
        int r0 = list[p + 0], r1 = list[p + 1], r2 = list[p + 2], r3 = list[p + 3];
        int r4 = list[p + 4], r5 = list[p + 5], r6 = list[p + 6], r7 = list[p + 7];
        uint t0 = *(const uint*)(sp + (size_t)r0 * D);
        uint t1 = *(const uint*)(sp + (size_t)r1 * D);
        uint t2 = *(const uint*)(sp + (size_t)r2 * D);
        uint t3 = *(const uint*)(sp + (size_t)r3 * D);
        uint t4 = *(const uint*)(sp + (size_t)r4 * D);
        uint t5 = *(const uint*)(sp + (size_t)r5 * D);
        uint t6 = *(const uint*)(sp + (size_t)r6 * D);
        uint t7 = *(const uint*)(sp + (size_t)r7 * D);
        ax += bflo(t0) + bflo(t1) + bflo(t2) + bflo(t3)
            + bflo(t4) + bflo(t5) + bflo(t6) + bflo(t7);
        ay += bfhi(t0) + bfhi(t1) + bfhi(t2) + bfhi(t3)
            + bfhi(t4) + bfhi(t5) + bfhi(t6) + bfhi(t7);
    }
    for (; p < e; ++p) {
        uint t = *(const uint*)(sp + (size_t)list[p] * D);
        ax += bflo(t);
        ay += bfhi(t);
    }
    float rc = recip[seg];
    uint o = ((uint)f2bf(ay * rc) << 16) | (uint)f2bf(ax * rc);
    *(uint*)(out + (size_t)seg * D + lane * 2) = o;
}

// ---------------------------------------------------------------- bf16 MFMA GEMM
// C[M,N] = relu_bf16(A[M,K] @ W[N,K]^T + bias[N] (+ extra[M,N]))
__launch_bounds__(256)
__global__ void gemm_bf16(const ushort* __restrict__ A, const ushort* __restrict__ W,
                          const float* __restrict__ bias, const ushort* __restrict__ extra,
                          ushort* __restrict__ C, int M, int N, int K) {
    __shared__ union {
        struct { ushort A[64][40]; ushort B[64][40]; } ab;
        float Cs[64][68];
    } sm;

    const int tid = threadIdx.x;
    const int rowBase = blockIdx.x * 64;
    const int colBase = blockIdx.y * 64;
    const int w = tid >> 6, lane = tid & 63;
    const int quad = lane >> 4, mrow = lane & 15;

    floatx4 acc[4] = {{0,0,0,0},{0,0,0,0},{0,0,0,0},{0,0,0,0}};

    const int lrow = tid >> 2;
    const int lkc  = (tid & 3) << 3;
    const int grow = rowBase + lrow;

    for (int k0 = 0; k0 < K; k0 += 32) {
        uint4 av = make_uint4(0, 0, 0, 0);
        if (grow < M) av = *(const uint4*)(A + (size_t)grow * K + k0 + lkc);
        uint4 wv = *(const uint4*)(W + (size_t)(colBase + lrow) * K + k0 + lkc);
        __syncthreads();
        *(uint4*)&sm.ab.A[lrow][lkc] = av;
        *(uint4*)&sm.ab.B[lrow][lkc] = wv;
        __syncthreads();
        short8 af = *(const short8*)&sm.ab.A[w * 16 + mrow][quad * 8];
        #pragma unroll
        for (int t = 0; t < 4; ++t) {
            short8 bfr = *(const short8*)&sm.ab.B[t * 16 + mrow][quad * 8];
            acc[t] = __builtin_amdgcn_mfma_f32_16x16x32_bf16(af, bfr, acc[t], 0, 0, 0);
        }
    }

    __syncthreads();
    #pragma unroll
    for (int t = 0; t < 4; ++t)
        #pragma unroll
        for (int r = 0; r < 4; ++r)
            sm.Cs[w * 16 + quad * 4 + r][t * 16 + mrow] = acc[t][r];
    __syncthreads();

    const int orow  = tid >> 2;
    const int c0    = (tid & 3) << 4;
    const int growo = rowBase + orow;
    if (growo < M) {
        const int gcol = colBase + c0;
        float bj[16];
        #pragma unroll
        for (int j4 = 0; j4 < 4; ++j4)
            *(float4*)&bj[j4 * 4] = *(const float4*)(bias + gcol + j4 * 4);
        float ex[16];
        #pragma unroll
        for (int j = 0; j < 16; ++j) ex[j] = 0.f;
        if (extra) {
            const ushort* ep = extra + (size_t)growo * N + gcol;
            uint4 e0 = *(const uint4*)ep;
            uint4 e1 = *(const uint4*)(ep + 8);
            uint eu[8] = {e0.x, e0.y, e0.z, e0.w, e1.x, e1.y, e1.z, e1.w};
            #pragma unroll
            for (int q = 0; q < 8; ++q) {
                ex[q * 2 + 0] = bflo(eu[q]);
                ex[q * 2 + 1] = bfhi(eu[q]);
            }
        }
        union { ushort u16[16]; uint4 u4[2]; } ov;
        #pragma unroll
        for (int j = 0; j < 16; ++j) {
            float v = sm.Cs[orow][c0 + j] + bj[j] + ex[j];
            ov.u16[j] = f2bf(fmaxf(v, 0.f));
        }
        ushort* cp = C + (size_t)growo * N + gcol;
        *(uint4*)cp = ov.u4[0];
        *(uint4*)(cp + 8) = ov.u4[1];
    }
}

// ---------------------------------------------------------------- head
__global__ void head_kernel(const ushort* __restrict__ h,
                            const float* __restrict__ Wa,
                            const float* __restrict__ ba,
                            float* __restrict__ out) {
    int wid  = (int)(((long long)blockIdx.x * blockDim.x + threadIdx.x) >> 6);
    int lane = threadIdx.x & 63;
    if (wid >= N_NODES) return;

    uint h2 = *(const uint*)(h + (size_t)wid * D + lane * 2);
    float hx = bflo(h2), hy = bfhi(h2);
    float a[4];
    #pragma unroll
    for (int j = 0; j < 4; ++j) {
        float2 w2 = *(const float2*)(Wa + j * D + lane * 2);
        float p = hx * w2.x + hy * w2.y;
        #pragma unroll
        for (int s = 32; s > 0; s >>= 1)
            p += __shfl_xor(p, s, 64);
        a[j] = p + ba[j];
    }
    float mx = fmaxf(fmaxf(a[0], a[1]), fmaxf(a[2], a[3]));
    float se = expf(a[0] - mx) + expf(a[1] - mx) + expf(a[2] - mx) + expf(a[3] - mx);
    float lse = mx + logf(se);
    if (lane < 4)
        out[(size_t)wid * 4 + lane] = a[lane] - lse;
}

// ---------------------------------------------------------------- launch
extern "C" void kernel_launch(void* const* d_in, const int* in_sizes, int n_in,
                              void* d_out, int out_size, void* d_ws, size_t ws_size,
                              hipStream_t stream) {
    const float* x     = (const float*)d_in[0];
    const int*   v_idx = (const int*)d_in[1];
    const int*   e_idx = (const int*)d_in[2];
    const float* W1    = (const float*)d_in[3];
    const float* b1    = (const float*)d_in[4];
    const float* W2    = (const float*)d_in[5];
    const float* b2    = (const float*)d_in[6];
    const float* Wu    = (const float*)d_in[7];
    const float* bu    = (const float*)d_in[8];
    const float* Wa    = (const float*)d_in[9];
    const float* ba    = (const float*)d_in[10];
    float* out = (float*)d_out;

    char* wsp = (char*)d_ws;
    auto alloc = [&](size_t bytes) -> char* {
        char* p = wsp;
        wsp += (bytes + 255) & ~(size_t)255;
        return p;
    };

    ushort* xb     = (ushort*)alloc((size_t)N_NODES * D * 2);
    ushort* bufY   = (ushort*)alloc((size_t)N_NODES * D * 2);
    ushort* bufX   = (ushort*)alloc((size_t)N_NODES * D * 2);
    ushort* m1     = (ushort*)alloc((size_t)N_NODES * H * 2);
    ushort* e_feat = (ushort*)alloc((size_t)N_EDGES * D * 2);
    ushort* W1b    = (ushort*)alloc((size_t)H * D * 2);
    ushort* W2b    = (ushort*)alloc((size_t)D * H * 2);
    ushort* Wub    = (ushort*)alloc((size_t)D * D * 2);
    int*    e_vert = (int*)alloc((size_t)NNZ * 4);
    int*    v_edge = (int*)alloc((size_t)NNZ * 4);
    int*    ecnt   = (int*)alloc((size_t)(N_EDGES + N_NODES) * 4);
    int*    vcnt   = ecnt + N_EDGES;
    int*    e_off  = (int*)alloc((size_t)(N_EDGES + 16) * 4);
    int*    v_off  = (int*)alloc((size_t)(N_NODES + 16) * 4);
    float*  erecip = (float*)alloc((size_t)N_EDGES * 4);
    float*  vrecip = (float*)alloc((size_t)N_NODES * 4);
    int*    localE = (int*)alloc((size_t)N_EDGES * 4);
    int*    localV = (int*)alloc((size_t)N_NODES * 4);
    int*    bsumE  = (int*)alloc(80 * 4);
    int*    bsumV  = (int*)alloc(80 * 4);
    ushort* v_agg  = m1;   // alias: m1 dead once GEMM2 has consumed it

    const int nbE = (N_EDGES + 2047) / 2048;   // 13
    const int nbV = (N_NODES + 2047) / 2048;   // 25

    f32_to_bf16_vec<<<(N_NODES * D / 4 + 255) / 256, 256, 0, stream>>>(x, xb, N_NODES * D / 4);
    f32_to_bf16_vec<<<(H * D / 4 + 255) / 256, 256, 0, stream>>>(W1, W1b, H * D / 4);
    f32_to_bf16_vec<<<(D * H / 4 + 255) / 256, 256, 0, stream>>>(W2, W2b, D * H / 4);
    f32_to_bf16_vec<<<(D * D / 4 + 255) / 256, 256, 0, stream>>>(Wu, Wub, D * D / 4);

    hipMemsetAsync(ecnt, 0, (size_t)(N_EDGES + N_NODES) * 4, stream);
    count_degrees<<<(NNZ + 255) / 256, 256, 0, stream>>>(v_idx, e_idx, vcnt, ecnt);
    make_recip<<<(N_EDGES + 255) / 256, 256, 0, stream>>>(ecnt, erecip, N_EDGES);
    make_recip<<<(N_NODES + 255) / 256, 256, 0, stream>>>(vcnt, vrecip, N_NODES);
    scan_phase1<<<nbE, 256, 0, stream>>>(ecnt, localE, bsumE, N_EDGES);
    scan_phase1<<<nbV, 256, 0, stream>>>(vcnt, localV, bsumV, N_NODES);
    scan_phase2<<<1, 64, 0, stream>>>(bsumE, nbE);
    scan_phase2<<<1, 64, 0, stream>>>(bsumV, nbV);
    scan_phase3<<<(N_EDGES + 255) / 256, 256, 0, stream>>>(localE, bsumE, e_off, ecnt, N_EDGES, nbE);
    scan_phase3<<<(N_NODES + 255) / 256, 256, 0, stream>>>(localV, bsumV, v_off, vcnt, N_NODES, nbV);
    fill_csr<<<(NNZ + 255) / 256, 256, 0, stream>>>(v_idx, e_idx, ecnt, vcnt, e_vert, v_edge);

    const int gridM = (N_NODES + 63) / 64;   // 782

    const ushort* h = xb;
    for (int depth = 0; depth < 2; ++depth) {
        gemm_bf16<<<dim3(gridM, H / 64), 256, 0, stream>>>(
            h, W1b, b1, nullptr, m1, N_NODES, H, D);
        gemm_bf16<<<dim3(gridM, D / 64), 256, 0, stream>>>(
            m1, W2b, b2, nullptr, bufX, N_NODES, D, H);
        gather_rows<<<(N_EDGES * 64 + 255) / 256, 256, 0, stream>>>(
            bufX, e_off, e_vert, erecip, e_feat, N_EDGES);
        gather_rows<<<(N_NODES * 64 + 255) / 256, 256, 0, stream>>>(
            e_feat, v_off, v_edge, vrecip, v_agg, N_NODES);
        ushort* hn = (depth == 0) ? bufY : bufX;
        gemm_bf16<<<dim3(gridM, D / 64), 256, 0, stream>>>(
            h, Wub, bu, v_agg, hn, N_NODES, D, D);
        h = hn;
    }

    head_kernel<<<(N_NODES * 64 + 255) / 256, 256, 0, stream>>>(h, Wa, ba, out);
}

// Round 5
// 389.819 us; speedup vs baseline: 11.6022x; 1.3461x over previous
//
#include <hip/hip_runtime.h>
#include <hip/hip_bf16.h>
#include <math.h>

#define N_NODES 50000
#define N_EDGES 25000
#define NNZ     600000
#define D       128
#define H       256

#define BW    98            // bucket width (segments per bucket)
#define NBE   256           // ceil(25000/98)
#define NBV   511           // ceil(50000/98)
#define CHUNK 4096          // COO items per block in hist/place

typedef short short8 __attribute__((ext_vector_type(8)));
typedef float floatx4 __attribute__((ext_vector_type(4)));

__device__ inline ushort f2bf(float f) {              // RNE fp32 -> bf16
    uint u = __float_as_uint(f);
    u += 0x7FFF + ((u >> 16) & 1);
    return (ushort)(u >> 16);
}
__device__ inline float bflo(uint u) { return __uint_as_float(u << 16); }
__device__ inline float bfhi(uint u) { return __uint_as_float(u & 0xffff0000u); }

// ---------------------------------------------------------------- convert
__global__ void f32_to_bf16_vec(const float* __restrict__ src, ushort* __restrict__ dst, int n4) {
    int i = blockIdx.x * blockDim.x + threadIdx.x;
    if (i < n4) {
        float4 v = ((const float4*)src)[i];
        ushort4 o;
        o.x = f2bf(v.x); o.y = f2bf(v.y); o.z = f2bf(v.z); o.w = f2bf(v.w);
        ((ushort4*)dst)[i] = o;
    }
}

// ---------------------------------------------------------------- bucketed CSR build
// Phase 1: global bucket histograms (LDS pre-aggregated)
__global__ void bucket_hist(const int* __restrict__ v_idx, const int* __restrict__ e_idx,
                            int* __restrict__ cntE, int* __restrict__ cntV) {
    __shared__ int hE[NBE];
    __shared__ int hV[NBV];
    for (int i = threadIdx.x; i < NBE; i += 256) hE[i] = 0;
    for (int i = threadIdx.x; i < NBV; i += 256) hV[i] = 0;
    __syncthreads();
    int base = blockIdx.x * CHUNK;
    int end  = min(base + CHUNK, NNZ);
    for (int i = base + threadIdx.x; i < end; i += 256) {
        atomicAdd(&hE[e_idx[i] / BW], 1);
        atomicAdd(&hV[v_idx[i] / BW], 1);
    }
    __syncthreads();
    for (int i = threadIdx.x; i < NBE; i += 256) if (hE[i]) atomicAdd(&cntE[i], hE[i]);
    for (int i = threadIdx.x; i < NBV; i += 256) if (hV[i]) atomicAdd(&cntV[i], hV[i]);
}

// Phase 2: exclusive scan of bucket counts (block 0: E, block 1: V); also off[n]=NNZ
__global__ void bucket_scan(const int* __restrict__ cntE, int* __restrict__ ptrE, int* __restrict__ curE,
                            const int* __restrict__ cntV, int* __restrict__ ptrV, int* __restrict__ curV,
                            int* __restrict__ e_off, int* __restrict__ v_off) {
    __shared__ int s[512];
    int n = (blockIdx.x == 0) ? NBE : NBV;
    const int* cnt = (blockIdx.x == 0) ? cntE : cntV;
    int* ptr = (blockIdx.x == 0) ? ptrE : ptrV;
    int* cur = (blockIdx.x == 0) ? curE : curV;
    int t = threadIdx.x;
    int v = (t < n) ? cnt[t] : 0;
    s[t] = v;
    __syncthreads();
    for (int d = 1; d < 512; d <<= 1) {
        int u = (t >= d) ? s[t - d] : 0;
        __syncthreads();
        s[t] += u;
        __syncthreads();
    }
    if (t < n) {
        int ex = s[t] - v;
        ptr[t] = ex;
        cur[t] = ex;
    }
    if (t == 0) {
        if (blockIdx.x == 0) e_off[N_EDGES] = NNZ;
        else                 v_off[N_NODES] = NNZ;
    }
}

// Phase 3: place (key,val) records into buckets; per-(block,bucket) reservation
__global__ void bucket_place(const int* __restrict__ v_idx, const int* __restrict__ e_idx,
                             int* __restrict__ curE, int* __restrict__ curV,
                             int2* __restrict__ recE, int2* __restrict__ recV) {
    __shared__ int hE[NBE], hV[NBV];     // histogram, then reused as LDS cursor
    __shared__ int rE[NBE], rV[NBV];     // reserved global base per bucket
    for (int i = threadIdx.x; i < NBE; i += 256) hE[i] = 0;
    for (int i = threadIdx.x; i < NBV; i += 256) hV[i] = 0;
    __syncthreads();
    int base = blockIdx.x * CHUNK;
    int end  = min(base + CHUNK, NNZ);
    int myE[16], myV[16];
    #pragma unroll
    for (int j = 0; j < 16; ++j) {
        int i = base + threadIdx.x + j * 256;
        myE[j] = -1; myV[j] = -1;
        if (i < end) {
            myE[j] = e_idx[i];
            myV[j] = v_idx[i];
            atomicAdd(&hE[myE[j] / BW], 1);
            atomicAdd(&hV[myV[j] / BW], 1);
        }
    }
    __syncthreads();
    for (int i = threadIdx.x; i < NBE; i += 256) {
        int c = hE[i];
        rE[i] = c ? atomicAdd(&curE[i], c) : 0;
    }
    for (int i = threadIdx.x; i < NBV; i += 256) {
        int c = hV[i];
        rV[i] = c ? atomicAdd(&curV[i], c) : 0;
    }
    __syncthreads();
    for (int i = threadIdx.x; i < NBE; i += 256) hE[i] = 0;
    for (int i = threadIdx.x; i < NBV; i += 256) hV[i] = 0;
    __syncthreads();
    #pragma unroll
    for (int j = 0; j < 16; ++j) {
        if (myE[j] >= 0) {
            int bk = myE[j] / BW;
            int p = rE[bk] + atomicAdd(&hE[bk], 1);
            recE[p] = make_int2(myE[j], myV[j]);
            bk = myV[j] / BW;
            p = rV[bk] + atomicAdd(&hV[bk], 1);
            recV[p] = make_int2(myV[j], myE[j]);
        }
    }
}

// Phase 4: one block per bucket -> final CSR segment + offsets + recip
__global__ void bucket_final(const int2* __restrict__ recE, const int* __restrict__ ptrE,
                             const int2* __restrict__ recV, const int* __restrict__ ptrV,
                             int* __restrict__ e_off, float* __restrict__ erecip, int* __restrict__ e_vert,
                             int* __restrict__ v_off, float* __restrict__ vrecip, int* __restrict__ v_edge) {
    __shared__ int hist[BW], scn[BW], cur[BW];
    const bool eSide = blockIdx.x < NBE;
    const int b = eSide ? blockIdx.x : blockIdx.x - NBE;
    const int2* rec = eSide ? recE : recV;
    const int* ptr  = eSide ? ptrE : ptrV;
    const int nseg  = eSide ? N_EDGES : N_NODES;
    const int nb    = eSide ? NBE : NBV;
    int* off        = eSide ? e_off : v_off;
    float* recip    = eSide ? erecip : vrecip;
    int* outv       = eSide ? e_vert : v_edge;

    const int s = ptr[b];
    const int e = (b + 1 < nb) ? ptr[b + 1] : NNZ;
    const int k0 = b * BW;

    for (int i = threadIdx.x; i < BW; i += 256) hist[i] = 0;
    __syncthreads();
    for (int i = s + threadIdx.x; i < e; i += 256)
        atomicAdd(&hist[rec[i].x - k0], 1);
    __syncthreads();

    if (threadIdx.x < 64) {
        int lane = threadIdx.x;
        int v0 = hist[lane];
        int a = v0;
        #pragma unroll
        for (int d = 1; d < 64; d <<= 1) {
            int u = __shfl_up(a, d, 64);
            if (lane >= d) a += u;
        }
        scn[lane] = a - v0;
        int tot0 = __shfl(a, 63, 64);
        int v1 = (lane < BW - 64) ? hist[64 + lane] : 0;
        int a1 = v1;
        #pragma unroll
        for (int d = 1; d < 64; d <<= 1) {
            int u = __shfl_up(a1, d, 64);
            if (lane >= d) a1 += u;
        }
        if (lane < BW - 64) scn[64 + lane] = tot0 + a1 - v1;
    }
    __syncthreads();

    for (int i = threadIdx.x; i < BW; i += 256) {
        int seg = k0 + i;
        if (seg < nseg) {
            off[seg] = s + scn[i];
            recip[seg] = 1.0f / (float)max(hist[i], 1);
        }
        cur[i] = scn[i];
    }
    __syncthreads();
    for (int i = s + threadIdx.x; i < e; i += 256) {
        int2 r = rec[i];
        int p = s + atomicAdd(&cur[r.x - k0], 1);
        outv[p] = r.y;
    }
}

// ---------------------------------------------------------------- gather (bf16 rows)
__global__ void gather_rows(const ushort* __restrict__ src,
                            const int* __restrict__ off,
                            const int* __restrict__ list,
                            const float* __restrict__ recip,
                            ushort* __restrict__ out, int nseg) {
    int seg  = (int)(((long long)blockIdx.x * blockDim.x + threadIdx.x) >> 6);
    int lane = threadIdx.x & 63;
    if (seg >= nseg) return;
    int s = __builtin_amdgcn_readfirstlane(off[seg]);
    int e = __builtin_amdgcn_readfirstlane(off[seg + 1]);
    const ushort* sp = src + lane * 2;
    float ax = 0.f, ay = 0.f;
    int p = s;
    for (; p + 8 <= e; p += 8) {
        int r0 = list[p + 0], r1 = list[p + 1], r2 = list[p + 2], r3 = list[p + 3];
        int r4 = list[p + 4], r5 = list[p + 5], r6 = list[p + 6], r7 = list[p + 7];
        uint t0 = *(const uint*)(sp + (size_t)r0 * D);
        uint t1 = *(const uint*)(sp + (size_t)r1 * D);
        uint t2 = *(const uint*)(sp + (size_t)r2 * D);
        uint t3 = *(const uint*)(sp + (size_t)r3 * D);
        uint t4 = *(const uint*)(sp + (size_t)r4 * D);
        uint t5 = *(const uint*)(sp + (size_t)r5 * D);
        uint t6 = *(const uint*)(sp + (size_t)r6 * D);
        uint t7 = *(const uint*)(sp + (size_t)r7 * D);
        ax += bflo(t0) + bflo(t1) + bflo(t2) + bflo(t3)
            + bflo(t4) + bflo(t5) + bflo(t6) + bflo(t7);
        ay += bfhi(t0) + bfhi(t1) + bfhi(t2) + bfhi(t3)
            + bfhi(t4) + bfhi(t5) + bfhi(t6) + bfhi(t7);
    }
    for (; p < e; ++p) {
        uint t = *(const uint*)(sp + (size_t)list[p] * D);
        ax += bflo(t);
        ay += bfhi(t);
    }
    float rc = recip[seg];
    uint o = ((uint)f2bf(ay * rc) << 16) | (uint)f2bf(ax * rc);
    *(uint*)(out + (size_t)seg * D + lane * 2) = o;
}

// ---------------------------------------------------------------- bf16 MFMA GEMM
__launch_bounds__(256)
__global__ void gemm_bf16(const ushort* __restrict__ A, const ushort* __restrict__ W,
                          const float* __restrict__ bias, const ushort* __restrict__ extra,
                          ushort* __restrict__ C, int M, int N, int K) {
    __shared__ union {
        struct { ushort A[64][40]; ushort B[64][40]; } ab;
        float Cs[64][68];
    } sm;

    const int tid = threadIdx.x;
    const int rowBase = blockIdx.x * 64;
    const int colBase = blockIdx.y * 64;
    const int w = tid >> 6, lane = tid & 63;
    const int quad = lane >> 4, mrow = lane & 15;

    floatx4 acc[4] = {{0,0,0,0},{0,0,0,0},{0,0,0,0},{0,0,0,0}};

    const int lrow = tid >> 2;
    const int lkc  = (tid & 3) << 3;
    const int grow = rowBase + lrow;

    for (int k0 = 0; k0 < K; k0 += 32) {
        uint4 av = make_uint4(0, 0, 0, 0);
        if (grow < M) av = *(const uint4*)(A + (size_t)grow * K + k0 + lkc);
        uint4 wv = *(const uint4*)(W + (size_t)(colBase + lrow) * K + k0 + lkc);
        __syncthreads();
        *(uint4*)&sm.ab.A[lrow][lkc] = av;
        *(uint4*)&sm.ab.B[lrow][lkc] = wv;
        __syncthreads();
        short8 af = *(const short8*)&sm.ab.A[w * 16 + mrow][quad * 8];
        #pragma unroll
        for (int t = 0; t < 4; ++t) {
            short8 bfr = *(const short8*)&sm.ab.B[t * 16 + mrow][quad * 8];
            acc[t] = __builtin_amdgcn_mfma_f32_16x16x32_bf16(af, bfr, acc[t], 0, 0, 0);
        }
    }

    __syncthreads();
    #pragma unroll
    for (int t = 0; t < 4; ++t)
        #pragma unroll
        for (int r = 0; r < 4; ++r)
            sm.Cs[w * 16 + quad * 4 + r][t * 16 + mrow] = acc[t][r];
    __syncthreads();

    const int orow  = tid >> 2;
    const int c0    = (tid & 3) << 4;
    const int growo = rowBase + orow;
    if (growo < M) {
        const int gcol = colBase + c0;
        float bj[16];
        #pragma unroll
        for (int j4 = 0; j4 < 4; ++j4)
            *(float4*)&bj[j4 * 4] = *(const float4*)(bias + gcol + j4 * 4);
        float ex[16];
        #pragma unroll
        for (int j = 0; j < 16; ++j) ex[j] = 0.f;
        if (extra) {
            const ushort* ep = extra + (size_t)growo * N + gcol;
            uint4 e0 = *(const uint4*)ep;
            uint4 e1 = *(const uint4*)(ep + 8);
            uint eu[8] = {e0.x, e0.y, e0.z, e0.w, e1.x, e1.y, e1.z, e1.w};
            #pragma unroll
            for (int q = 0; q < 8; ++q) {
                ex[q * 2 + 0] = bflo(eu[q]);
                ex[q * 2 + 1] = bfhi(eu[q]);
            }
        }
        union { ushort u16[16]; uint4 u4[2]; } ov;
        #pragma unroll
        for (int j = 0; j < 16; ++j) {
            float v = sm.Cs[orow][c0 + j] + bj[j] + ex[j];
            ov.u16[j] = f2bf(fmaxf(v, 0.f));
        }
        ushort* cp = C + (size_t)growo * N + gcol;
        *(uint4*)cp = ov.u4[0];
        *(uint4*)(cp + 8) = ov.u4[1];
    }
}

// ---------------------------------------------------------------- head
__global__ void head_kernel(const ushort* __restrict__ h,
                            const float* __restrict__ Wa,
                            const float* __restrict__ ba,
                            float* __restrict__ out) {
    int wid  = (int)(((long long)blockIdx.x * blockDim.x + threadIdx.x) >> 6);
    int lane = threadIdx.x & 63;
    if (wid >= N_NODES) return;

    uint h2 = *(const uint*)(h + (size_t)wid * D + lane * 2);
    float hx = bflo(h2), hy = bfhi(h2);
    float a[4];
    #pragma unroll
    for (int j = 0; j < 4; ++j) {
        float2 w2 = *(const float2*)(Wa + j * D + lane * 2);
        float p = hx * w2.x + hy * w2.y;
        #pragma unroll
        for (int s = 32; s > 0; s >>= 1)
            p += __shfl_xor(p, s, 64);
        a[j] = p + ba[j];
    }
    float mx = fmaxf(fmaxf(a[0], a[1]), fmaxf(a[2], a[3]));
    float se = expf(a[0] - mx) + expf(a[1] - mx) + expf(a[2] - mx) + expf(a[3] - mx);
    float lse = mx + logf(se);
    if (lane < 4)
        out[(size_t)wid * 4 + lane] = a[lane] - lse;
}

// ---------------------------------------------------------------- launch
extern "C" void kernel_launch(void* const* d_in, const int* in_sizes, int n_in,
                              void* d_out, int out_size, void* d_ws, size_t ws_size,
                              hipStream_t stream) {
    const float* x     = (const float*)d_in[0];
    const int*   v_idx = (const int*)d_in[1];
    const int*   e_idx = (const int*)d_in[2];
    const float* W1    = (const float*)d_in[3];
    const float* b1    = (const float*)d_in[4];
    const float* W2    = (const float*)d_in[5];
    const float* b2    = (const float*)d_in[6];
    const float* Wu    = (const float*)d_in[7];
    const float* bu    = (const float*)d_in[8];
    const float* Wa    = (const float*)d_in[9];
    const float* ba    = (const float*)d_in[10];
    float* out = (float*)d_out;

    char* wsp = (char*)d_ws;
    auto alloc = [&](size_t bytes) -> char* {
        char* p = wsp;
        wsp += (bytes + 255) & ~(size_t)255;
        return p;
    };

    ushort* xb     = (ushort*)alloc((size_t)N_NODES * D * 2);
    ushort* bufY   = (ushort*)alloc((size_t)N_NODES * D * 2);
    ushort* bufX   = (ushort*)alloc((size_t)N_NODES * D * 2);
    ushort* m1     = (ushort*)alloc((size_t)N_NODES * H * 2);
    ushort* e_feat = (ushort*)alloc((size_t)N_EDGES * D * 2);
    ushort* W1b    = (ushort*)alloc((size_t)H * D * 2);
    ushort* W2b    = (ushort*)alloc((size_t)D * H * 2);
    ushort* Wub    = (ushort*)alloc((size_t)D * D * 2);
    int*    e_vert = (int*)alloc((size_t)NNZ * 4);
    int*    v_edge = (int*)alloc((size_t)NNZ * 4);
    int2*   recE   = (int2*)alloc((size_t)NNZ * 8);
    int2*   recV   = (int2*)alloc((size_t)NNZ * 8);
    int*    cntE   = (int*)alloc((size_t)(NBE + NBV) * 4);   // one memset covers both
    int*    cntV   = cntE + NBE;
    int*    ptrE   = (int*)alloc((size_t)NBE * 4);
    int*    ptrV   = (int*)alloc((size_t)NBV * 4);
    int*    curE   = (int*)alloc((size_t)NBE * 4);
    int*    curV   = (int*)alloc((size_t)NBV * 4);
    int*    e_off  = (int*)alloc((size_t)(N_EDGES + 16) * 4);
    int*    v_off  = (int*)alloc((size_t)(N_NODES + 16) * 4);
    float*  erecip = (float*)alloc((size_t)N_EDGES * 4);
    float*  vrecip = (float*)alloc((size_t)N_NODES * 4);
    ushort* v_agg  = m1;   // alias: m1 dead once GEMM2 has consumed it

    const int cooBlocks = (NNZ + CHUNK - 1) / CHUNK;   // 147

    f32_to_bf16_vec<<<(N_NODES * D / 4 + 255) / 256, 256, 0, stream>>>(x, xb, N_NODES * D / 4);
    f32_to_bf16_vec<<<(H * D / 4 + 255) / 256, 256, 0, stream>>>(W1, W1b, H * D / 4);
    f32_to_bf16_vec<<<(D * H / 4 + 255) / 256, 256, 0, stream>>>(W2, W2b, D * H / 4);
    f32_to_bf16_vec<<<(D * D / 4 + 255) / 256, 256, 0, stream>>>(Wu, Wub, D * D / 4);

    // ---- bucketed CSR build ----
    hipMemsetAsync(cntE, 0, (size_t)(NBE + NBV) * 4, stream);
    bucket_hist<<<cooBlocks, 256, 0, stream>>>(v_idx, e_idx, cntE, cntV);
    bucket_scan<<<2, 512, 0, stream>>>(cntE, ptrE, curE, cntV, ptrV, curV, e_off, v_off);
    bucket_place<<<cooBlocks, 256, 0, stream>>>(v_idx, e_idx, curE, curV, recE, recV);
    bucket_final<<<NBE + NBV, 256, 0, stream>>>(recE, ptrE, recV, ptrV,
                                                e_off, erecip, e_vert,
                                                v_off, vrecip, v_edge);

    const int gridM = (N_NODES + 63) / 64;   // 782

    const ushort* h = xb;
    for (int depth = 0; depth < 2; ++depth) {
        gemm_bf16<<<dim3(gridM, H / 64), 256, 0, stream>>>(
            h, W1b, b1, nullptr, m1, N_NODES, H, D);
        gemm_bf16<<<dim3(gridM, D / 64), 256, 0, stream>>>(
            m1, W2b, b2, nullptr, bufX, N_NODES, D, H);
        gather_rows<<<(N_EDGES * 64 + 255) / 256, 256, 0, stream>>>(
            bufX, e_off, e_vert, erecip, e_feat, N_EDGES);
        gather_rows<<<(N_NODES * 64 + 255) / 256, 256, 0, stream>>>(
            e_feat, v_off, v_edge, vrecip, v_agg, N_NODES);
        ushort* hn = (depth == 0) ? bufY : bufX;
        gemm_bf16<<<dim3(gridM, D / 64), 256, 0, stream>>>(
            h, Wub, bu, v_agg, hn, N_NODES, D, D);
        h = hn;
    }

    head_kernel<<<(N_NODES * 64 + 255) / 256, 256, 0, stream>>>(h, Wa, ba, out);
}

// Round 6
// 342.213 us; speedup vs baseline: 13.2162x; 1.1391x over previous
//
#include <hip/hip_runtime.h>
#include <hip/hip_bf16.h>
#include <math.h>

#define N_NODES 50000
#define N_EDGES 25000
#define NNZ     600000
#define D       128
#define H       256

#define BW    98            // bucket width (segments per bucket)
#define NBE   256           // ceil(25000/98)
#define NBV   511           // ceil(50000/98)
#define CHUNK 4096          // COO items per block in hist/place

typedef short short8 __attribute__((ext_vector_type(8)));
typedef float floatx4 __attribute__((ext_vector_type(4)));

__device__ inline ushort f2bf(float f) {              // RNE fp32 -> bf16
    uint u = __float_as_uint(f);
    u += 0x7FFF + ((u >> 16) & 1);
    return (ushort)(u >> 16);
}
__device__ inline float bflo(uint u) { return __uint_as_float(u << 16); }
__device__ inline float bfhi(uint u) { return __uint_as_float(u & 0xffff0000u); }

// ---------------------------------------------------------------- convert
__global__ void f32_to_bf16_vec(const float* __restrict__ src, ushort* __restrict__ dst, int n4) {
    int i = blockIdx.x * blockDim.x + threadIdx.x;
    if (i < n4) {
        float4 v = ((const float4*)src)[i];
        ushort4 o;
        o.x = f2bf(v.x); o.y = f2bf(v.y); o.z = f2bf(v.z); o.w = f2bf(v.w);
        ((ushort4*)dst)[i] = o;
    }
}

// ---------------------------------------------------------------- bucketed CSR build
__global__ void bucket_hist(const int* __restrict__ v_idx, const int* __restrict__ e_idx,
                            int* __restrict__ cntE, int* __restrict__ cntV) {
    __shared__ int hE[NBE];
    __shared__ int hV[NBV];
    for (int i = threadIdx.x; i < NBE; i += 256) hE[i] = 0;
    for (int i = threadIdx.x; i < NBV; i += 256) hV[i] = 0;
    __syncthreads();
    int base = blockIdx.x * CHUNK;
    int end  = min(base + CHUNK, NNZ);
    for (int i = base + threadIdx.x; i < end; i += 256) {
        atomicAdd(&hE[e_idx[i] / BW], 1);
        atomicAdd(&hV[v_idx[i] / BW], 1);
    }
    __syncthreads();
    for (int i = threadIdx.x; i < NBE; i += 256) if (hE[i]) atomicAdd(&cntE[i], hE[i]);
    for (int i = threadIdx.x; i < NBV; i += 256) if (hV[i]) atomicAdd(&cntV[i], hV[i]);
}

__global__ void bucket_scan(const int* __restrict__ cntE, int* __restrict__ ptrE, int* __restrict__ curE,
                            const int* __restrict__ cntV, int* __restrict__ ptrV, int* __restrict__ curV,
                            int* __restrict__ e_off, int* __restrict__ v_off) {
    __shared__ int s[512];
    int n = (blockIdx.x == 0) ? NBE : NBV;
    const int* cnt = (blockIdx.x == 0) ? cntE : cntV;
    int* ptr = (blockIdx.x == 0) ? ptrE : ptrV;
    int* cur = (blockIdx.x == 0) ? curE : curV;
    int t = threadIdx.x;
    int v = (t < n) ? cnt[t] : 0;
    s[t] = v;
    __syncthreads();
    for (int d = 1; d < 512; d <<= 1) {
        int u = (t >= d) ? s[t - d] : 0;
        __syncthreads();
        s[t] += u;
        __syncthreads();
    }
    if (t < n) {
        int ex = s[t] - v;
        ptr[t] = ex;
        cur[t] = ex;
    }
    if (t == 0) {
        if (blockIdx.x == 0) e_off[N_EDGES] = NNZ;
        else                 v_off[N_NODES] = NNZ;
    }
}

__global__ void bucket_place(const int* __restrict__ v_idx, const int* __restrict__ e_idx,
                             int* __restrict__ curE, int* __restrict__ curV,
                             int2* __restrict__ recE, int2* __restrict__ recV) {
    __shared__ int hE[NBE], hV[NBV];
    __shared__ int rE[NBE], rV[NBV];
    for (int i = threadIdx.x; i < NBE; i += 256) hE[i] = 0;
    for (int i = threadIdx.x; i < NBV; i += 256) hV[i] = 0;
    __syncthreads();
    int base = blockIdx.x * CHUNK;
    int end  = min(base + CHUNK, NNZ);
    int myE[16], myV[16];
    #pragma unroll
    for (int j = 0; j < 16; ++j) {
        int i = base + threadIdx.x + j * 256;
        myE[j] = -1; myV[j] = -1;
        if (i < end) {
            myE[j] = e_idx[i];
            myV[j] = v_idx[i];
            atomicAdd(&hE[myE[j] / BW], 1);
            atomicAdd(&hV[myV[j] / BW], 1);
        }
    }
    __syncthreads();
    for (int i = threadIdx.x; i < NBE; i += 256) {
        int c = hE[i];
        rE[i] = c ? atomicAdd(&curE[i], c) : 0;
    }
    for (int i = threadIdx.x; i < NBV; i += 256) {
        int c = hV[i];
        rV[i] = c ? atomicAdd(&curV[i], c) : 0;
    }
    __syncthreads();
    for (int i = threadIdx.x; i < NBE; i += 256) hE[i] = 0;
    for (int i = threadIdx.x; i < NBV; i += 256) hV[i] = 0;
    __syncthreads();
    #pragma unroll
    for (int j = 0; j < 16; ++j) {
        if (myE[j] >= 0) {
            int bk = myE[j] / BW;
            int p = rE[bk] + atomicAdd(&hE[bk], 1);
            recE[p] = make_int2(myE[j], myV[j]);
            bk = myV[j] / BW;
            p = rV[bk] + atomicAdd(&hV[bk], 1);
            recV[p] = make_int2(myV[j], myE[j]);
        }
    }
}

__global__ void bucket_final(const int2* __restrict__ recE, const int* __restrict__ ptrE,
                             const int2* __restrict__ recV, const int* __restrict__ ptrV,
                             int* __restrict__ e_off, float* __restrict__ erecip, int* __restrict__ e_vert,
                             int* __restrict__ v_off, float* __restrict__ vrecip, int* __restrict__ v_edge) {
    __shared__ int hist[BW], scn[BW], cur[BW];
    const bool eSide = blockIdx.x < NBE;
    const int b = eSide ? blockIdx.x : blockIdx.x - NBE;
    const int2* rec = eSide ? recE : recV;
    const int* ptr  = eSide ? ptrE : ptrV;
    const int nseg  = eSide ? N_EDGES : N_NODES;
    const int nb    = eSide ? NBE : NBV;
    int* off        = eSide ? e_off : v_off;
    float* recip    = eSide ? erecip : vrecip;
    int* outv       = eSide ? e_vert : v_edge;

    const int s = ptr[b];
    const int e = (b + 1 < nb) ? ptr[b + 1] : NNZ;
    const int k0 = b * BW;

    for (int i = threadIdx.x; i < BW; i += 256) hist[i] = 0;
    __syncthreads();
    for (int i = s + threadIdx.x; i < e; i += 256)
        atomicAdd(&hist[rec[i].x - k0], 1);
    __syncthreads();

    if (threadIdx.x < 64) {
        int lane = threadIdx.x;
        int v0 = hist[lane];
        int a = v0;
        #pragma unroll
        for (int d = 1; d < 64; d <<= 1) {
            int u = __shfl_up(a, d, 64);
            if (lane >= d) a += u;
        }
        scn[lane] = a - v0;
        int tot0 = __shfl(a, 63, 64);
        int v1 = (lane < BW - 64) ? hist[64 + lane] : 0;
        int a1 = v1;
        #pragma unroll
        for (int d = 1; d < 64; d <<= 1) {
            int u = __shfl_up(a1, d, 64);
            if (lane >= d) a1 += u;
        }
        if (lane < BW - 64) scn[64 + lane] = tot0 + a1 - v1;
    }
    __syncthreads();

    for (int i = threadIdx.x; i < BW; i += 256) {
        int seg = k0 + i;
        if (seg < nseg) {
            off[seg] = s + scn[i];
            recip[seg] = 1.0f / (float)max(hist[i], 1);
        }
        cur[i] = scn[i];
    }
    __syncthreads();
    for (int i = s + threadIdx.x; i < e; i += 256) {
        int2 r = rec[i];
        int p = s + atomicAdd(&cur[r.x - k0], 1);
        outv[p] = r.y;
    }
}

// ---------------------------------------------------------------- gather (bf16 rows)
__global__ void gather_rows(const ushort* __restrict__ src,
                            const int* __restrict__ off,
                            const int* __restrict__ list,
                            const float* __restrict__ recip,
                            ushort* __restrict__ out, int nseg) {
    int seg  = (int)(((long long)blockIdx.x * blockDim.x + threadIdx.x) >> 6);
    int lane = threadIdx.x & 63;
    if (seg >= nseg) return;
    int s = __builtin_amdgcn_readfirstlane(off[seg]);
    int e = __builtin_amdgcn_readfirstlane(off[seg + 1]);
    const ushort* sp = src + lane * 2;
    float ax = 0.f, ay = 0.f;
    int p = s;
    for (; p + 8 <= e; p += 8) {
        int r0 = list[p + 0], r1 = list[p + 1], r2 = list[p + 2], r3 = list[p + 3];
        int r4 = list[p + 4], r5 = list[p + 5], r6 = list[p + 6], r7 = list[p + 7];
        uint t0 = *(const uint*)(sp + (size_t)r0 * D);
        uint t1 = *(const uint*)(sp + (size_t)r1 * D);
        uint t2 = *(const uint*)(sp + (size_t)r2 * D);
        uint t3 = *(const uint*)(sp + (size_t)r3 * D);
        uint t4 = *(const uint*)(sp + (size_t)r4 * D);
        uint t5 = *(const uint*)(sp + (size_t)r5 * D);
        uint t6 = *(const uint*)(sp + (size_t)r6 * D);
        uint t7 = *(const uint*)(sp + (size_t)r7 * D);
        ax += bflo(t0) + bflo(t1) + bflo(t2) + bflo(t3)
            + bflo(t4) + bflo(t5) + bflo(t6) + bflo(t7);
        ay += bfhi(t0) + bfhi(t1) + bfhi(t2) + bfhi(t3)
            + bfhi(t4) + bfhi(t5) + bfhi(t6) + bfhi(t7);
    }
    for (; p < e; ++p) {
        uint t = *(const uint*)(sp + (size_t)list[p] * D);
        ax += bflo(t);
        ay += bfhi(t);
    }
    float rc = recip[seg];
    uint o = ((uint)f2bf(ay * rc) << 16) | (uint)f2bf(ax * rc);
    *(uint*)(out + (size_t)seg * D + lane * 2) = o;
}

// ---------------------------------------------------------------- fused MLP
// m2 = relu(relu(h @ W1^T + b1) @ W2^T + b2), per 64-row block; m1 lives in LDS.
__launch_bounds__(256)
__global__ void mlp_fused(const ushort* __restrict__ A,   // [M,128] bf16
                          const ushort* __restrict__ W1,  // [256,128] bf16
                          const float* __restrict__ b1,
                          const ushort* __restrict__ W2,  // [128,256] bf16
                          const float* __restrict__ b2,
                          ushort* __restrict__ m2out,     // [M,128] bf16
                          int M) {
    __shared__ ushort Af[64][136];    // A tile 64x128 (+8 pad)
    __shared__ ushort Bs[64][40];     // weight staging 64x32 (+8 pad)
    __shared__ ushort m1s[64][264];   // m1 tile 64x256 (+8 pad)
    __shared__ float  Cs[64][68];     // phase-B epilogue

    const int tid = threadIdx.x;
    const int w = tid >> 6, lane = tid & 63;
    const int quad = lane >> 4, mrow = lane & 15;
    const int rowBase = blockIdx.x * 64;

    // ---- stage full A tile (64x128) ----
    #pragma unroll
    for (int r = 0; r < 4; ++r) {
        int idx = tid + r * 256;          // 0..1023
        int row = idx >> 4;               // 0..63
        int c   = (idx & 15) << 3;        // 0,8,...,120
        uint4 av = make_uint4(0, 0, 0, 0);
        if (rowBase + row < M)
            av = *(const uint4*)(A + (size_t)(rowBase + row) * D + c);
        *(uint4*)&Af[row][c] = av;
    }

    const int scol = tid >> 2;            // 0..63 (staging row)
    const int skk  = (tid & 3) << 3;      // 0,8,16,24

    // ---- phase A: m1 = relu(A @ W1^T + b1), held in LDS ----
    for (int n0 = 0; n0 < H; n0 += 64) {
        floatx4 acc[4] = {{0,0,0,0},{0,0,0,0},{0,0,0,0},{0,0,0,0}};
        for (int k0 = 0; k0 < D; k0 += 32) {
            __syncthreads();
            *(uint4*)&Bs[scol][skk] = *(const uint4*)(W1 + (size_t)(n0 + scol) * D + k0 + skk);
            __syncthreads();
            short8 af = *(const short8*)&Af[w * 16 + mrow][k0 + quad * 8];
            #pragma unroll
            for (int t = 0; t < 4; ++t) {
                short8 bfr = *(const short8*)&Bs[t * 16 + mrow][quad * 8];
                acc[t] = __builtin_amdgcn_mfma_f32_16x16x32_bf16(af, bfr, acc[t], 0, 0, 0);
            }
        }
        #pragma unroll
        for (int t = 0; t < 4; ++t) {
            float bb = b1[n0 + t * 16 + mrow];
            #pragma unroll
            for (int r = 0; r < 4; ++r) {
                float v = acc[t][r] + bb;
                m1s[w * 16 + quad * 4 + r][n0 + t * 16 + mrow] = f2bf(fmaxf(v, 0.f));
            }
        }
    }
    __syncthreads();   // m1s complete

    // ---- phase B: m2 = relu(m1 @ W2^T + b2) ----
    for (int n0 = 0; n0 < D; n0 += 64) {
        floatx4 acc[4] = {{0,0,0,0},{0,0,0,0},{0,0,0,0},{0,0,0,0}};
        for (int k0 = 0; k0 < H; k0 += 32) {
            __syncthreads();
            *(uint4*)&Bs[scol][skk] = *(const uint4*)(W2 + (size_t)(n0 + scol) * H + k0 + skk);
            __syncthreads();
            short8 af = *(const short8*)&m1s[w * 16 + mrow][k0 + quad * 8];
            #pragma unroll
            for (int t = 0; t < 4; ++t) {
                short8 bfr = *(const short8*)&Bs[t * 16 + mrow][quad * 8];
                acc[t] = __builtin_amdgcn_mfma_f32_16x16x32_bf16(af, bfr, acc[t], 0, 0, 0);
            }
        }
        __syncthreads();
        #pragma unroll
        for (int t = 0; t < 4; ++t)
            #pragma unroll
            for (int r = 0; r < 4; ++r)
                Cs[w * 16 + quad * 4 + r][t * 16 + mrow] = acc[t][r];
        __syncthreads();

        const int orow = tid >> 2;
        const int c0   = (tid & 3) << 4;
        if (rowBase + orow < M) {
            union { ushort u16[16]; uint4 u4[2]; } ov;
            #pragma unroll
            for (int j4 = 0; j4 < 4; ++j4) {
                float4 bb = *(const float4*)(b2 + n0 + c0 + j4 * 4);
                float bjv[4] = {bb.x, bb.y, bb.z, bb.w};
                #pragma unroll
                for (int j = 0; j < 4; ++j) {
                    float v = Cs[orow][c0 + j4 * 4 + j] + bjv[j];
                    ov.u16[j4 * 4 + j] = f2bf(fmaxf(v, 0.f));
                }
            }
            ushort* cp = m2out + (size_t)(rowBase + orow) * D + n0 + c0;
            *(uint4*)cp = ov.u4[0];
            *(uint4*)(cp + 8) = ov.u4[1];
        }
    }
}

// ---------------------------------------------------------------- bf16 MFMA GEMM (Wu + aggregate)
__launch_bounds__(256)
__global__ void gemm_bf16(const ushort* __restrict__ A, const ushort* __restrict__ W,
                          const float* __restrict__ bias, const ushort* __restrict__ extra,
                          ushort* __restrict__ C, int M, int N, int K) {
    __shared__ union {
        struct { ushort A[64][40]; ushort B[64][40]; } ab;
        float Cs[64][68];
    } sm;

    const int tid = threadIdx.x;
    const int rowBase = blockIdx.x * 64;
    const int colBase = blockIdx.y * 64;
    const int w = tid >> 6, lane = tid & 63;
    const int quad = lane >> 4, mrow = lane & 15;

    floatx4 acc[4] = {{0,0,0,0},{0,0,0,0},{0,0,0,0},{0,0,0,0}};

    const int lrow = tid >> 2;
    const int lkc  = (tid & 3) << 3;
    const int grow = rowBase + lrow;

    for (int k0 = 0; k0 < K; k0 += 32) {
        uint4 av = make_uint4(0, 0, 0, 0);
        if (grow < M) av = *(const uint4*)(A + (size_t)grow * K + k0 + lkc);
        uint4 wv = *(const uint4*)(W + (size_t)(colBase + lrow) * K + k0 + lkc);
        __syncthreads();
        *(uint4*)&sm.ab.A[lrow][lkc] = av;
        *(uint4*)&sm.ab.B[lrow][lkc] = wv;
        __syncthreads();
        short8 af = *(const short8*)&sm.ab.A[w * 16 + mrow][quad * 8];
        #pragma unroll
        for (int t = 0; t < 4; ++t) {
            short8 bfr = *(const short8*)&sm.ab.B[t * 16 + mrow][quad * 8];
            acc[t] = __builtin_amdgcn_mfma_f32_16x16x32_bf16(af, bfr, acc[t], 0, 0, 0);
        }
    }

    __syncthreads();
    #pragma unroll
    for (int t = 0; t < 4; ++t)
        #pragma unroll
        for (int r = 0; r < 4; ++r)
            sm.Cs[w * 16 + quad * 4 + r][t * 16 + mrow] = acc[t][r];
    __syncthreads();

    const int orow  = tid >> 2;
    const int c0    = (tid & 3) << 4;
    const int growo = rowBase + orow;
    if (growo < M) {
        const int gcol = colBase + c0;
        float bj[16];
        #pragma unroll
        for (int j4 = 0; j4 < 4; ++j4)
            *(float4*)&bj[j4 * 4] = *(const float4*)(bias + gcol + j4 * 4);
        float ex[16];
        #pragma unroll
        for (int j = 0; j < 16; ++j) ex[j] = 0.f;
        if (extra) {
            const ushort* ep = extra + (size_t)growo * N + gcol;
            uint4 e0 = *(const uint4*)ep;
            uint4 e1 = *(const uint4*)(ep + 8);
            uint eu[8] = {e0.x, e0.y, e0.z, e0.w, e1.x, e1.y, e1.z, e1.w};
            #pragma unroll
            for (int q = 0; q < 8; ++q) {
                ex[q * 2 + 0] = bflo(eu[q]);
                ex[q * 2 + 1] = bfhi(eu[q]);
            }
        }
        union { ushort u16[16]; uint4 u4[2]; } ov;
        #pragma unroll
        for (int j = 0; j < 16; ++j) {
            float v = sm.Cs[orow][c0 + j] + bj[j] + ex[j];
            ov.u16[j] = f2bf(fmaxf(v, 0.f));
        }
        ushort* cp = C + (size_t)growo * N + gcol;
        *(uint4*)cp = ov.u4[0];
        *(uint4*)(cp + 8) = ov.u4[1];
    }
}

// ---------------------------------------------------------------- head
__global__ void head_kernel(const ushort* __restrict__ h,
                            const float* __restrict__ Wa,
                            const float* __restrict__ ba,
                            float* __restrict__ out) {
    int wid  = (int)(((long long)blockIdx.x * blockDim.x + threadIdx.x) >> 6);
    int lane = threadIdx.x & 63;
    if (wid >= N_NODES) return;

    uint h2 = *(const uint*)(h + (size_t)wid * D + lane * 2);
    float hx = bflo(h2), hy = bfhi(h2);
    float a[4];
    #pragma unroll
    for (int j = 0; j < 4; ++j) {
        float2 w2 = *(const float2*)(Wa + j * D + lane * 2);
        float p = hx * w2.x + hy * w2.y;
        #pragma unroll
        for (int s = 32; s > 0; s >>= 1)
            p += __shfl_xor(p, s, 64);
        a[j] = p + ba[j];
    }
    float mx = fmaxf(fmaxf(a[0], a[1]), fmaxf(a[2], a[3]));
    float se = expf(a[0] - mx) + expf(a[1] - mx) + expf(a[2] - mx) + expf(a[3] - mx);
    float lse = mx + logf(se);
    if (lane < 4)
        out[(size_t)wid * 4 + lane] = a[lane] - lse;
}

// ---------------------------------------------------------------- launch
extern "C" void kernel_launch(void* const* d_in, const int* in_sizes, int n_in,
                              void* d_out, int out_size, void* d_ws, size_t ws_size,
                              hipStream_t stream) {
    const float* x     = (const float*)d_in[0];
    const int*   v_idx = (const int*)d_in[1];
    const int*   e_idx = (const int*)d_in[2];
    const float* W1    = (const float*)d_in[3];
    const float* b1    = (const float*)d_in[4];
    const float* W2    = (const float*)d_in[5];
    const float* b2    = (const float*)d_in[6];
    const float* Wu    = (const float*)d_in[7];
    const float* bu    = (const float*)d_in[8];
    const float* Wa    = (const float*)d_in[9];
    const float* ba    = (const float*)d_in[10];
    float* out = (float*)d_out;

    char* wsp = (char*)d_ws;
    auto alloc = [&](size_t bytes) -> char* {
        char* p = wsp;
        wsp += (bytes + 255) & ~(size_t)255;
        return p;
    };

    ushort* xb     = (ushort*)alloc((size_t)N_NODES * D * 2);
    ushort* bufY   = (ushort*)alloc((size_t)N_NODES * D * 2);
    ushort* bufX   = (ushort*)alloc((size_t)N_NODES * D * 2);
    ushort* v_agg  = (ushort*)alloc((size_t)N_NODES * D * 2);
    ushort* e_feat = (ushort*)alloc((size_t)N_EDGES * D * 2);
    ushort* W1b    = (ushort*)alloc((size_t)H * D * 2);
    ushort* W2b    = (ushort*)alloc((size_t)D * H * 2);
    ushort* Wub    = (ushort*)alloc((size_t)D * D * 2);
    int*    e_vert = (int*)alloc((size_t)NNZ * 4);
    int*    v_edge = (int*)alloc((size_t)NNZ * 4);
    int2*   recE   = (int2*)alloc((size_t)NNZ * 8);
    int2*   recV   = (int2*)alloc((size_t)NNZ * 8);
    int*    cntE   = (int*)alloc((size_t)(NBE + NBV) * 4);
    int*    cntV   = cntE + NBE;
    int*    ptrE   = (int*)alloc((size_t)NBE * 4);
    int*    ptrV   = (int*)alloc((size_t)NBV * 4);
    int*    curE   = (int*)alloc((size_t)NBE * 4);
    int*    curV   = (int*)alloc((size_t)NBV * 4);
    int*    e_off  = (int*)alloc((size_t)(N_EDGES + 16) * 4);
    int*    v_off  = (int*)alloc((size_t)(N_NODES + 16) * 4);
    float*  erecip = (float*)alloc((size_t)N_EDGES * 4);
    float*  vrecip = (float*)alloc((size_t)N_NODES * 4);

    const int cooBlocks = (NNZ + CHUNK - 1) / CHUNK;   // 147

    f32_to_bf16_vec<<<(N_NODES * D / 4 + 255) / 256, 256, 0, stream>>>(x, xb, N_NODES * D / 4);
    f32_to_bf16_vec<<<(H * D / 4 + 255) / 256, 256, 0, stream>>>(W1, W1b, H * D / 4);
    f32_to_bf16_vec<<<(D * H / 4 + 255) / 256, 256, 0, stream>>>(W2, W2b, D * H / 4);
    f32_to_bf16_vec<<<(D * D / 4 + 255) / 256, 256, 0, stream>>>(Wu, Wub, D * D / 4);

    // ---- bucketed CSR build ----
    hipMemsetAsync(cntE, 0, (size_t)(NBE + NBV) * 4, stream);
    bucket_hist<<<cooBlocks, 256, 0, stream>>>(v_idx, e_idx, cntE, cntV);
    bucket_scan<<<2, 512, 0, stream>>>(cntE, ptrE, curE, cntV, ptrV, curV, e_off, v_off);
    bucket_place<<<cooBlocks, 256, 0, stream>>>(v_idx, e_idx, curE, curV, recE, recV);
    bucket_final<<<NBE + NBV, 256, 0, stream>>>(recE, ptrE, recV, ptrV,
                                                e_off, erecip, e_vert,
                                                v_off, vrecip, v_edge);

    const int gridM = (N_NODES + 63) / 64;   // 782

    const ushort* h = xb;
    for (int depth = 0; depth < 2; ++depth) {
        // m2 = relu(relu(h@W1^T+b1)@W2^T+b2), m1 never leaves LDS
        mlp_fused<<<gridM, 256, 0, stream>>>(h, W1b, b1, W2b, b2, bufX, N_NODES);
        gather_rows<<<(N_EDGES * 64 + 255) / 256, 256, 0, stream>>>(
            bufX, e_off, e_vert, erecip, e_feat, N_EDGES);
        gather_rows<<<(N_NODES * 64 + 255) / 256, 256, 0, stream>>>(
            e_feat, v_off, v_edge, vrecip, v_agg, N_NODES);
        ushort* hn = (depth == 0) ? bufY : bufX;
        gemm_bf16<<<dim3(gridM, D / 64), 256, 0, stream>>>(
            h, Wub, bu, v_agg, hn, N_NODES, D, D);
        h = hn;
    }

    head_kernel<<<(N_NODES * 64 + 255) / 256, 256, 0, stream>>>(h, Wa, ba, out);
}

// Round 7
// 330.017 us; speedup vs baseline: 13.7046x; 1.0370x over previous
//
#include <hip/hip_runtime.h>
#include <hip/hip_bf16.h>
#include <math.h>

#define N_NODES 50000
#define N_EDGES 25000
#define NNZ     600000
#define D       128
#define H       256

#define BW    98            // bucket width (segments per bucket)
#define NBE   256           // ceil(25000/98)
#define NBV   511           // ceil(50000/98)
#define CHUNK 4096          // COO items per block in hist/place

typedef short short8 __attribute__((ext_vector_type(8)));
typedef float floatx4 __attribute__((ext_vector_type(4)));

__device__ inline ushort f2bf(float f) {              // RNE fp32 -> bf16
    uint u = __float_as_uint(f);
    u += 0x7FFF + ((u >> 16) & 1);
    return (ushort)(u >> 16);
}
__device__ inline float bflo(uint u) { return __uint_as_float(u << 16); }
__device__ inline float bfhi(uint u) { return __uint_as_float(u & 0xffff0000u); }

// ---------------------------------------------------------------- convert
__global__ void f32_to_bf16_vec(const float* __restrict__ src, ushort* __restrict__ dst, int n4) {
    int i = blockIdx.x * blockDim.x + threadIdx.x;
    if (i < n4) {
        float4 v = ((const float4*)src)[i];
        ushort4 o;
        o.x = f2bf(v.x); o.y = f2bf(v.y); o.z = f2bf(v.z); o.w = f2bf(v.w);
        ((ushort4*)dst)[i] = o;
    }
}

// ---------------------------------------------------------------- bucketed CSR build
__global__ void bucket_hist(const int* __restrict__ v_idx, const int* __restrict__ e_idx,
                            int* __restrict__ cntE, int* __restrict__ cntV) {
    __shared__ int hE[NBE];
    __shared__ int hV[NBV];
    for (int i = threadIdx.x; i < NBE; i += 256) hE[i] = 0;
    for (int i = threadIdx.x; i < NBV; i += 256) hV[i] = 0;
    __syncthreads();
    int base = blockIdx.x * CHUNK;
    int end  = min(base + CHUNK, NNZ);
    for (int i = base + threadIdx.x; i < end; i += 256) {
        atomicAdd(&hE[e_idx[i] / BW], 1);
        atomicAdd(&hV[v_idx[i] / BW], 1);
    }
    __syncthreads();
    for (int i = threadIdx.x; i < NBE; i += 256) if (hE[i]) atomicAdd(&cntE[i], hE[i]);
    for (int i = threadIdx.x; i < NBV; i += 256) if (hV[i]) atomicAdd(&cntV[i], hV[i]);
}

__global__ void bucket_scan(const int* __restrict__ cntE, int* __restrict__ ptrE, int* __restrict__ curE,
                            const int* __restrict__ cntV, int* __restrict__ ptrV, int* __restrict__ curV,
                            int* __restrict__ e_off, int* __restrict__ v_off) {
    __shared__ int s[512];
    int n = (blockIdx.x == 0) ? NBE : NBV;
    const int* cnt = (blockIdx.x == 0) ? cntE : cntV;
    int* ptr = (blockIdx.x == 0) ? ptrE : ptrV;
    int* cur = (blockIdx.x == 0) ? curE : curV;
    int t = threadIdx.x;
    int v = (t < n) ? cnt[t] : 0;
    s[t] = v;
    __syncthreads();
    for (int d = 1; d < 512; d <<= 1) {
        int u = (t >= d) ? s[t - d] : 0;
        __syncthreads();
        s[t] += u;
        __syncthreads();
    }
    if (t < n) {
        int ex = s[t] - v;
        ptr[t] = ex;
        cur[t] = ex;
    }
    if (t == 0) {
        if (blockIdx.x == 0) e_off[N_EDGES] = NNZ;
        else                 v_off[N_NODES] = NNZ;
    }
}

__global__ void bucket_place(const int* __restrict__ v_idx, const int* __restrict__ e_idx,
                             int* __restrict__ curE, int* __restrict__ curV,
                             int2* __restrict__ recE, int2* __restrict__ recV) {
    __shared__ int hE[NBE], hV[NBV];
    __shared__ int rE[NBE], rV[NBV];
    for (int i = threadIdx.x; i < NBE; i += 256) hE[i] = 0;
    for (int i = threadIdx.x; i < NBV; i += 256) hV[i] = 0;
    __syncthreads();
    int base = blockIdx.x * CHUNK;
    int end  = min(base + CHUNK, NNZ);
    int myE[16], myV[16];
    #pragma unroll
    for (int j = 0; j < 16; ++j) {
        int i = base + threadIdx.x + j * 256;
        myE[j] = -1; myV[j] = -1;
        if (i < end) {
            myE[j] = e_idx[i];
            myV[j] = v_idx[i];
            atomicAdd(&hE[myE[j] / BW], 1);
            atomicAdd(&hV[myV[j] / BW], 1);
        }
    }
    __syncthreads();
    for (int i = threadIdx.x; i < NBE; i += 256) {
        int c = hE[i];
        rE[i] = c ? atomicAdd(&curE[i], c) : 0;
    }
    for (int i = threadIdx.x; i < NBV; i += 256) {
        int c = hV[i];
        rV[i] = c ? atomicAdd(&curV[i], c) : 0;
    }
    __syncthreads();
    for (int i = threadIdx.x; i < NBE; i += 256) hE[i] = 0;
    for (int i = threadIdx.x; i < NBV; i += 256) hV[i] = 0;
    __syncthreads();
    #pragma unroll
    for (int j = 0; j < 16; ++j) {
        if (myE[j] >= 0) {
            int bk = myE[j] / BW;
            int p = rE[bk] + atomicAdd(&hE[bk], 1);
            recE[p] = make_int2(myE[j], myV[j]);
            bk = myV[j] / BW;
            p = rV[bk] + atomicAdd(&hV[bk], 1);
            recV[p] = make_int2(myV[j], myE[j]);
        }
    }
}

__global__ void bucket_final(const int2* __restrict__ recE, const int* __restrict__ ptrE,
                             const int2* __restrict__ recV, const int* __restrict__ ptrV,
                             int* __restrict__ e_off, float* __restrict__ erecip, int* __restrict__ e_vert,
                             int* __restrict__ v_off, float* __restrict__ vrecip, int* __restrict__ v_edge) {
    __shared__ int hist[BW], scn[BW], cur[BW];
    const bool eSide = blockIdx.x < NBE;
    const int b = eSide ? blockIdx.x : blockIdx.x - NBE;
    const int2* rec = eSide ? recE : recV;
    const int* ptr  = eSide ? ptrE : ptrV;
    const int nseg  = eSide ? N_EDGES : N_NODES;
    const int nb    = eSide ? NBE : NBV;
    int* off        = eSide ? e_off : v_off;
    float* recip    = eSide ? erecip : vrecip;
    int* outv       = eSide ? e_vert : v_edge;

    const int s = ptr[b];
    const int e = (b + 1 < nb) ? ptr[b + 1] : NNZ;
    const int k0 = b * BW;

    for (int i = threadIdx.x; i < BW; i += 256) hist[i] = 0;
    __syncthreads();
    for (int i = s + threadIdx.x; i < e; i += 256)
        atomicAdd(&hist[rec[i].x - k0], 1);
    __syncthreads();

    if (threadIdx.x < 64) {
        int lane = threadIdx.x;
        int v0 = hist[lane];
        int a = v0;
        #pragma unroll
        for (int d = 1; d < 64; d <<= 1) {
            int u = __shfl_up(a, d, 64);
            if (lane >= d) a += u;
        }
        scn[lane] = a - v0;
        int tot0 = __shfl(a, 63, 64);
        int v1 = (lane < BW - 64) ? hist[64 + lane] : 0;
        int a1 = v1;
        #pragma unroll
        for (int d = 1; d < 64; d <<= 1) {
            int u = __shfl_up(a1, d, 64);
            if (lane >= d) a1 += u;
        }
        if (lane < BW - 64) scn[64 + lane] = tot0 + a1 - v1;
    }
    __syncthreads();

    for (int i = threadIdx.x; i < BW; i += 256) {
        int seg = k0 + i;
        if (seg < nseg) {
            off[seg] = s + scn[i];
            recip[seg] = 1.0f / (float)max(hist[i], 1);
        }
        cur[i] = scn[i];
    }
    __syncthreads();
    for (int i = s + threadIdx.x; i < e; i += 256) {
        int2 r = rec[i];
        int p = s + atomicAdd(&cur[r.x - k0], 1);
        outv[p] = r.y;
    }
}

// ---------------------------------------------------------------- gather (bf16 rows, quad layout)
// one wave per segment. 16 lanes per row (uint4 = 8 features each), 4 rows per
// load round, 8-row chunks = 8 outstanding loads. Optional fused epilogue:
// out = relu(uadd + sum*recip) when uadd != nullptr, else out = sum*recip.
__global__ void gather_rows(const ushort* __restrict__ src,
                            const int* __restrict__ off,
                            const int* __restrict__ list,
                            const float* __restrict__ recip,
                            const ushort* __restrict__ uadd,
                            ushort* __restrict__ outbuf, int nseg) {
    int seg  = (int)(((long long)blockIdx.x * blockDim.x + threadIdx.x) >> 6);
    int lane = threadIdx.x & 63;
    if (seg >= nseg) return;
    const int q  = lane >> 4;       // quarter: which row of the 4
    const int ql = lane & 15;       // feature group: 8 features at ql*8
    int s = __builtin_amdgcn_readfirstlane(off[seg]);
    int e = __builtin_amdgcn_readfirstlane(off[seg + 1]);
    const ushort* sp = src + ql * 8;

    float a0 = 0.f, a1 = 0.f, a2 = 0.f, a3 = 0.f;
    float a4 = 0.f, a5 = 0.f, a6 = 0.f, a7 = 0.f;

    int p = s;
    for (; p + 8 <= e; p += 8) {
        int i0 = list[p + 0], i1 = list[p + 1], i2 = list[p + 2], i3 = list[p + 3];
        int i4 = list[p + 4], i5 = list[p + 5], i6 = list[p + 6], i7 = list[p + 7];
        int r0 = (q < 2) ? (q == 0 ? i0 : i1) : (q == 2 ? i2 : i3);
        int r1 = (q < 2) ? (q == 0 ? i4 : i5) : (q == 2 ? i6 : i7);
        uint4 t0 = *(const uint4*)(sp + (size_t)r0 * D);
        uint4 t1 = *(const uint4*)(sp + (size_t)r1 * D);
        a0 += bflo(t0.x) + bflo(t1.x);  a1 += bfhi(t0.x) + bfhi(t1.x);
        a2 += bflo(t0.y) + bflo(t1.y);  a3 += bfhi(t0.y) + bfhi(t1.y);
        a4 += bflo(t0.z) + bflo(t1.z);  a5 += bfhi(t0.z) + bfhi(t1.z);
        a6 += bflo(t0.w) + bflo(t1.w);  a7 += bfhi(t0.w) + bfhi(t1.w);
    }
    for (; p + 4 <= e; p += 4) {
        int i0 = list[p + 0], i1 = list[p + 1], i2 = list[p + 2], i3 = list[p + 3];
        int r0 = (q < 2) ? (q == 0 ? i0 : i1) : (q == 2 ? i2 : i3);
        uint4 t0 = *(const uint4*)(sp + (size_t)r0 * D);
        a0 += bflo(t0.x);  a1 += bfhi(t0.x);
        a2 += bflo(t0.y);  a3 += bfhi(t0.y);
        a4 += bflo(t0.z);  a5 += bfhi(t0.z);
        a6 += bflo(t0.w);  a7 += bfhi(t0.w);
    }
    if (p < e) {
        int rem = e - p;              // 1..3
        if (q < rem) {
            int r0 = list[p + q];
            uint4 t0 = *(const uint4*)(sp + (size_t)r0 * D);
            a0 += bflo(t0.x);  a1 += bfhi(t0.x);
            a2 += bflo(t0.y);  a3 += bfhi(t0.y);
            a4 += bflo(t0.z);  a5 += bfhi(t0.z);
            a6 += bflo(t0.w);  a7 += bfhi(t0.w);
        }
    }

    // cross-quarter reduction (quarters hold different rows, same features)
    a0 += __shfl_xor(a0, 16, 64); a0 += __shfl_xor(a0, 32, 64);
    a1 += __shfl_xor(a1, 16, 64); a1 += __shfl_xor(a1, 32, 64);
    a2 += __shfl_xor(a2, 16, 64); a2 += __shfl_xor(a2, 32, 64);
    a3 += __shfl_xor(a3, 16, 64); a3 += __shfl_xor(a3, 32, 64);
    a4 += __shfl_xor(a4, 16, 64); a4 += __shfl_xor(a4, 32, 64);
    a5 += __shfl_xor(a5, 16, 64); a5 += __shfl_xor(a5, 32, 64);
    a6 += __shfl_xor(a6, 16, 64); a6 += __shfl_xor(a6, 32, 64);
    a7 += __shfl_xor(a7, 16, 64); a7 += __shfl_xor(a7, 32, 64);

    if (q == 0) {
        float rc = recip[seg];
        float f0 = a0 * rc, f1 = a1 * rc, f2 = a2 * rc, f3 = a3 * rc;
        float f4 = a4 * rc, f5 = a5 * rc, f6 = a6 * rc, f7 = a7 * rc;
        if (uadd) {
            uint4 uv = *(const uint4*)(uadd + (size_t)seg * D + ql * 8);
            f0 = fmaxf(f0 + bflo(uv.x), 0.f);  f1 = fmaxf(f1 + bfhi(uv.x), 0.f);
            f2 = fmaxf(f2 + bflo(uv.y), 0.f);  f3 = fmaxf(f3 + bfhi(uv.y), 0.f);
            f4 = fmaxf(f4 + bflo(uv.z), 0.f);  f5 = fmaxf(f5 + bfhi(uv.z), 0.f);
            f6 = fmaxf(f6 + bflo(uv.w), 0.f);  f7 = fmaxf(f7 + bfhi(uv.w), 0.f);
        }
        uint4 o;
        o.x = ((uint)f2bf(f1) << 16) | (uint)f2bf(f0);
        o.y = ((uint)f2bf(f3) << 16) | (uint)f2bf(f2);
        o.z = ((uint)f2bf(f5) << 16) | (uint)f2bf(f4);
        o.w = ((uint)f2bf(f7) << 16) | (uint)f2bf(f6);
        *(uint4*)(outbuf + (size_t)seg * D + ql * 8) = o;
    }
}

// ---------------------------------------------------------------- fused MLP + Wu
// m2 = relu(relu(h@W1^T+b1)@W2^T+b2)  and  u = h@Wu^T+bu  (no relu),
// per 64-row block; m1 lives in LDS, h tile (Af) reused by both paths.
__launch_bounds__(256)
__global__ void mlp_fused(const ushort* __restrict__ A,   // [M,128] bf16
                          const ushort* __restrict__ W1,  // [256,128] bf16
                          const float* __restrict__ b1,
                          const ushort* __restrict__ W2,  // [128,256] bf16
                          const float* __restrict__ b2,
                          const ushort* __restrict__ Wu,  // [128,128] bf16
                          const float* __restrict__ bu,
                          ushort* __restrict__ m2out,     // [M,128] bf16
                          ushort* __restrict__ uout,      // [M,128] bf16
                          int M) {
    __shared__ ushort Af[64][136];    // A tile 64x128 (+8 pad)
    __shared__ ushort Bs[64][40];     // weight staging 64x32 (+8 pad)
    __shared__ ushort m1s[64][264];   // m1 tile 64x256 (+8 pad)
    __shared__ float  Cs[64][68];     // epilogue transpose

    const int tid = threadIdx.x;
    const int w = tid >> 6, lane = tid & 63;
    const int quad = lane >> 4, mrow = lane & 15;
    const int rowBase = blockIdx.x * 64;

    // ---- stage full A tile (64x128) ----
    #pragma unroll
    for (int r = 0; r < 4; ++r) {
        int idx = tid + r * 256;
        int row = idx >> 4;
        int c   = (idx & 15) << 3;
        uint4 av = make_uint4(0, 0, 0, 0);
        if (rowBase + row < M)
            av = *(const uint4*)(A + (size_t)(rowBase + row) * D + c);
        *(uint4*)&Af[row][c] = av;
    }

    const int scol = tid >> 2;            // 0..63 (staging row)
    const int skk  = (tid & 3) << 3;      // 0,8,16,24
    const int orow = tid >> 2;
    const int c0   = (tid & 3) << 4;

    // ---- phase A: m1 = relu(A @ W1^T + b1), held in LDS ----
    for (int n0 = 0; n0 < H; n0 += 64) {
        floatx4 acc[4] = {{0,0,0,0},{0,0,0,0},{0,0,0,0},{0,0,0,0}};
        for (int k0 = 0; k0 < D; k0 += 32) {
            __syncthreads();
            *(uint4*)&Bs[scol][skk] = *(const uint4*)(W1 + (size_t)(n0 + scol) * D + k0 + skk);
            __syncthreads();
            short8 af = *(const short8*)&Af[w * 16 + mrow][k0 + quad * 8];
            #pragma unroll
            for (int t = 0; t < 4; ++t) {
                short8 bfr = *(const short8*)&Bs[t * 16 + mrow][quad * 8];
                acc[t] = __builtin_amdgcn_mfma_f32_16x16x32_bf16(af, bfr, acc[t], 0, 0, 0);
            }
        }
        #pragma unroll
        for (int t = 0; t < 4; ++t) {
            float bb = b1[n0 + t * 16 + mrow];
            #pragma unroll
            for (int r = 0; r < 4; ++r) {
                float v = acc[t][r] + bb;
                m1s[w * 16 + quad * 4 + r][n0 + t * 16 + mrow] = f2bf(fmaxf(v, 0.f));
            }
        }
    }

    // ---- phase C: u = A @ Wu^T + bu (no relu), uses Af ----
    for (int n0 = 0; n0 < D; n0 += 64) {
        floatx4 acc[4] = {{0,0,0,0},{0,0,0,0},{0,0,0,0},{0,0,0,0}};
        for (int k0 = 0; k0 < D; k0 += 32) {
            __syncthreads();
            *(uint4*)&Bs[scol][skk] = *(const uint4*)(Wu + (size_t)(n0 + scol) * D + k0 + skk);
            __syncthreads();
            short8 af = *(const short8*)&Af[w * 16 + mrow][k0 + quad * 8];
            #pragma unroll
            for (int t = 0; t < 4; ++t) {
                short8 bfr = *(const short8*)&Bs[t * 16 + mrow][quad * 8];
                acc[t] = __builtin_amdgcn_mfma_f32_16x16x32_bf16(af, bfr, acc[t], 0, 0, 0);
            }
        }
        __syncthreads();
        #pragma unroll
        for (int t = 0; t < 4; ++t)
            #pragma unroll
            for (int r = 0; r < 4; ++r)
                Cs[w * 16 + quad * 4 + r][t * 16 + mrow] = acc[t][r];
        __syncthreads();

        if (rowBase + orow < M) {
            union { ushort u16[16]; uint4 u4[2]; } ov;
            #pragma unroll
            for (int j4 = 0; j4 < 4; ++j4) {
                float4 bb = *(const float4*)(bu + n0 + c0 + j4 * 4);
                float bjv[4] = {bb.x, bb.y, bb.z, bb.w};
                #pragma unroll
                for (int j = 0; j < 4; ++j)
                    ov.u16[j4 * 4 + j] = f2bf(Cs[orow][c0 + j4 * 4 + j] + bjv[j]);
            }
            ushort* cp = uout + (size_t)(rowBase + orow) * D + n0 + c0;
            *(uint4*)cp = ov.u4[0];
            *(uint4*)(cp + 8) = ov.u4[1];
        }
    }

    // ---- phase B: m2 = relu(m1 @ W2^T + b2) ----
    for (int n0 = 0; n0 < D; n0 += 64) {
        floatx4 acc[4] = {{0,0,0,0},{0,0,0,0},{0,0,0,0},{0,0,0,0}};
        for (int k0 = 0; k0 < H; k0 += 32) {
            __syncthreads();
            *(uint4*)&Bs[scol][skk] = *(const uint4*)(W2 + (size_t)(n0 + scol) * H + k0 + skk);
            __syncthreads();
            short8 af = *(const short8*)&m1s[w * 16 + mrow][k0 + quad * 8];
            #pragma unroll
            for (int t = 0; t < 4; ++t) {
                short8 bfr = *(const short8*)&Bs[t * 16 + mrow][quad * 8];
                acc[t] = __builtin_amdgcn_mfma_f32_16x16x32_bf16(af, bfr, acc[t], 0, 0, 0);
            }
        }
        __syncthreads();
        #pragma unroll
        for (int t = 0; t < 4; ++t)
            #pragma unroll
            for (int r = 0; r < 4; ++r)
                Cs[w * 16 + quad * 4 + r][t * 16 + mrow] = acc[t][r];
        __syncthreads();

        if (rowBase + orow < M) {
            union { ushort u16[16]; uint4 u4[2]; } ov;
            #pragma unroll
            for (int j4 = 0; j4 < 4; ++j4) {
                float4 bb = *(const float4*)(b2 + n0 + c0 + j4 * 4);
                float bjv[4] = {bb.x, bb.y, bb.z, bb.w};
                #pragma unroll
                for (int j = 0; j < 4; ++j) {
                    float v = Cs[orow][c0 + j4 * 4 + j] + bjv[j];
                    ov.u16[j4 * 4 + j] = f2bf(fmaxf(v, 0.f));
                }
            }
            ushort* cp = m2out + (size_t)(rowBase + orow) * D + n0 + c0;
            *(uint4*)cp = ov.u4[0];
            *(uint4*)(cp + 8) = ov.u4[1];
        }
    }
}

// ---------------------------------------------------------------- head
__global__ void head_kernel(const ushort* __restrict__ h,
                            const float* __restrict__ Wa,
                            const float* __restrict__ ba,
                            float* __restrict__ out) {
    int wid  = (int)(((long long)blockIdx.x * blockDim.x + threadIdx.x) >> 6);
    int lane = threadIdx.x & 63;
    if (wid >= N_NODES) return;

    uint h2 = *(const uint*)(h + (size_t)wid * D + lane * 2);
    float hx = bflo(h2), hy = bfhi(h2);
    float a[4];
    #pragma unroll
    for (int j = 0; j < 4; ++j) {
        float2 w2 = *(const float2*)(Wa + j * D + lane * 2);
        float p = hx * w2.x + hy * w2.y;
        #pragma unroll
        for (int s = 32; s > 0; s >>= 1)
            p += __shfl_xor(p, s, 64);
        a[j] = p + ba[j];
    }
    float mx = fmaxf(fmaxf(a[0], a[1]), fmaxf(a[2], a[3]));
    float se = expf(a[0] - mx) + expf(a[1] - mx) + expf(a[2] - mx) + expf(a[3] - mx);
    float lse = mx + logf(se);
    if (lane < 4)
        out[(size_t)wid * 4 + lane] = a[lane] - lse;
}

// ---------------------------------------------------------------- launch
extern "C" void kernel_launch(void* const* d_in, const int* in_sizes, int n_in,
                              void* d_out, int out_size, void* d_ws, size_t ws_size,
                              hipStream_t stream) {
    const float* x     = (const float*)d_in[0];
    const int*   v_idx = (const int*)d_in[1];
    const int*   e_idx = (const int*)d_in[2];
    const float* W1    = (const float*)d_in[3];
    const float* b1    = (const float*)d_in[4];
    const float* W2    = (const float*)d_in[5];
    const float* b2    = (const float*)d_in[6];
    const float* Wu    = (const float*)d_in[7];
    const float* bu    = (const float*)d_in[8];
    const float* Wa    = (const float*)d_in[9];
    const float* ba    = (const float*)d_in[10];
    float* out = (float*)d_out;

    char* wsp = (char*)d_ws;
    auto alloc = [&](size_t bytes) -> char* {
        char* p = wsp;
        wsp += (bytes + 255) & ~(size_t)255;
        return p;
    };

    ushort* xb     = (ushort*)alloc((size_t)N_NODES * D * 2);
    ushort* hA     = (ushort*)alloc((size_t)N_NODES * D * 2);
    ushort* hB     = (ushort*)alloc((size_t)N_NODES * D * 2);
    ushort* m2b    = (ushort*)alloc((size_t)N_NODES * D * 2);
    ushort* ub     = (ushort*)alloc((size_t)N_NODES * D * 2);
    ushort* e_feat = (ushort*)alloc((size_t)N_EDGES * D * 2);
    ushort* W1b    = (ushort*)alloc((size_t)H * D * 2);
    ushort* W2b    = (ushort*)alloc((size_t)D * H * 2);
    ushort* Wub    = (ushort*)alloc((size_t)D * D * 2);
    int*    e_vert = (int*)alloc((size_t)NNZ * 4);
    int*    v_edge = (int*)alloc((size_t)NNZ * 4);
    int2*   recE   = (int2*)alloc((size_t)NNZ * 8);
    int2*   recV   = (int2*)alloc((size_t)NNZ * 8);
    int*    cntE   = (int*)alloc((size_t)(NBE + NBV) * 4);
    int*    cntV   = cntE + NBE;
    int*    ptrE   = (int*)alloc((size_t)NBE * 4);
    int*    ptrV   = (int*)alloc((size_t)NBV * 4);
    int*    curE   = (int*)alloc((size_t)NBE * 4);
    int*    curV   = (int*)alloc((size_t)NBV * 4);
    int*    e_off  = (int*)alloc((size_t)(N_EDGES + 16) * 4);
    int*    v_off  = (int*)alloc((size_t)(N_NODES + 16) * 4);
    float*  erecip = (float*)alloc((size_t)N_EDGES * 4);
    float*  vrecip = (float*)alloc((size_t)N_NODES * 4);

    const int cooBlocks = (NNZ + CHUNK - 1) / CHUNK;   // 147

    f32_to_bf16_vec<<<(N_NODES * D / 4 + 255) / 256, 256, 0, stream>>>(x, xb, N_NODES * D / 4);
    f32_to_bf16_vec<<<(H * D / 4 + 255) / 256, 256, 0, stream>>>(W1, W1b, H * D / 4);
    f32_to_bf16_vec<<<(D * H / 4 + 255) / 256, 256, 0, stream>>>(W2, W2b, D * H / 4);
    f32_to_bf16_vec<<<(D * D / 4 + 255) / 256, 256, 0, stream>>>(Wu, Wub, D * D / 4);

    // ---- bucketed CSR build ----
    hipMemsetAsync(cntE, 0, (size_t)(NBE + NBV) * 4, stream);
    bucket_hist<<<cooBlocks, 256, 0, stream>>>(v_idx, e_idx, cntE, cntV);
    bucket_scan<<<2, 512, 0, stream>>>(cntE, ptrE, curE, cntV, ptrV, curV, e_off, v_off);
    bucket_place<<<cooBlocks, 256, 0, stream>>>(v_idx, e_idx, curE, curV, recE, recV);
    bucket_final<<<NBE + NBV, 256, 0, stream>>>(recE, ptrE, recV, ptrV,
                                                e_off, erecip, e_vert,
                                                v_off, vrecip, v_edge);

    const int gridM = (N_NODES + 63) / 64;   // 782

    const ushort* h = xb;
    for (int depth = 0; depth < 2; ++depth) {
        // m2 = MLP(h) (m1 in LDS only) and u = h@Wu^T + bu (reuses the h tile)
        mlp_fused<<<gridM, 256, 0, stream>>>(h, W1b, b1, W2b, b2, Wub, bu, m2b, ub, N_NODES);
        // e_feat[e] = erecip[e] * sum m2[v in e]
        gather_rows<<<(N_EDGES * 64 + 255) / 256, 256, 0, stream>>>(
            m2b, e_off, e_vert, erecip, nullptr, e_feat, N_EDGES);
        // hn[v] = relu(u[v] + vrecip[v] * sum e_feat[e in v])
        ushort* hn = (depth == 0) ? hA : hB;
        gather_rows<<<(N_NODES * 64 + 255) / 256, 256, 0, stream>>>(
            e_feat, v_off, v_edge, vrecip, ub, hn, N_NODES);
        h = hn;
    }

    head_kernel<<<(N_NODES * 64 + 255) / 256, 256, 0, stream>>>(h, Wa, ba, out);
}

// Round 8
// 316.240 us; speedup vs baseline: 14.3016x; 1.0436x over previous
//
#include <hip/hip_runtime.h>
#include <hip/hip_bf16.h>
#include <math.h>

#define N_NODES 50000
#define N_EDGES 25000
#define NNZ     600000
#define D       128
#define H       256

#define BW    98            // bucket width (segments per bucket)
#define NBE   256           // ceil(25000/98)
#define NBV   511           // ceil(50000/98)
#define CHUNK 4096          // COO items per block in hist/place

typedef short short8 __attribute__((ext_vector_type(8)));
typedef float floatx4 __attribute__((ext_vector_type(4)));

__device__ inline ushort f2bf(float f) {              // RNE fp32 -> bf16
    uint u = __float_as_uint(f);
    u += 0x7FFF + ((u >> 16) & 1);
    return (ushort)(u >> 16);
}
__device__ inline float bflo(uint u) { return __uint_as_float(u << 16); }
__device__ inline float bfhi(uint u) { return __uint_as_float(u & 0xffff0000u); }

// ---------------------------------------------------------------- convert
__global__ void f32_to_bf16_vec(const float* __restrict__ src, ushort* __restrict__ dst, int n4) {
    int i = blockIdx.x * blockDim.x + threadIdx.x;
    if (i < n4) {
        float4 v = ((const float4*)src)[i];
        ushort4 o;
        o.x = f2bf(v.x); o.y = f2bf(v.y); o.z = f2bf(v.z); o.w = f2bf(v.w);
        ((ushort4*)dst)[i] = o;
    }
}

// ---------------------------------------------------------------- bucketed CSR build
__global__ void bucket_hist(const int* __restrict__ v_idx, const int* __restrict__ e_idx,
                            int* __restrict__ cntE, int* __restrict__ cntV) {
    __shared__ int hE[NBE];
    __shared__ int hV[NBV];
    for (int i = threadIdx.x; i < NBE; i += 256) hE[i] = 0;
    for (int i = threadIdx.x; i < NBV; i += 256) hV[i] = 0;
    __syncthreads();
    int base = blockIdx.x * CHUNK;
    int end  = min(base + CHUNK, NNZ);
    for (int i = base + threadIdx.x; i < end; i += 256) {
        atomicAdd(&hE[e_idx[i] / BW], 1);
        atomicAdd(&hV[v_idx[i] / BW], 1);
    }
    __syncthreads();
    for (int i = threadIdx.x; i < NBE; i += 256) if (hE[i]) atomicAdd(&cntE[i], hE[i]);
    for (int i = threadIdx.x; i < NBV; i += 256) if (hV[i]) atomicAdd(&cntV[i], hV[i]);
}

__global__ void bucket_scan(const int* __restrict__ cntE, int* __restrict__ ptrE, int* __restrict__ curE,
                            const int* __restrict__ cntV, int* __restrict__ ptrV, int* __restrict__ curV,
                            int* __restrict__ e_off, int* __restrict__ v_off) {
    __shared__ int s[512];
    int n = (blockIdx.x == 0) ? NBE : NBV;
    const int* cnt = (blockIdx.x == 0) ? cntE : cntV;
    int* ptr = (blockIdx.x == 0) ? ptrE : ptrV;
    int* cur = (blockIdx.x == 0) ? curE : curV;
    int t = threadIdx.x;
    int v = (t < n) ? cnt[t] : 0;
    s[t] = v;
    __syncthreads();
    for (int d = 1; d < 512; d <<= 1) {
        int u = (t >= d) ? s[t - d] : 0;
        __syncthreads();
        s[t] += u;
        __syncthreads();
    }
    if (t < n) {
        int ex = s[t] - v;
        ptr[t] = ex;
        cur[t] = ex;
    }
    if (t == 0) {
        if (blockIdx.x == 0) e_off[N_EDGES] = NNZ;
        else                 v_off[N_NODES] = NNZ;
    }
}

__global__ void bucket_place(const int* __restrict__ v_idx, const int* __restrict__ e_idx,
                             int* __restrict__ curE, int* __restrict__ curV,
                             int2* __restrict__ recE, int2* __restrict__ recV) {
    __shared__ int hE[NBE], hV[NBV];
    __shared__ int rE[NBE], rV[NBV];
    for (int i = threadIdx.x; i < NBE; i += 256) hE[i] = 0;
    for (int i = threadIdx.x; i < NBV; i += 256) hV[i] = 0;
    __syncthreads();
    int base = blockIdx.x * CHUNK;
    int end  = min(base + CHUNK, NNZ);
    int myE[16], myV[16];
    #pragma unroll
    for (int j = 0; j < 16; ++j) {
        int i = base + threadIdx.x + j * 256;
        myE[j] = -1; myV[j] = -1;
        if (i < end) {
            myE[j] = e_idx[i];
            myV[j] = v_idx[i];
            atomicAdd(&hE[myE[j] / BW], 1);
            atomicAdd(&hV[myV[j] / BW], 1);
        }
    }
    __syncthreads();
    for (int i = threadIdx.x; i < NBE; i += 256) {
        int c = hE[i];
        rE[i] = c ? atomicAdd(&curE[i], c) : 0;
    }
    for (int i = threadIdx.x; i < NBV; i += 256) {
        int c = hV[i];
        rV[i] = c ? atomicAdd(&curV[i], c) : 0;
    }
    __syncthreads();
    for (int i = threadIdx.x; i < NBE; i += 256) hE[i] = 0;
    for (int i = threadIdx.x; i < NBV; i += 256) hV[i] = 0;
    __syncthreads();
    #pragma unroll
    for (int j = 0; j < 16; ++j) {
        if (myE[j] >= 0) {
            int bk = myE[j] / BW;
            int p = rE[bk] + atomicAdd(&hE[bk], 1);
            recE[p] = make_int2(myE[j], myV[j]);
            bk = myV[j] / BW;
            p = rV[bk] + atomicAdd(&hV[bk], 1);
            recV[p] = make_int2(myV[j], myE[j]);
        }
    }
}

__global__ void bucket_final(const int2* __restrict__ recE, const int* __restrict__ ptrE,
                             const int2* __restrict__ recV, const int* __restrict__ ptrV,
                             int* __restrict__ e_off, float* __restrict__ erecip, int* __restrict__ e_vert,
                             int* __restrict__ v_off, float* __restrict__ vrecip, int* __restrict__ v_edge) {
    __shared__ int hist[BW], scn[BW], cur[BW];
    const bool eSide = blockIdx.x < NBE;
    const int b = eSide ? blockIdx.x : blockIdx.x - NBE;
    const int2* rec = eSide ? recE : recV;
    const int* ptr  = eSide ? ptrE : ptrV;
    const int nseg  = eSide ? N_EDGES : N_NODES;
    const int nb    = eSide ? NBE : NBV;
    int* off        = eSide ? e_off : v_off;
    float* recip    = eSide ? erecip : vrecip;
    int* outv       = eSide ? e_vert : v_edge;

    const int s = ptr[b];
    const int e = (b + 1 < nb) ? ptr[b + 1] : NNZ;
    const int k0 = b * BW;

    for (int i = threadIdx.x; i < BW; i += 256) hist[i] = 0;
    __syncthreads();
    for (int i = s + threadIdx.x; i < e; i += 256)
        atomicAdd(&hist[rec[i].x - k0], 1);
    __syncthreads();

    if (threadIdx.x < 64) {
        int lane = threadIdx.x;
        int v0 = hist[lane];
        int a = v0;
        #pragma unroll
        for (int d = 1; d < 64; d <<= 1) {
            int u = __shfl_up(a, d, 64);
            if (lane >= d) a += u;
        }
        scn[lane] = a - v0;
        int tot0 = __shfl(a, 63, 64);
        int v1 = (lane < BW - 64) ? hist[64 + lane] : 0;
        int a1 = v1;
        #pragma unroll
        for (int d = 1; d < 64; d <<= 1) {
            int u = __shfl_up(a1, d, 64);
            if (lane >= d) a1 += u;
        }
        if (lane < BW - 64) scn[64 + lane] = tot0 + a1 - v1;
    }
    __syncthreads();

    for (int i = threadIdx.x; i < BW; i += 256) {
        int seg = k0 + i;
        if (seg < nseg) {
            off[seg] = s + scn[i];
            recip[seg] = 1.0f / (float)max(hist[i], 1);
        }
        cur[i] = scn[i];
    }
    __syncthreads();
    for (int i = s + threadIdx.x; i < e; i += 256) {
        int2 r = rec[i];
        int p = s + atomicAdd(&cur[r.x - k0], 1);
        outv[p] = r.y;
    }
}

// ---------------------------------------------------------------- gather (bf16 rows, quad layout)
// one wave per segment. 16 lanes per row (uint4 = 8 features each), 4 rows per
// load round; 16-row chunks = 4 loads in flight per lane. Fused epilogue:
// out = relu(uadd + sum*recip) when uadd != nullptr, else out = sum*recip.
__global__ void gather_rows(const ushort* __restrict__ src,
                            const int* __restrict__ off,
                            const int* __restrict__ list,
                            const float* __restrict__ recip,
                            const ushort* __restrict__ uadd,
                            ushort* __restrict__ outbuf, int nseg) {
    int seg  = (int)(((long long)blockIdx.x * blockDim.x + threadIdx.x) >> 6);
    int lane = threadIdx.x & 63;
    if (seg >= nseg) return;
    const int q  = lane >> 4;       // quarter: which row of the 4
    const int ql = lane & 15;       // feature group: 8 features at ql*8
    int s = __builtin_amdgcn_readfirstlane(off[seg]);
    int e = __builtin_amdgcn_readfirstlane(off[seg + 1]);
    const ushort* sp = src + ql * 8;

    float a0 = 0.f, a1 = 0.f, a2 = 0.f, a3 = 0.f;
    float a4 = 0.f, a5 = 0.f, a6 = 0.f, a7 = 0.f;

    int p = s;
    for (; p + 16 <= e; p += 16) {
        int j0  = list[p + 0],  j1  = list[p + 1],  j2  = list[p + 2],  j3  = list[p + 3];
        int j4  = list[p + 4],  j5  = list[p + 5],  j6  = list[p + 6],  j7  = list[p + 7];
        int j8  = list[p + 8],  j9  = list[p + 9],  j10 = list[p + 10], j11 = list[p + 11];
        int j12 = list[p + 12], j13 = list[p + 13], j14 = list[p + 14], j15 = list[p + 15];
        int r0 = (q < 2) ? (q == 0 ? j0  : j1)  : (q == 2 ? j2  : j3);
        int r1 = (q < 2) ? (q == 0 ? j4  : j5)  : (q == 2 ? j6  : j7);
        int r2 = (q < 2) ? (q == 0 ? j8  : j9)  : (q == 2 ? j10 : j11);
        int r3 = (q < 2) ? (q == 0 ? j12 : j13) : (q == 2 ? j14 : j15);
        uint4 t0 = *(const uint4*)(sp + (size_t)r0 * D);
        uint4 t1 = *(const uint4*)(sp + (size_t)r1 * D);
        uint4 t2 = *(const uint4*)(sp + (size_t)r2 * D);
        uint4 t3 = *(const uint4*)(sp + (size_t)r3 * D);
        a0 += bflo(t0.x) + bflo(t1.x) + bflo(t2.x) + bflo(t3.x);
        a1 += bfhi(t0.x) + bfhi(t1.x) + bfhi(t2.x) + bfhi(t3.x);
        a2 += bflo(t0.y) + bflo(t1.y) + bflo(t2.y) + bflo(t3.y);
        a3 += bfhi(t0.y) + bfhi(t1.y) + bfhi(t2.y) + bfhi(t3.y);
        a4 += bflo(t0.z) + bflo(t1.z) + bflo(t2.z) + bflo(t3.z);
        a5 += bfhi(t0.z) + bfhi(t1.z) + bfhi(t2.z) + bfhi(t3.z);
        a6 += bflo(t0.w) + bflo(t1.w) + bflo(t2.w) + bflo(t3.w);
        a7 += bfhi(t0.w) + bfhi(t1.w) + bfhi(t2.w) + bfhi(t3.w);
    }
    for (; p + 4 <= e; p += 4) {
        int i0 = list[p + 0], i1 = list[p + 1], i2 = list[p + 2], i3 = list[p + 3];
        int r0 = (q < 2) ? (q == 0 ? i0 : i1) : (q == 2 ? i2 : i3);
        uint4 t0 = *(const uint4*)(sp + (size_t)r0 * D);
        a0 += bflo(t0.x);  a1 += bfhi(t0.x);
        a2 += bflo(t0.y);  a3 += bfhi(t0.y);
        a4 += bflo(t0.z);  a5 += bfhi(t0.z);
        a6 += bflo(t0.w);  a7 += bfhi(t0.w);
    }
    if (p < e) {
        int rem = e - p;              // 1..3
        if (q < rem) {
            int r0 = list[p + q];
            uint4 t0 = *(const uint4*)(sp + (size_t)r0 * D);
            a0 += bflo(t0.x);  a1 += bfhi(t0.x);
            a2 += bflo(t0.y);  a3 += bfhi(t0.y);
            a4 += bflo(t0.z);  a5 += bfhi(t0.z);
            a6 += bflo(t0.w);  a7 += bfhi(t0.w);
        }
    }

    // cross-quarter reduction (quarters hold different rows, same features)
    a0 += __shfl_xor(a0, 16, 64); a0 += __shfl_xor(a0, 32, 64);
    a1 += __shfl_xor(a1, 16, 64); a1 += __shfl_xor(a1, 32, 64);
    a2 += __shfl_xor(a2, 16, 64); a2 += __shfl_xor(a2, 32, 64);
    a3 += __shfl_xor(a3, 16, 64); a3 += __shfl_xor(a3, 32, 64);
    a4 += __shfl_xor(a4, 16, 64); a4 += __shfl_xor(a4, 32, 64);
    a5 += __shfl_xor(a5, 16, 64); a5 += __shfl_xor(a5, 32, 64);
    a6 += __shfl_xor(a6, 16, 64); a6 += __shfl_xor(a6, 32, 64);
    a7 += __shfl_xor(a7, 16, 64); a7 += __shfl_xor(a7, 32, 64);

    if (q == 0) {
        float rc = recip[seg];
        float f0 = a0 * rc, f1 = a1 * rc, f2 = a2 * rc, f3 = a3 * rc;
        float f4 = a4 * rc, f5 = a5 * rc, f6 = a6 * rc, f7 = a7 * rc;
        if (uadd) {
            uint4 uv = *(const uint4*)(uadd + (size_t)seg * D + ql * 8);
            f0 = fmaxf(f0 + bflo(uv.x), 0.f);  f1 = fmaxf(f1 + bfhi(uv.x), 0.f);
            f2 = fmaxf(f2 + bflo(uv.y), 0.f);  f3 = fmaxf(f3 + bfhi(uv.y), 0.f);
            f4 = fmaxf(f4 + bflo(uv.z), 0.f);  f5 = fmaxf(f5 + bfhi(uv.z), 0.f);
            f6 = fmaxf(f6 + bflo(uv.w), 0.f);  f7 = fmaxf(f7 + bfhi(uv.w), 0.f);
        }
        uint4 o;
        o.x = ((uint)f2bf(f1) << 16) | (uint)f2bf(f0);
        o.y = ((uint)f2bf(f3) << 16) | (uint)f2bf(f2);
        o.z = ((uint)f2bf(f5) << 16) | (uint)f2bf(f4);
        o.w = ((uint)f2bf(f7) << 16) | (uint)f2bf(f6);
        *(uint4*)(outbuf + (size_t)seg * D + ql * 8) = o;
    }
}

// ---------------------------------------------------------------- fused MLP + Wu
// m2 = relu(relu(h@W1^T+b1)@W2^T+b2)  and  u = h@Wu^T+bu  per 64-row block.
// 44 KB LDS -> 3 blocks/CU. Weight panels staged whole (1 barrier pair per
// 16 MFMAs); m1 processed in 64-col chunks (never materialized); m2
// accumulated in 32 VGPRs/lane across chunks. Each wave writes/reads only
// its own 16 m1c rows -> no barrier on the m1 handoff.
__launch_bounds__(256, 3)
__global__ void mlp_fused(const ushort* __restrict__ A,   // [M,128] bf16
                          const ushort* __restrict__ W1b, // [256,128] bf16
                          const float* __restrict__ b1,
                          const ushort* __restrict__ W2b, // [128,256] bf16
                          const float* __restrict__ b2,
                          const ushort* __restrict__ Wub, // [128,128] bf16
                          const float* __restrict__ bu,
                          ushort* __restrict__ m2out,     // [M,128] bf16
                          ushort* __restrict__ uout,      // [M,128] bf16
                          int M) {
    __shared__ ushort Af[64][136];                 // 17408 B
    __shared__ __align__(16) char Pbuf[18432];     // panel / epilogue union
    __shared__ ushort m1c[64][72];                 // 9216 B
    ushort* P = (ushort*)Pbuf;
    float (*Cs)[68] = (float(*)[68])Pbuf;

    const int tid = threadIdx.x;
    const int w = tid >> 6, lane = tid & 63;
    const int quad = lane >> 4, mrow = lane & 15;
    const int rowBase = blockIdx.x * 64;
    const int orow = tid >> 2;
    const int c0   = (tid & 3) << 4;

    // ---- stage A tile (64x128) ----
    #pragma unroll
    for (int r = 0; r < 4; ++r) {
        int idx = tid + r * 256;
        int row = idx >> 4;
        int c   = (idx & 15) << 3;
        uint4 av = make_uint4(0, 0, 0, 0);
        if (rowBase + row < M)
            av = *(const uint4*)(A + (size_t)(rowBase + row) * D + c);
        *(uint4*)&Af[row][c] = av;
    }

    // ---- phase C: u = Af @ Wu^T + bu (no relu) ----
    for (int n0 = 0; n0 < D; n0 += 64) {
        __syncthreads();
        #pragma unroll
        for (int r = 0; r < 4; ++r) {
            int idx = tid + r * 256;
            int row = idx >> 4;
            int c   = (idx & 15) << 3;
            *(uint4*)&P[row * 136 + c] = *(const uint4*)(Wub + (size_t)(n0 + row) * D + c);
        }
        __syncthreads();
        floatx4 acc[4] = {{0,0,0,0},{0,0,0,0},{0,0,0,0},{0,0,0,0}};
        #pragma unroll
        for (int k0 = 0; k0 < D; k0 += 32) {
            short8 af = *(const short8*)&Af[w * 16 + mrow][k0 + quad * 8];
            #pragma unroll
            for (int t = 0; t < 4; ++t) {
                short8 bfr = *(const short8*)&P[(t * 16 + mrow) * 136 + k0 + quad * 8];
                acc[t] = __builtin_amdgcn_mfma_f32_16x16x32_bf16(af, bfr, acc[t], 0, 0, 0);
            }
        }
        __syncthreads();
        #pragma unroll
        for (int t = 0; t < 4; ++t)
            #pragma unroll
            for (int r = 0; r < 4; ++r)
                Cs[w * 16 + quad * 4 + r][t * 16 + mrow] = acc[t][r];
        __syncthreads();
        if (rowBase + orow < M) {
            union { ushort u16[16]; uint4 u4[2]; } ov;
            #pragma unroll
            for (int j4 = 0; j4 < 4; ++j4) {
                float4 bb = *(const float4*)(bu + n0 + c0 + j4 * 4);
                float bjv[4] = {bb.x, bb.y, bb.z, bb.w};
                #pragma unroll
                for (int j = 0; j < 4; ++j)
                    ov.u16[j4 * 4 + j] = f2bf(Cs[orow][c0 + j4 * 4 + j] + bjv[j]);
            }
            ushort* cp = uout + (size_t)(rowBase + orow) * D + n0 + c0;
            *(uint4*)cp = ov.u4[0];
            *(uint4*)(cp + 8) = ov.u4[1];
        }
    }

    // ---- interleaved phase A/B over 64-col m1 chunks ----
    floatx4 acc2[8] = {{0,0,0,0},{0,0,0,0},{0,0,0,0},{0,0,0,0},
                       {0,0,0,0},{0,0,0,0},{0,0,0,0},{0,0,0,0}};
    for (int kc = 0; kc < 4; ++kc) {
        __syncthreads();
        // stage W1 panel: rows kc*64..+64, all 128 k
        #pragma unroll
        for (int r = 0; r < 4; ++r) {
            int idx = tid + r * 256;
            int row = idx >> 4;
            int c   = (idx & 15) << 3;
            *(uint4*)&P[row * 136 + c] = *(const uint4*)(W1b + (size_t)(kc * 64 + row) * D + c);
        }
        __syncthreads();
        floatx4 acc1[4] = {{0,0,0,0},{0,0,0,0},{0,0,0,0},{0,0,0,0}};
        #pragma unroll
        for (int k0 = 0; k0 < D; k0 += 32) {
            short8 af = *(const short8*)&Af[w * 16 + mrow][k0 + quad * 8];
            #pragma unroll
            for (int t = 0; t < 4; ++t) {
                short8 bfr = *(const short8*)&P[(t * 16 + mrow) * 136 + k0 + quad * 8];
                acc1[t] = __builtin_amdgcn_mfma_f32_16x16x32_bf16(af, bfr, acc1[t], 0, 0, 0);
            }
        }
        // bias+relu -> m1c (own rows only; same-wave read below, no barrier)
        #pragma unroll
        for (int t = 0; t < 4; ++t) {
            float bb = b1[kc * 64 + t * 16 + mrow];
            #pragma unroll
            for (int r = 0; r < 4; ++r)
                m1c[w * 16 + quad * 4 + r][t * 16 + mrow] = f2bf(fmaxf(acc1[t][r] + bb, 0.f));
        }
        __syncthreads();   // all waves done reading W1 panel
        // stage W2 slice: all 128 rows, k = kc*64..+64  -> P as [128][72]
        #pragma unroll
        for (int r = 0; r < 4; ++r) {
            int idx = tid + r * 256;      // 0..1023
            int row = idx >> 3;           // 0..127
            int c8  = (idx & 7) << 3;     // 0..56
            *(uint4*)&P[row * 72 + c8] = *(const uint4*)(W2b + (size_t)row * H + kc * 64 + c8);
        }
        __syncthreads();
        #pragma unroll
        for (int k0 = 0; k0 < 64; k0 += 32) {
            short8 af = *(const short8*)&m1c[w * 16 + mrow][k0 + quad * 8];
            #pragma unroll
            for (int t2 = 0; t2 < 8; ++t2) {
                short8 bfr = *(const short8*)&P[(t2 * 16 + mrow) * 72 + k0 + quad * 8];
                acc2[t2] = __builtin_amdgcn_mfma_f32_16x16x32_bf16(af, bfr, acc2[t2], 0, 0, 0);
            }
        }
    }

    // ---- m2 epilogue (two 64-col halves through Cs) ----
    #pragma unroll
    for (int hh = 0; hh < 2; ++hh) {
        __syncthreads();
        #pragma unroll
        for (int t = 0; t < 4; ++t)
            #pragma unroll
            for (int r = 0; r < 4; ++r)
                Cs[w * 16 + quad * 4 + r][t * 16 + mrow] = acc2[hh * 4 + t][r];
        __syncthreads();
        if (rowBase + orow < M) {
            union { ushort u16[16]; uint4 u4[2]; } ov;
            #pragma unroll
            for (int j4 = 0; j4 < 4; ++j4) {
                float4 bb = *(const float4*)(b2 + hh * 64 + c0 + j4 * 4);
                float bjv[4] = {bb.x, bb.y, bb.z, bb.w};
                #pragma unroll
                for (int j = 0; j < 4; ++j) {
                    float v = Cs[orow][c0 + j4 * 4 + j] + bjv[j];
                    ov.u16[j4 * 4 + j] = f2bf(fmaxf(v, 0.f));
                }
            }
            ushort* cp = m2out + (size_t)(rowBase + orow) * D + hh * 64 + c0;
            *(uint4*)cp = ov.u4[0];
            *(uint4*)(cp + 8) = ov.u4[1];
        }
    }
}

// ---------------------------------------------------------------- head
__global__ void head_kernel(const ushort* __restrict__ h,
                            const float* __restrict__ Wa,
                            const float* __restrict__ ba,
                            float* __restrict__ out) {
    int wid  = (int)(((long long)blockIdx.x * blockDim.x + threadIdx.x) >> 6);
    int lane = threadIdx.x & 63;
    if (wid >= N_NODES) return;

    uint h2 = *(const uint*)(h + (size_t)wid * D + lane * 2);
    float hx = bflo(h2), hy = bfhi(h2);
    float a[4];
    #pragma unroll
    for (int j = 0; j < 4; ++j) {
        float2 w2 = *(const float2*)(Wa + j * D + lane * 2);
        float p = hx * w2.x + hy * w2.y;
        #pragma unroll
        for (int s = 32; s > 0; s >>= 1)
            p += __shfl_xor(p, s, 64);
        a[j] = p + ba[j];
    }
    float mx = fmaxf(fmaxf(a[0], a[1]), fmaxf(a[2], a[3]));
    float se = expf(a[0] - mx) + expf(a[1] - mx) + expf(a[2] - mx) + expf(a[3] - mx);
    float lse = mx + logf(se);
    if (lane < 4)
        out[(size_t)wid * 4 + lane] = a[lane] - lse;
}

// ---------------------------------------------------------------- launch
extern "C" void kernel_launch(void* const* d_in, const int* in_sizes, int n_in,
                              void* d_out, int out_size, void* d_ws, size_t ws_size,
                              hipStream_t stream) {
    const float* x     = (const float*)d_in[0];
    const int*   v_idx = (const int*)d_in[1];
    const int*   e_idx = (const int*)d_in[2];
    const float* W1    = (const float*)d_in[3];
    const float* b1    = (const float*)d_in[4];
    const float* W2    = (const float*)d_in[5];
    const float* b2    = (const float*)d_in[6];
    const float* Wu    = (const float*)d_in[7];
    const float* bu    = (const float*)d_in[8];
    const float* Wa    = (const float*)d_in[9];
    const float* ba    = (const float*)d_in[10];
    float* out = (float*)d_out;

    char* wsp = (char*)d_ws;
    auto alloc = [&](size_t bytes) -> char* {
        char* p = wsp;
        wsp += (bytes + 255) & ~(size_t)255;
        return p;
    };

    ushort* xb     = (ushort*)alloc((size_t)N_NODES * D * 2);
    ushort* hA     = (ushort*)alloc((size_t)N_NODES * D * 2);
    ushort* hB     = (ushort*)alloc((size_t)N_NODES * D * 2);
    ushort* m2b    = (ushort*)alloc((size_t)N_NODES * D * 2);
    ushort* ub     = (ushort*)alloc((size_t)N_NODES * D * 2);
    ushort* e_feat = (ushort*)alloc((size_t)N_EDGES * D * 2);
    ushort* W1b    = (ushort*)alloc((size_t)H * D * 2);
    ushort* W2b    = (ushort*)alloc((size_t)D * H * 2);
    ushort* Wub    = (ushort*)alloc((size_t)D * D * 2);
    int*    e_vert = (int*)alloc((size_t)NNZ * 4);
    int*    v_edge = (int*)alloc((size_t)NNZ * 4);
    int2*   recE   = (int2*)alloc((size_t)NNZ * 8);
    int2*   recV   = (int2*)alloc((size_t)NNZ * 8);
    int*    cntE   = (int*)alloc((size_t)(NBE + NBV) * 4);
    int*    cntV   = cntE + NBE;
    int*    ptrE   = (int*)alloc((size_t)NBE * 4);
    int*    ptrV   = (int*)alloc((size_t)NBV * 4);
    int*    curE   = (int*)alloc((size_t)NBE * 4);
    int*    curV   = (int*)alloc((size_t)NBV * 4);
    int*    e_off  = (int*)alloc((size_t)(N_EDGES + 16) * 4);
    int*    v_off  = (int*)alloc((size_t)(N_NODES + 16) * 4);
    float*  erecip = (float*)alloc((size_t)N_EDGES * 4);
    float*  vrecip = (float*)alloc((size_t)N_NODES * 4);

    const int cooBlocks = (NNZ + CHUNK - 1) / CHUNK;   // 147

    f32_to_bf16_vec<<<(N_NODES * D / 4 + 255) / 256, 256, 0, stream>>>(x, xb, N_NODES * D / 4);
    f32_to_bf16_vec<<<(H * D / 4 + 255) / 256, 256, 0, stream>>>(W1, W1b, H * D / 4);
    f32_to_bf16_vec<<<(D * H / 4 + 255) / 256, 256, 0, stream>>>(W2, W2b, D * H / 4);
    f32_to_bf16_vec<<<(D * D / 4 + 255) / 256, 256, 0, stream>>>(Wu, Wub, D * D / 4);

    // ---- bucketed CSR build ----
    hipMemsetAsync(cntE, 0, (size_t)(NBE + NBV) * 4, stream);
    bucket_hist<<<cooBlocks, 256, 0, stream>>>(v_idx, e_idx, cntE, cntV);
    bucket_scan<<<2, 512, 0, stream>>>(cntE, ptrE, curE, cntV, ptrV, curV, e_off, v_off);
    bucket_place<<<cooBlocks, 256, 0, stream>>>(v_idx, e_idx, curE, curV, recE, recV);
    bucket_final<<<NBE + NBV, 256, 0, stream>>>(recE, ptrE, recV, ptrV,
                                                e_off, erecip, e_vert,
                                                v_off, vrecip, v_edge);

    const int gridM = (N_NODES + 63) / 64;   // 782

    const ushort* h = xb;
    for (int depth = 0; depth < 2; ++depth) {
        mlp_fused<<<gridM, 256, 0, stream>>>(h, W1b, b1, W2b, b2, Wub, bu, m2b, ub, N_NODES);
        gather_rows<<<(N_EDGES * 64 + 255) / 256, 256, 0, stream>>>(
            m2b, e_off, e_vert, erecip, nullptr, e_feat, N_EDGES);
        ushort* hn = (depth == 0) ? hA : hB;
        gather_rows<<<(N_NODES * 64 + 255) / 256, 256, 0, stream>>>(
            e_feat, v_off, v_edge, vrecip, ub, hn, N_NODES);
        h = hn;
    }

    head_kernel<<<(N_NODES * 64 + 255) / 256, 256, 0, stream>>>(h, Wa, ba, out);
}

// Round 9
// 298.452 us; speedup vs baseline: 15.1540x; 1.0596x over previous
//
#include <hip/hip_runtime.h>
#include <hip/hip_bf16.h>
#include <math.h>

#define N_NODES 50000
#define N_EDGES 25000
#define NNZ     600000
#define D       128
#define H       256

#define BW    98            // bucket width (segments per bucket)
#define NBE   256           // ceil(25000/98)
#define NBV   511           // ceil(50000/98)
#define CAPE  3072          // per-bucket record capacity, E (mean 2352, sd 48)
#define CAPV  1536          // per-bucket record capacity, V (mean 1176, sd 34)
#define CHUNK 4096          // COO items per block in place

typedef short short8 __attribute__((ext_vector_type(8)));
typedef float floatx4 __attribute__((ext_vector_type(4)));

__device__ inline ushort f2bf(float f) {              // RNE fp32 -> bf16
    uint u = __float_as_uint(f);
    u += 0x7FFF + ((u >> 16) & 1);
    return (ushort)(u >> 16);
}
__device__ inline float bflo(uint u) { return __uint_as_float(u << 16); }
__device__ inline float bfhi(uint u) { return __uint_as_float(u & 0xffff0000u); }

// ---------------------------------------------------------------- convert
__global__ void f32_to_bf16_vec(const float* __restrict__ src, ushort* __restrict__ dst, int n4) {
    int i = blockIdx.x * blockDim.x + threadIdx.x;
    if (i < n4) {
        float4 v = ((const float4*)src)[i];
        ushort4 o;
        o.x = f2bf(v.x); o.y = f2bf(v.y); o.z = f2bf(v.z); o.w = f2bf(v.w);
        ((ushort4*)dst)[i] = o;
    }
}

// ---------------------------------------------------------------- bucketed CSR build
// Single placement pass: per-block LDS histograms reserve contiguous runs in
// fixed-capacity padded bucket regions (no global scan needed).
__global__ void bucket_place(const int* __restrict__ v_idx, const int* __restrict__ e_idx,
                             int* __restrict__ cntE, int* __restrict__ cntV,
                             int2* __restrict__ recE, int2* __restrict__ recV) {
    __shared__ int hE[NBE], hV[NBV];     // histogram, then reused as LDS cursor
    __shared__ int rE[NBE], rV[NBV];     // reserved base-within-bucket
    for (int i = threadIdx.x; i < NBE; i += 256) hE[i] = 0;
    for (int i = threadIdx.x; i < NBV; i += 256) hV[i] = 0;
    __syncthreads();
    int base = blockIdx.x * CHUNK;
    int end  = min(base + CHUNK, NNZ);
    int myE[16], myV[16];
    #pragma unroll
    for (int j = 0; j < 16; ++j) {
        int i = base + threadIdx.x + j * 256;
        myE[j] = -1; myV[j] = -1;
        if (i < end) {
            myE[j] = e_idx[i];
            myV[j] = v_idx[i];
            atomicAdd(&hE[myE[j] / BW], 1);
            atomicAdd(&hV[myV[j] / BW], 1);
        }
    }
    __syncthreads();
    for (int i = threadIdx.x; i < NBE; i += 256) {
        int c = hE[i];
        rE[i] = c ? atomicAdd(&cntE[i], c) : 0;
    }
    for (int i = threadIdx.x; i < NBV; i += 256) {
        int c = hV[i];
        rV[i] = c ? atomicAdd(&cntV[i], c) : 0;
    }
    __syncthreads();
    for (int i = threadIdx.x; i < NBE; i += 256) hE[i] = 0;
    for (int i = threadIdx.x; i < NBV; i += 256) hV[i] = 0;
    __syncthreads();
    #pragma unroll
    for (int j = 0; j < 16; ++j) {
        if (myE[j] >= 0) {
            int bk = myE[j] / BW;
            int p = rE[bk] + atomicAdd(&hE[bk], 1);
            recE[(size_t)bk * CAPE + p] = make_int2(myE[j], myV[j]);
            bk = myV[j] / BW;
            p = rV[bk] + atomicAdd(&hV[bk], 1);
            recV[(size_t)bk * CAPV + p] = make_int2(myV[j], myE[j]);
        }
    }
}

// one block per bucket -> per-segment {start,count} descriptors + recip + adjacency
__global__ void bucket_final(const int2* __restrict__ recE, const int* __restrict__ cntE,
                             const int2* __restrict__ recV, const int* __restrict__ cntV,
                             int2* __restrict__ e_sd, float* __restrict__ erecip, int* __restrict__ e_vert,
                             int2* __restrict__ v_sd, float* __restrict__ vrecip, int* __restrict__ v_edge) {
    __shared__ int hist[BW], scn[BW], cur[BW];
    const bool eSide = blockIdx.x < NBE;
    const int b = eSide ? blockIdx.x : blockIdx.x - NBE;
    const int cap   = eSide ? CAPE : CAPV;
    const int2* rec = (eSide ? recE : recV) + (size_t)b * cap;
    const int cnt   = (eSide ? cntE : cntV)[b];
    const int nseg  = eSide ? N_EDGES : N_NODES;
    int2* sd        = eSide ? e_sd : v_sd;
    float* recip    = eSide ? erecip : vrecip;
    int* outv       = (eSide ? e_vert : v_edge) + (size_t)b * cap;
    const int k0 = b * BW;

    for (int i = threadIdx.x; i < BW; i += 256) hist[i] = 0;
    __syncthreads();
    for (int i = threadIdx.x; i < cnt; i += 256)
        atomicAdd(&hist[rec[i].x - k0], 1);
    __syncthreads();

    if (threadIdx.x < 64) {
        int lane = threadIdx.x;
        int v0 = hist[lane];
        int a = v0;
        #pragma unroll
        for (int d = 1; d < 64; d <<= 1) {
            int u = __shfl_up(a, d, 64);
            if (lane >= d) a += u;
        }
        scn[lane] = a - v0;
        int tot0 = __shfl(a, 63, 64);
        int v1 = (lane < BW - 64) ? hist[64 + lane] : 0;
        int a1 = v1;
        #pragma unroll
        for (int d = 1; d < 64; d <<= 1) {
            int u = __shfl_up(a1, d, 64);
            if (lane >= d) a1 += u;
        }
        if (lane < BW - 64) scn[64 + lane] = tot0 + a1 - v1;
    }
    __syncthreads();

    const int gbase = b * cap;
    for (int i = threadIdx.x; i < BW; i += 256) {
        int seg = k0 + i;
        if (seg < nseg) {
            sd[seg] = make_int2(gbase + scn[i], hist[i]);
            recip[seg] = 1.0f / (float)max(hist[i], 1);
        }
        cur[i] = scn[i];
    }
    __syncthreads();
    for (int i = threadIdx.x; i < cnt; i += 256) {
        int2 r = rec[i];
        int p = atomicAdd(&cur[r.x - k0], 1);
        outv[p] = r.y;
    }
}

// ---------------------------------------------------------------- gather (bf16 rows, quad layout)
// one wave per segment; 16 lanes per row (uint4 = 8 features each), 4 rows per
// load round; 16-row chunks double-buffered -> 8 loads in flight per lane.
// Epilogues: plain mean / fused relu(u + mean) / fused head (log_softmax out).
#define LOADC(pp, t0, t1, t2, t3)                                                  \
    do {                                                                           \
        int j0  = list[(pp) + 0],  j1  = list[(pp) + 1];                           \
        int j2  = list[(pp) + 2],  j3  = list[(pp) + 3];                           \
        int j4  = list[(pp) + 4],  j5  = list[(pp) + 5];                           \
        int j6  = list[(pp) + 6],  j7  = list[(pp) + 7];                           \
        int j8  = list[(pp) + 8],  j9  = list[(pp) + 9];                           \
        int j10 = list[(pp) + 10], j11 = list[(pp) + 11];                          \
        int j12 = list[(pp) + 12], j13 = list[(pp) + 13];                          \
        int j14 = list[(pp) + 14], j15 = list[(pp) + 15];                          \
        int r0 = (q < 2) ? (q == 0 ? j0  : j1)  : (q == 2 ? j2  : j3);             \
        int r1 = (q < 2) ? (q == 0 ? j4  : j5)  : (q == 2 ? j6  : j7);             \
        int r2 = (q < 2) ? (q == 0 ? j8  : j9)  : (q == 2 ? j10 : j11);            \
        int r3 = (q < 2) ? (q == 0 ? j12 : j13) : (q == 2 ? j14 : j15);            \
        t0 = *(const uint4*)(sp + (size_t)r0 * D);                                 \
        t1 = *(const uint4*)(sp + (size_t)r1 * D);                                 \
        t2 = *(const uint4*)(sp + (size_t)r2 * D);                                 \
        t3 = *(const uint4*)(sp + (size_t)r3 * D);                                 \
    } while (0)

#define ACCC(t0, t1, t2, t3)                                                       \
    do {                                                                           \
        a0 += bflo(t0.x) + bflo(t1.x) + bflo(t2.x) + bflo(t3.x);                   \
        a1 += bfhi(t0.x) + bfhi(t1.x) + bfhi(t2.x) + bfhi(t3.x);                   \
        a2 += bflo(t0.y) + bflo(t1.y) + bflo(t2.y) + bflo(t3.y);                   \
        a3 += bfhi(t0.y) + bfhi(t1.y) + bfhi(t2.y) + bfhi(t3.y);                   \
        a4 += bflo(t0.z) + bflo(t1.z) + bflo(t2.z) + bflo(t3.z);                   \
        a5 += bfhi(t0.z) + bfhi(t1.z) + bfhi(t2.z) + bfhi(t3.z);                   \
        a6 += bflo(t0.w) + bflo(t1.w) + bflo(t2.w) + bflo(t3.w);                   \
        a7 += bfhi(t0.w) + bfhi(t1.w) + bfhi(t2.w) + bfhi(t3.w);                   \
    } while (0)

__global__ void gather_rows(const ushort* __restrict__ src,
                            const int2* __restrict__ sd,
                            const int* __restrict__ list,
                            const float* __restrict__ recip,
                            const ushort* __restrict__ uadd,
                            ushort* __restrict__ outbuf,
                            const float* __restrict__ Wa,
                            const float* __restrict__ ba,
                            float* __restrict__ headout,
                            int nseg) {
    int seg  = (int)(((long long)blockIdx.x * blockDim.x + threadIdx.x) >> 6);
    int lane = threadIdx.x & 63;
    if (seg >= nseg) return;
    const int q  = lane >> 4;       // quarter: which row of the 4
    const int ql = lane & 15;       // feature group: 8 features at ql*8
    int2 dsc = sd[seg];
    int s   = __builtin_amdgcn_readfirstlane(dsc.x);
    int cnt = __builtin_amdgcn_readfirstlane(dsc.y);
    int e = s + cnt;
    const ushort* sp = src + ql * 8;

    float a0 = 0.f, a1 = 0.f, a2 = 0.f, a3 = 0.f;
    float a4 = 0.f, a5 = 0.f, a6 = 0.f, a7 = 0.f;

    int p = s;
    if (p + 16 <= e) {
        uint4 t0, t1, t2, t3;
        LOADC(p, t0, t1, t2, t3);
        p += 16;
        while (p + 16 <= e) {
            uint4 n0, n1, n2, n3;
            LOADC(p, n0, n1, n2, n3);       // issue next chunk before consuming current
            ACCC(t0, t1, t2, t3);
            t0 = n0; t1 = n1; t2 = n2; t3 = n3;
            p += 16;
        }
        ACCC(t0, t1, t2, t3);
    }
    for (; p + 4 <= e; p += 4) {
        int i0 = list[p + 0], i1 = list[p + 1], i2 = list[p + 2], i3 = list[p + 3];
        int r0 = (q < 2) ? (q == 0 ? i0 : i1) : (q == 2 ? i2 : i3);
        uint4 t0 = *(const uint4*)(sp + (size_t)r0 * D);
        a0 += bflo(t0.x);  a1 += bfhi(t0.x);
        a2 += bflo(t0.y);  a3 += bfhi(t0.y);
        a4 += bflo(t0.z);  a5 += bfhi(t0.z);
        a6 += bflo(t0.w);  a7 += bfhi(t0.w);
    }
    if (p < e) {
        int rem = e - p;              // 1..3
        if (q < rem) {
            int r0 = list[p + q];
            uint4 t0 = *(const uint4*)(sp + (size_t)r0 * D);
            a0 += bflo(t0.x);  a1 += bfhi(t0.x);
            a2 += bflo(t0.y);  a3 += bfhi(t0.y);
            a4 += bflo(t0.z);  a5 += bfhi(t0.z);
            a6 += bflo(t0.w);  a7 += bfhi(t0.w);
        }
    }

    // cross-quarter reduction (quarters hold different rows, same features)
    a0 += __shfl_xor(a0, 16, 64); a0 += __shfl_xor(a0, 32, 64);
    a1 += __shfl_xor(a1, 16, 64); a1 += __shfl_xor(a1, 32, 64);
    a2 += __shfl_xor(a2, 16, 64); a2 += __shfl_xor(a2, 32, 64);
    a3 += __shfl_xor(a3, 16, 64); a3 += __shfl_xor(a3, 32, 64);
    a4 += __shfl_xor(a4, 16, 64); a4 += __shfl_xor(a4, 32, 64);
    a5 += __shfl_xor(a5, 16, 64); a5 += __shfl_xor(a5, 32, 64);
    a6 += __shfl_xor(a6, 16, 64); a6 += __shfl_xor(a6, 32, 64);
    a7 += __shfl_xor(a7, 16, 64); a7 += __shfl_xor(a7, 32, 64);

    if (q == 0) {
        float rc = recip[seg];
        float f0 = a0 * rc, f1 = a1 * rc, f2 = a2 * rc, f3 = a3 * rc;
        float f4 = a4 * rc, f5 = a5 * rc, f6 = a6 * rc, f7 = a7 * rc;
        if (uadd) {
            uint4 uv = *(const uint4*)(uadd + (size_t)seg * D + ql * 8);
            f0 = fmaxf(f0 + bflo(uv.x), 0.f);  f1 = fmaxf(f1 + bfhi(uv.x), 0.f);
            f2 = fmaxf(f2 + bflo(uv.y), 0.f);  f3 = fmaxf(f3 + bfhi(uv.y), 0.f);
            f4 = fmaxf(f4 + bflo(uv.z), 0.f);  f5 = fmaxf(f5 + bfhi(uv.z), 0.f);
            f6 = fmaxf(f6 + bflo(uv.w), 0.f);  f7 = fmaxf(f7 + bfhi(uv.w), 0.f);
        }
        if (headout) {
            // a = h @ Wa^T + ba across quarter-0's 16 lanes (8 features each)
            float av[4];
            #pragma unroll
            for (int j = 0; j < 4; ++j) {
                const float* wr = Wa + j * D + ql * 8;
                float4 wA = *(const float4*)wr;
                float4 wB = *(const float4*)(wr + 4);
                float pj = f0 * wA.x + f1 * wA.y + f2 * wA.z + f3 * wA.w
                         + f4 * wB.x + f5 * wB.y + f6 * wB.z + f7 * wB.w;
                pj += __shfl_xor(pj, 1, 64);
                pj += __shfl_xor(pj, 2, 64);
                pj += __shfl_xor(pj, 4, 64);
                pj += __shfl_xor(pj, 8, 64);
                av[j] = pj + ba[j];
            }
            if (ql == 0) {
                float mx = fmaxf(fmaxf(av[0], av[1]), fmaxf(av[2], av[3]));
                float se = expf(av[0] - mx) + expf(av[1] - mx)
                         + expf(av[2] - mx) + expf(av[3] - mx);
                float lse = mx + logf(se);
                float4 o = make_float4(av[0] - lse, av[1] - lse, av[2] - lse, av[3] - lse);
                *(float4*)(headout + (size_t)seg * 4) = o;
            }
        } else {
            uint4 o;
            o.x = ((uint)f2bf(f1) << 16) | (uint)f2bf(f0);
            o.y = ((uint)f2bf(f3) << 16) | (uint)f2bf(f2);
            o.z = ((uint)f2bf(f5) << 16) | (uint)f2bf(f4);
            o.w = ((uint)f2bf(f7) << 16) | (uint)f2bf(f6);
            *(uint4*)(outbuf + (size_t)seg * D + ql * 8) = o;
        }
    }
}

// ---------------------------------------------------------------- fused MLP + Wu
// m2 = relu(relu(h@W1^T+b1)@W2^T+b2)  and  u = h@Wu^T+bu  per 64-row block.
// 44 KB LDS -> 3 blocks/CU. Weight panels staged whole (1 barrier pair per
// 16 MFMAs); m1 processed in 64-col chunks (never materialized).
__launch_bounds__(256, 3)
__global__ void mlp_fused(const ushort* __restrict__ A,   // [M,128] bf16
                          const ushort* __restrict__ W1b, // [256,128] bf16
                          const float* __restrict__ b1,
                          const ushort* __restrict__ W2b, // [128,256] bf16
                          const float* __restrict__ b2,
                          const ushort* __restrict__ Wub, // [128,128] bf16
                          const float* __restrict__ bu,
                          ushort* __restrict__ m2out,     // [M,128] bf16
                          ushort* __restrict__ uout,      // [M,128] bf16
                          int M) {
    __shared__ ushort Af[64][136];                 // 17408 B
    __shared__ __align__(16) char Pbuf[18432];     // panel / epilogue union
    __shared__ ushort m1c[64][72];                 // 9216 B
    ushort* P = (ushort*)Pbuf;
    float (*Cs)[68] = (float(*)[68])Pbuf;

    const int tid = threadIdx.x;
    const int w = tid >> 6, lane = tid & 63;
    const int quad = lane >> 4, mrow = lane & 15;
    const int rowBase = blockIdx.x * 64;
    const int orow = tid >> 2;
    const int c0   = (tid & 3) << 4;

    // ---- stage A tile (64x128) ----
    #pragma unroll
    for (int r = 0; r < 4; ++r) {
        int idx = tid + r * 256;
        int row = idx >> 4;
        int c   = (idx & 15) << 3;
        uint4 av = make_uint4(0, 0, 0, 0);
        if (rowBase + row < M)
            av = *(const uint4*)(A + (size_t)(rowBase + row) * D + c);
        *(uint4*)&Af[row][c] = av;
    }

    // ---- phase C: u = Af @ Wu^T + bu (no relu) ----
    for (int n0 = 0; n0 < D; n0 += 64) {
        __syncthreads();
        #pragma unroll
        for (int r = 0; r < 4; ++r) {
            int idx = tid + r * 256;
            int row = idx >> 4;
            int c   = (idx & 15) << 3;
            *(uint4*)&P[row * 136 + c] = *(const uint4*)(Wub + (size_t)(n0 + row) * D + c);
        }
        __syncthreads();
        floatx4 acc[4] = {{0,0,0,0},{0,0,0,0},{0,0,0,0},{0,0,0,0}};
        #pragma unroll
        for (int k0 = 0; k0 < D; k0 += 32) {
            short8 af = *(const short8*)&Af[w * 16 + mrow][k0 + quad * 8];
            #pragma unroll
            for (int t = 0; t < 4; ++t) {
                short8 bfr = *(const short8*)&P[(t * 16 + mrow) * 136 + k0 + quad * 8];
                acc[t] = __builtin_amdgcn_mfma_f32_16x16x32_bf16(af, bfr, acc[t], 0, 0, 0);
            }
        }
        __syncthreads();
        #pragma unroll
        for (int t = 0; t < 4; ++t)
            #pragma unroll
            for (int r = 0; r < 4; ++r)
                Cs[w * 16 + quad * 4 + r][t * 16 + mrow] = acc[t][r];
        __syncthreads();
        if (rowBase + orow < M) {
            union { ushort u16[16]; uint4 u4[2]; } ov;
            #pragma unroll
            for (int j4 = 0; j4 < 4; ++j4) {
                float4 bb = *(const float4*)(bu + n0 + c0 + j4 * 4);
                float bjv[4] = {bb.x, bb.y, bb.z, bb.w};
                #pragma unroll
                for (int j = 0; j < 4; ++j)
                    ov.u16[j4 * 4 + j] = f2bf(Cs[orow][c0 + j4 * 4 + j] + bjv[j]);
            }
            ushort* cp = uout + (size_t)(rowBase + orow) * D + n0 + c0;
            *(uint4*)cp = ov.u4[0];
            *(uint4*)(cp + 8) = ov.u4[1];
        }
    }

    // ---- interleaved phase A/B over 64-col m1 chunks ----
    floatx4 acc2[8] = {{0,0,0,0},{0,0,0,0},{0,0,0,0},{0,0,0,0},
                       {0,0,0,0},{0,0,0,0},{0,0,0,0},{0,0,0,0}};
    for (int kc = 0; kc < 4; ++kc) {
        __syncthreads();
        #pragma unroll
        for (int r = 0; r < 4; ++r) {
            int idx = tid + r * 256;
            int row = idx >> 4;
            int c   = (idx & 15) << 3;
            *(uint4*)&P[row * 136 + c] = *(const uint4*)(W1b + (size_t)(kc * 64 + row) * D + c);
        }
        __syncthreads();
        floatx4 acc1[4] = {{0,0,0,0},{0,0,0,0},{0,0,0,0},{0,0,0,0}};
        #pragma unroll
        for (int k0 = 0; k0 < D; k0 += 32) {
            short8 af = *(const short8*)&Af[w * 16 + mrow][k0 + quad * 8];
            #pragma unroll
            for (int t = 0; t < 4; ++t) {
                short8 bfr = *(const short8*)&P[(t * 16 + mrow) * 136 + k0 + quad * 8];
                acc1[t] = __builtin_amdgcn_mfma_f32_16x16x32_bf16(af, bfr, acc1[t], 0, 0, 0);
            }
        }
        #pragma unroll
        for (int t = 0; t < 4; ++t) {
            float bb = b1[kc * 64 + t * 16 + mrow];
            #pragma unroll
            for (int r = 0; r < 4; ++r)
                m1c[w * 16 + quad * 4 + r][t * 16 + mrow] = f2bf(fmaxf(acc1[t][r] + bb, 0.f));
        }
        __syncthreads();   // all waves done reading W1 panel
        #pragma unroll
        for (int r = 0; r < 4; ++r) {
            int idx = tid + r * 256;      // 0..1023
            int row = idx >> 3;           // 0..127
            int c8  = (idx & 7) << 3;     // 0..56
            *(uint4*)&P[row * 72 + c8] = *(const uint4*)(W2b + (size_t)row * H + kc * 64 + c8);
        }
        __syncthreads();
        #pragma unroll
        for (int k0 = 0; k0 < 64; k0 += 32) {
            short8 af = *(const short8*)&m1c[w * 16 + mrow][k0 + quad * 8];
            #pragma unroll
            for (int t2 = 0; t2 < 8; ++t2) {
                short8 bfr = *(const short8*)&P[(t2 * 16 + mrow) * 72 + k0 + quad * 8];
                acc2[t2] = __builtin_amdgcn_mfma_f32_16x16x32_bf16(af, bfr, acc2[t2], 0, 0, 0);
            }
        }
    }

    // ---- m2 epilogue (two 64-col halves through Cs) ----
    #pragma unroll
    for (int hh = 0; hh < 2; ++hh) {
        __syncthreads();
        #pragma unroll
        for (int t = 0; t < 4; ++t)
            #pragma unroll
            for (int r = 0; r < 4; ++r)
                Cs[w * 16 + quad * 4 + r][t * 16 + mrow] = acc2[hh * 4 + t][r];
        __syncthreads();
        if (rowBase + orow < M) {
            union { ushort u16[16]; uint4 u4[2]; } ov;
            #pragma unroll
            for (int j4 = 0; j4 < 4; ++j4) {
                float4 bb = *(const float4*)(b2 + hh * 64 + c0 + j4 * 4);
                float bjv[4] = {bb.x, bb.y, bb.z, bb.w};
                #pragma unroll
                for (int j = 0; j < 4; ++j) {
                    float v = Cs[orow][c0 + j4 * 4 + j] + bjv[j];
                    ov.u16[j4 * 4 + j] = f2bf(fmaxf(v, 0.f));
                }
            }
            ushort* cp = m2out + (size_t)(rowBase + orow) * D + hh * 64 + c0;
            *(uint4*)cp = ov.u4[0];
            *(uint4*)(cp + 8) = ov.u4[1];
        }
    }
}

// ---------------------------------------------------------------- launch
extern "C" void kernel_launch(void* const* d_in, const int* in_sizes, int n_in,
                              void* d_out, int out_size, void* d_ws, size_t ws_size,
                              hipStream_t stream) {
    const float* x     = (const float*)d_in[0];
    const int*   v_idx = (const int*)d_in[1];
    const int*   e_idx = (const int*)d_in[2];
    const float* W1    = (const float*)d_in[3];
    const float* b1    = (const float*)d_in[4];
    const float* W2    = (const float*)d_in[5];
    const float* b2    = (const float*)d_in[6];
    const float* Wu    = (const float*)d_in[7];
    const float* bu    = (const float*)d_in[8];
    const float* Wa    = (const float*)d_in[9];
    const float* ba    = (const float*)d_in[10];
    float* out = (float*)d_out;

    char* wsp = (char*)d_ws;
    auto alloc = [&](size_t bytes) -> char* {
        char* p = wsp;
        wsp += (bytes + 255) & ~(size_t)255;
        return p;
    };

    ushort* xb     = (ushort*)alloc((size_t)N_NODES * D * 2);
    ushort* hA     = (ushort*)alloc((size_t)N_NODES * D * 2);
    ushort* m2b    = (ushort*)alloc((size_t)N_NODES * D * 2);
    ushort* ub     = (ushort*)alloc((size_t)N_NODES * D * 2);
    ushort* e_feat = (ushort*)alloc((size_t)N_EDGES * D * 2);
    ushort* W1b    = (ushort*)alloc((size_t)H * D * 2);
    ushort* W2b    = (ushort*)alloc((size_t)D * H * 2);
    ushort* Wub    = (ushort*)alloc((size_t)D * D * 2);
    int*    e_vert = (int*)alloc((size_t)NBE * CAPE * 4);
    int*    v_edge = (int*)alloc((size_t)NBV * CAPV * 4);
    int2*   recE   = (int2*)alloc((size_t)NBE * CAPE * 8);
    int2*   recV   = (int2*)alloc((size_t)NBV * CAPV * 8);
    int*    cntE   = (int*)alloc((size_t)(NBE + NBV) * 4);   // one memset covers both
    int*    cntV   = cntE + NBE;
    int2*   e_sd   = (int2*)alloc((size_t)N_EDGES * 8);
    int2*   v_sd   = (int2*)alloc((size_t)N_NODES * 8);
    float*  erecip = (float*)alloc((size_t)N_EDGES * 4);
    float*  vrecip = (float*)alloc((size_t)N_NODES * 4);

    const int cooBlocks = (NNZ + CHUNK - 1) / CHUNK;   // 147

    f32_to_bf16_vec<<<(N_NODES * D / 4 + 255) / 256, 256, 0, stream>>>(x, xb, N_NODES * D / 4);
    f32_to_bf16_vec<<<(H * D / 4 + 255) / 256, 256, 0, stream>>>(W1, W1b, H * D / 4);
    f32_to_bf16_vec<<<(D * H / 4 + 255) / 256, 256, 0, stream>>>(W2, W2b, D * H / 4);
    f32_to_bf16_vec<<<(D * D / 4 + 255) / 256, 256, 0, stream>>>(Wu, Wub, D * D / 4);

    // ---- bucketed CSR build (single placement pass, padded buckets) ----
    hipMemsetAsync(cntE, 0, (size_t)(NBE + NBV) * 4, stream);
    bucket_place<<<cooBlocks, 256, 0, stream>>>(v_idx, e_idx, cntE, cntV, recE, recV);
    bucket_final<<<NBE + NBV, 256, 0, stream>>>(recE, cntE, recV, cntV,
                                                e_sd, erecip, e_vert,
                                                v_sd, vrecip, v_edge);

    const int gridM = (N_NODES + 63) / 64;   // 782

    const ushort* h = xb;
    for (int depth = 0; depth < 2; ++depth) {
        mlp_fused<<<gridM, 256, 0, stream>>>(h, W1b, b1, W2b, b2, Wub, bu, m2b, ub, N_NODES);
        // e_feat[e] = erecip[e] * sum m2[v in e]
        gather_rows<<<(N_EDGES * 64 + 255) / 256, 256, 0, stream>>>(
            m2b, e_sd, e_vert, erecip, nullptr, e_feat, nullptr, nullptr, nullptr, N_EDGES);
        if (depth == 0) {
            // h1[v] = relu(u[v] + vrecip[v] * sum e_feat[e in v])
            gather_rows<<<(N_NODES * 64 + 255) / 256, 256, 0, stream>>>(
                e_feat, v_sd, v_edge, vrecip, ub, hA, nullptr, nullptr, nullptr, N_NODES);
            h = hA;
        } else {
            // final: fused head -> out = log_softmax(relu(u+agg) @ Wa^T + ba)
            gather_rows<<<(N_NODES * 64 + 255) / 256, 256, 0, stream>>>(
                e_feat, v_sd, v_edge, vrecip, ub, nullptr, Wa, ba, out, N_NODES);
        }
    }
}

// Round 10
// 269.642 us; speedup vs baseline: 16.7732x; 1.1068x over previous
//
#include <hip/hip_runtime.h>
#include <hip/hip_bf16.h>
#include <math.h>

#define N_NODES 50000
#define N_EDGES 25000
#define NNZ     600000
#define D       128
#define H       256

#define BW    98            // bucket width (segments per bucket)
#define NBE   256           // ceil(25000/98)
#define NBV   511           // ceil(50000/98)
#define CAPE  3072          // per-bucket record capacity, E (mean 2352, sd 48)
#define CAPV  1536          // per-bucket record capacity, V (mean 1176, sd 34)
#define CHUNK 4096          // COO items per block in place

typedef short short8 __attribute__((ext_vector_type(8)));
typedef float floatx4 __attribute__((ext_vector_type(4)));

__device__ inline ushort f2bf(float f) {              // RNE fp32 -> bf16
    uint u = __float_as_uint(f);
    u += 0x7FFF + ((u >> 16) & 1);
    return (ushort)(u >> 16);
}
__device__ inline float bflo(uint u) { return __uint_as_float(u << 16); }
__device__ inline float bfhi(uint u) { return __uint_as_float(u & 0xffff0000u); }

// ---------------------------------------------------------------- convert (all tensors, one dispatch)
__global__ void convert_all(const float* __restrict__ x,  ushort* __restrict__ xb,
                            const float* __restrict__ W1, ushort* __restrict__ W1b,
                            const float* __restrict__ W2, ushort* __restrict__ W2b,
                            const float* __restrict__ Wu, ushort* __restrict__ Wub) {
    const int nx = N_NODES * D / 4;
    const int n1 = H * D / 4;
    const int n2 = D * H / 4;
    const int nu = D * D / 4;
    int i = blockIdx.x * blockDim.x + threadIdx.x;
    const float* src; ushort* dst; int j = i;
    if (j < nx)                { src = x;  dst = xb;  }
    else if ((j -= nx) < n1)   { src = W1; dst = W1b; }
    else if ((j -= n1) < n2)   { src = W2; dst = W2b; }
    else if ((j -= n2) < nu)   { src = Wu; dst = Wub; }
    else return;
    float4 v = ((const float4*)src)[j];
    ushort4 o;
    o.x = f2bf(v.x); o.y = f2bf(v.y); o.z = f2bf(v.z); o.w = f2bf(v.w);
    ((ushort4*)dst)[j] = o;
}

// ---------------------------------------------------------------- bucketed CSR build
__global__ void bucket_place(const int* __restrict__ v_idx, const int* __restrict__ e_idx,
                             int* __restrict__ cntE, int* __restrict__ cntV,
                             int2* __restrict__ recE, int2* __restrict__ recV) {
    __shared__ int hE[NBE], hV[NBV];     // histogram, then reused as LDS cursor
    __shared__ int rE[NBE], rV[NBV];     // reserved base-within-bucket
    for (int i = threadIdx.x; i < NBE; i += 256) hE[i] = 0;
    for (int i = threadIdx.x; i < NBV; i += 256) hV[i] = 0;
    __syncthreads();
    int base = blockIdx.x * CHUNK;
    int end  = min(base + CHUNK, NNZ);
    int myE[16], myV[16];
    #pragma unroll
    for (int j = 0; j < 16; ++j) {
        int i = base + threadIdx.x + j * 256;
        myE[j] = -1; myV[j] = -1;
        if (i < end) {
            myE[j] = e_idx[i];
            myV[j] = v_idx[i];
            atomicAdd(&hE[myE[j] / BW], 1);
            atomicAdd(&hV[myV[j] / BW], 1);
        }
    }
    __syncthreads();
    for (int i = threadIdx.x; i < NBE; i += 256) {
        int c = hE[i];
        rE[i] = c ? atomicAdd(&cntE[i], c) : 0;
    }
    for (int i = threadIdx.x; i < NBV; i += 256) {
        int c = hV[i];
        rV[i] = c ? atomicAdd(&cntV[i], c) : 0;
    }
    __syncthreads();
    for (int i = threadIdx.x; i < NBE; i += 256) hE[i] = 0;
    for (int i = threadIdx.x; i < NBV; i += 256) hV[i] = 0;
    __syncthreads();
    #pragma unroll
    for (int j = 0; j < 16; ++j) {
        if (myE[j] >= 0) {
            int bk = myE[j] / BW;
            int p = rE[bk] + atomicAdd(&hE[bk], 1);
            recE[(size_t)bk * CAPE + p] = make_int2(myE[j], myV[j]);
            bk = myV[j] / BW;
            p = rV[bk] + atomicAdd(&hV[bk], 1);
            recV[(size_t)bk * CAPV + p] = make_int2(myV[j], myE[j]);
        }
    }
}

// one block per bucket -> per-segment {start,count} descriptors + recip + adjacency
__global__ void bucket_final(const int2* __restrict__ recE, const int* __restrict__ cntE,
                             const int2* __restrict__ recV, const int* __restrict__ cntV,
                             int2* __restrict__ e_sd, float* __restrict__ erecip, int* __restrict__ e_vert,
                             int2* __restrict__ v_sd, float* __restrict__ vrecip, int* __restrict__ v_edge) {
    __shared__ int hist[BW], scn[BW], cur[BW];
    const bool eSide = blockIdx.x < NBE;
    const int b = eSide ? blockIdx.x : blockIdx.x - NBE;
    const int cap   = eSide ? CAPE : CAPV;
    const int2* rec = (eSide ? recE : recV) + (size_t)b * cap;
    const int cnt   = (eSide ? cntE : cntV)[b];
    const int nseg  = eSide ? N_EDGES : N_NODES;
    int2* sd        = eSide ? e_sd : v_sd;
    float* recip    = eSide ? erecip : vrecip;
    int* outv       = (eSide ? e_vert : v_edge) + (size_t)b * cap;
    const int k0 = b * BW;

    for (int i = threadIdx.x; i < BW; i += 256) hist[i] = 0;
    __syncthreads();
    for (int i = threadIdx.x; i < cnt; i += 256)
        atomicAdd(&hist[rec[i].x - k0], 1);
    __syncthreads();

    if (threadIdx.x < 64) {
        int lane = threadIdx.x;
        int v0 = hist[lane];
        int a = v0;
        #pragma unroll
        for (int d = 1; d < 64; d <<= 1) {
            int u = __shfl_up(a, d, 64);
            if (lane >= d) a += u;
        }
        scn[lane] = a - v0;
        int tot0 = __shfl(a, 63, 64);
        int v1 = (lane < BW - 64) ? hist[64 + lane] : 0;
        int a1 = v1;
        #pragma unroll
        for (int d = 1; d < 64; d <<= 1) {
            int u = __shfl_up(a1, d, 64);
            if (lane >= d) a1 += u;
        }
        if (lane < BW - 64) scn[64 + lane] = tot0 + a1 - v1;
    }
    __syncthreads();

    const int gbase = b * cap;
    for (int i = threadIdx.x; i < BW; i += 256) {
        int seg = k0 + i;
        if (seg < nseg) {
            sd[seg] = make_int2(gbase + scn[i], hist[i]);
            recip[seg] = 1.0f / (float)max(hist[i], 1);
        }
        cur[i] = scn[i];
    }
    __syncthreads();
    for (int i = threadIdx.x; i < cnt; i += 256) {
        int2 r = rec[i];
        int p = atomicAdd(&cur[r.x - k0], 1);
        outv[p] = r.y;
    }
}

// ---------------------------------------------------------------- gather (one segment per 16-lane quarter)
// Each quarter owns one segment; its 16 lanes hold one full 256 B row (uint4 =
// 8 features/lane). 4 independent row loads in flight per round; no cross-
// quarter reduction. Epilogues: mean / relu(u+mean) / fused log_softmax head.
__global__ void gather_rows(const ushort* __restrict__ src,
                            const int2* __restrict__ sd,
                            const int* __restrict__ list,
                            const float* __restrict__ recip,
                            const ushort* __restrict__ uadd,
                            ushort* __restrict__ outbuf,
                            const float* __restrict__ Wa,
                            const float* __restrict__ ba,
                            float* __restrict__ headout,
                            int nseg) {
    long long gtid = (long long)blockIdx.x * blockDim.x + threadIdx.x;
    int seg = (int)(gtid >> 4);           // one segment per 16 lanes
    int ql  = threadIdx.x & 15;           // feature group: 8 features at ql*8
    if (seg >= nseg) return;
    int2 dsc = sd[seg];
    int s = dsc.x, cnt = dsc.y;
    const ushort* sp = src + ql * 8;

    float f0 = 0.f, f1 = 0.f, f2 = 0.f, f3 = 0.f;
    float f4 = 0.f, f5 = 0.f, f6 = 0.f, f7 = 0.f;

    int p = 0;
    for (; p + 4 <= cnt; p += 4) {
        int r0 = list[s + p + 0];
        int r1 = list[s + p + 1];
        int r2 = list[s + p + 2];
        int r3 = list[s + p + 3];
        uint4 t0 = *(const uint4*)(sp + (size_t)r0 * D);
        uint4 t1 = *(const uint4*)(sp + (size_t)r1 * D);
        uint4 t2 = *(const uint4*)(sp + (size_t)r2 * D);
        uint4 t3 = *(const uint4*)(sp + (size_t)r3 * D);
        f0 += bflo(t0.x) + bflo(t1.x) + bflo(t2.x) + bflo(t3.x);
        f1 += bfhi(t0.x) + bfhi(t1.x) + bfhi(t2.x) + bfhi(t3.x);
        f2 += bflo(t0.y) + bflo(t1.y) + bflo(t2.y) + bflo(t3.y);
        f3 += bfhi(t0.y) + bfhi(t1.y) + bfhi(t2.y) + bfhi(t3.y);
        f4 += bflo(t0.z) + bflo(t1.z) + bflo(t2.z) + bflo(t3.z);
        f5 += bfhi(t0.z) + bfhi(t1.z) + bfhi(t2.z) + bfhi(t3.z);
        f6 += bflo(t0.w) + bflo(t1.w) + bflo(t2.w) + bflo(t3.w);
        f7 += bfhi(t0.w) + bfhi(t1.w) + bfhi(t2.w) + bfhi(t3.w);
    }
    for (; p < cnt; ++p) {
        int r0 = list[s + p];
        uint4 t0 = *(const uint4*)(sp + (size_t)r0 * D);
        f0 += bflo(t0.x);  f1 += bfhi(t0.x);
        f2 += bflo(t0.y);  f3 += bfhi(t0.y);
        f4 += bflo(t0.z);  f5 += bfhi(t0.z);
        f6 += bflo(t0.w);  f7 += bfhi(t0.w);
    }

    float rc = recip[seg];
    f0 *= rc; f1 *= rc; f2 *= rc; f3 *= rc;
    f4 *= rc; f5 *= rc; f6 *= rc; f7 *= rc;
    if (uadd) {
        uint4 uv = *(const uint4*)(uadd + (size_t)seg * D + ql * 8);
        f0 = fmaxf(f0 + bflo(uv.x), 0.f);  f1 = fmaxf(f1 + bfhi(uv.x), 0.f);
        f2 = fmaxf(f2 + bflo(uv.y), 0.f);  f3 = fmaxf(f3 + bfhi(uv.y), 0.f);
        f4 = fmaxf(f4 + bflo(uv.z), 0.f);  f5 = fmaxf(f5 + bfhi(uv.z), 0.f);
        f6 = fmaxf(f6 + bflo(uv.w), 0.f);  f7 = fmaxf(f7 + bfhi(uv.w), 0.f);
    }
    if (headout) {
        // a = h @ Wa^T + ba, reduced across this quarter's 16 lanes
        float av[4];
        #pragma unroll
        for (int j = 0; j < 4; ++j) {
            const float* wr = Wa + j * D + ql * 8;
            float4 wA = *(const float4*)wr;
            float4 wB = *(const float4*)(wr + 4);
            float pj = f0 * wA.x + f1 * wA.y + f2 * wA.z + f3 * wA.w
                     + f4 * wB.x + f5 * wB.y + f6 * wB.z + f7 * wB.w;
            pj += __shfl_xor(pj, 1, 64);
            pj += __shfl_xor(pj, 2, 64);
            pj += __shfl_xor(pj, 4, 64);
            pj += __shfl_xor(pj, 8, 64);
            av[j] = pj + ba[j];
        }
        if (ql == 0) {
            float mx = fmaxf(fmaxf(av[0], av[1]), fmaxf(av[2], av[3]));
            float se = expf(av[0] - mx) + expf(av[1] - mx)
                     + expf(av[2] - mx) + expf(av[3] - mx);
            float lse = mx + logf(se);
            float4 o = make_float4(av[0] - lse, av[1] - lse, av[2] - lse, av[3] - lse);
            *(float4*)(headout + (size_t)seg * 4) = o;
        }
    } else {
        uint4 o;
        o.x = ((uint)f2bf(f1) << 16) | (uint)f2bf(f0);
        o.y = ((uint)f2bf(f3) << 16) | (uint)f2bf(f2);
        o.z = ((uint)f2bf(f5) << 16) | (uint)f2bf(f4);
        o.w = ((uint)f2bf(f7) << 16) | (uint)f2bf(f6);
        *(uint4*)(outbuf + (size_t)seg * D + ql * 8) = o;
    }
}

// ---------------------------------------------------------------- fused MLP + Wu
// m2 = relu(relu(h@W1^T+b1)@W2^T+b2)  and  u = h@Wu^T+bu  per 64-row block.
// 44 KB LDS -> 3 blocks/CU. Weight panels staged whole (1 barrier pair per
// 16 MFMAs); m1 processed in 64-col chunks (never materialized).
__launch_bounds__(256, 3)
__global__ void mlp_fused(const ushort* __restrict__ A,   // [M,128] bf16
                          const ushort* __restrict__ W1b, // [256,128] bf16
                          const float* __restrict__ b1,
                          const ushort* __restrict__ W2b, // [128,256] bf16
                          const float* __restrict__ b2,
                          const ushort* __restrict__ Wub, // [128,128] bf16
                          const float* __restrict__ bu,
                          ushort* __restrict__ m2out,     // [M,128] bf16
                          ushort* __restrict__ uout,      // [M,128] bf16
                          int M) {
    __shared__ ushort Af[64][136];                 // 17408 B
    __shared__ __align__(16) char Pbuf[18432];     // panel / epilogue union
    __shared__ ushort m1c[64][72];                 // 9216 B
    ushort* P = (ushort*)Pbuf;
    float (*Cs)[68] = (float(*)[68])Pbuf;

    const int tid = threadIdx.x;
    const int w = tid >> 6, lane = tid & 63;
    const int quad = lane >> 4, mrow = lane & 15;
    const int rowBase = blockIdx.x * 64;
    const int orow = tid >> 2;
    const int c0   = (tid & 3) << 4;

    // ---- stage A tile (64x128) ----
    #pragma unroll
    for (int r = 0; r < 4; ++r) {
        int idx = tid + r * 256;
        int row = idx >> 4;
        int c   = (idx & 15) << 3;
        uint4 av = make_uint4(0, 0, 0, 0);
        if (rowBase + row < M)
            av = *(const uint4*)(A + (size_t)(rowBase + row) * D + c);
        *(uint4*)&Af[row][c] = av;
    }

    // ---- phase C: u = Af @ Wu^T + bu (no relu) ----
    for (int n0 = 0; n0 < D; n0 += 64) {
        __syncthreads();
        #pragma unroll
        for (int r = 0; r < 4; ++r) {
            int idx = tid + r * 256;
            int row = idx >> 4;
            int c   = (idx & 15) << 3;
            *(uint4*)&P[row * 136 + c] = *(const uint4*)(Wub + (size_t)(n0 + row) * D + c);
        }
        __syncthreads();
        floatx4 acc[4] = {{0,0,0,0},{0,0,0,0},{0,0,0,0},{0,0,0,0}};
        #pragma unroll
        for (int k0 = 0; k0 < D; k0 += 32) {
            short8 af = *(const short8*)&Af[w * 16 + mrow][k0 + quad * 8];
            #pragma unroll
            for (int t = 0; t < 4; ++t) {
                short8 bfr = *(const short8*)&P[(t * 16 + mrow) * 136 + k0 + quad * 8];
                acc[t] = __builtin_amdgcn_mfma_f32_16x16x32_bf16(af, bfr, acc[t], 0, 0, 0);
            }
        }
        __syncthreads();
        #pragma unroll
        for (int t = 0; t < 4; ++t)
            #pragma unroll
            for (int r = 0; r < 4; ++r)
                Cs[w * 16 + quad * 4 + r][t * 16 + mrow] = acc[t][r];
        __syncthreads();
        if (rowBase + orow < M) {
            union { ushort u16[16]; uint4 u4[2]; } ov;
            #pragma unroll
            for (int j4 = 0; j4 < 4; ++j4) {
                float4 bb = *(const float4*)(bu + n0 + c0 + j4 * 4);
                float bjv[4] = {bb.x, bb.y, bb.z, bb.w};
                #pragma unroll
                for (int j = 0; j < 4; ++j)
                    ov.u16[j4 * 4 + j] = f2bf(Cs[orow][c0 + j4 * 4 + j] + bjv[j]);
            }
            ushort* cp = uout + (size_t)(rowBase + orow) * D + n0 + c0;
            *(uint4*)cp = ov.u4[0];
            *(uint4*)(cp + 8) = ov.u4[1];
        }
    }

    // ---- interleaved phase A/B over 64-col m1 chunks ----
    floatx4 acc2[8] = {{0,0,0,0},{0,0,0,0},{0,0,0,0},{0,0,0,0},
                       {0,0,0,0},{0,0,0,0},{0,0,0,0},{0,0,0,0}};
    for (int kc = 0; kc < 4; ++kc) {
        __syncthreads();
        #pragma unroll
        for (int r = 0; r < 4; ++r) {
            int idx = tid + r * 256;
            int row = idx >> 4;
            int c   = (idx & 15) << 3;
            *(uint4*)&P[row * 136 + c] = *(const uint4*)(W1b + (size_t)(kc * 64 + row) * D + c);
        }
        __syncthreads();
        floatx4 acc1[4] = {{0,0,0,0},{0,0,0,0},{0,0,0,0},{0,0,0,0}};
        #pragma unroll
        for (int k0 = 0; k0 < D; k0 += 32) {
            short8 af = *(const short8*)&Af[w * 16 + mrow][k0 + quad * 8];
            #pragma unroll
            for (int t = 0; t < 4; ++t) {
                short8 bfr = *(const short8*)&P[(t * 16 + mrow) * 136 + k0 + quad * 8];
                acc1[t] = __builtin_amdgcn_mfma_f32_16x16x32_bf16(af, bfr, acc1[t], 0, 0, 0);
            }
        }
        #pragma unroll
        for (int t = 0; t < 4; ++t) {
            float bb = b1[kc * 64 + t * 16 + mrow];
            #pragma unroll
            for (int r = 0; r < 4; ++r)
                m1c[w * 16 + quad * 4 + r][t * 16 + mrow] = f2bf(fmaxf(acc1[t][r] + bb, 0.f));
        }
        __syncthreads();   // all waves done reading W1 panel
        #pragma unroll
        for (int r = 0; r < 4; ++r) {
            int idx = tid + r * 256;      // 0..1023
            int row = idx >> 3;           // 0..127
            int c8  = (idx & 7) << 3;     // 0..56
            *(uint4*)&P[row * 72 + c8] = *(const uint4*)(W2b + (size_t)row * H + kc * 64 + c8);
        }
        __syncthreads();
        #pragma unroll
        for (int k0 = 0; k0 < 64; k0 += 32) {
            short8 af = *(const short8*)&m1c[w * 16 + mrow][k0 + quad * 8];
            #pragma unroll
            for (int t2 = 0; t2 < 8; ++t2) {
                short8 bfr = *(const short8*)&P[(t2 * 16 + mrow) * 72 + k0 + quad * 8];
                acc2[t2] = __builtin_amdgcn_mfma_f32_16x16x32_bf16(af, bfr, acc2[t2], 0, 0, 0);
            }
        }
    }

    // ---- m2 epilogue (two 64-col halves through Cs) ----
    #pragma unroll
    for (int hh = 0; hh < 2; ++hh) {
        __syncthreads();
        #pragma unroll
        for (int t = 0; t < 4; ++t)
            #pragma unroll
            for (int r = 0; r < 4; ++r)
                Cs[w * 16 + quad * 4 + r][t * 16 + mrow] = acc2[hh * 4 + t][r];
        __syncthreads();
        if (rowBase + orow < M) {
            union { ushort u16[16]; uint4 u4[2]; } ov;
            #pragma unroll
            for (int j4 = 0; j4 < 4; ++j4) {
                float4 bb = *(const float4*)(b2 + hh * 64 + c0 + j4 * 4);
                float bjv[4] = {bb.x, bb.y, bb.z, bb.w};
                #pragma unroll
                for (int j = 0; j < 4; ++j) {
                    float v = Cs[orow][c0 + j4 * 4 + j] + bjv[j];
                    ov.u16[j4 * 4 + j] = f2bf(fmaxf(v, 0.f));
                }
            }
            ushort* cp = m2out + (size_t)(rowBase + orow) * D + hh * 64 + c0;
            *(uint4*)cp = ov.u4[0];
            *(uint4*)(cp + 8) = ov.u4[1];
        }
    }
}

// ---------------------------------------------------------------- launch
extern "C" void kernel_launch(void* const* d_in, const int* in_sizes, int n_in,
                              void* d_out, int out_size, void* d_ws, size_t ws_size,
                              hipStream_t stream) {
    const float* x     = (const float*)d_in[0];
    const int*   v_idx = (const int*)d_in[1];
    const int*   e_idx = (const int*)d_in[2];
    const float* W1    = (const float*)d_in[3];
    const float* b1    = (const float*)d_in[4];
    const float* W2    = (const float*)d_in[5];
    const float* b2    = (const float*)d_in[6];
    const float* Wu    = (const float*)d_in[7];
    const float* bu    = (const float*)d_in[8];
    const float* Wa    = (const float*)d_in[9];
    const float* ba    = (const float*)d_in[10];
    float* out = (float*)d_out;

    char* wsp = (char*)d_ws;
    auto alloc = [&](size_t bytes) -> char* {
        char* p = wsp;
        wsp += (bytes + 255) & ~(size_t)255;
        return p;
    };

    ushort* xb     = (ushort*)alloc((size_t)N_NODES * D * 2);
    ushort* hA     = (ushort*)alloc((size_t)N_NODES * D * 2);
    ushort* m2b    = (ushort*)alloc((size_t)N_NODES * D * 2);
    ushort* ub     = (ushort*)alloc((size_t)N_NODES * D * 2);
    ushort* e_feat = (ushort*)alloc((size_t)N_EDGES * D * 2);
    ushort* W1b    = (ushort*)alloc((size_t)H * D * 2);
    ushort* W2b    = (ushort*)alloc((size_t)D * H * 2);
    ushort* Wub    = (ushort*)alloc((size_t)D * D * 2);
    int*    e_vert = (int*)alloc((size_t)NBE * CAPE * 4);
    int*    v_edge = (int*)alloc((size_t)NBV * CAPV * 4);
    int2*   recE   = (int2*)alloc((size_t)NBE * CAPE * 8);
    int2*   recV   = (int2*)alloc((size_t)NBV * CAPV * 8);
    int*    cntE   = (int*)alloc((size_t)(NBE + NBV) * 4);   // one memset covers both
    int*    cntV   = cntE + NBE;
    int2*   e_sd   = (int2*)alloc((size_t)N_EDGES * 8);
    int2*   v_sd   = (int2*)alloc((size_t)N_NODES * 8);
    float*  erecip = (float*)alloc((size_t)N_EDGES * 4);
    float*  vrecip = (float*)alloc((size_t)N_NODES * 4);

    const int cooBlocks = (NNZ + CHUNK - 1) / CHUNK;   // 147
    const int convTotal = N_NODES * D / 4 + H * D / 4 + D * H / 4 + D * D / 4;

    convert_all<<<(convTotal + 255) / 256, 256, 0, stream>>>(
        x, xb, W1, W1b, W2, W2b, Wu, Wub);

    // ---- bucketed CSR build (single placement pass, padded buckets) ----
    hipMemsetAsync(cntE, 0, (size_t)(NBE + NBV) * 4, stream);
    bucket_place<<<cooBlocks, 256, 0, stream>>>(v_idx, e_idx, cntE, cntV, recE, recV);
    bucket_final<<<NBE + NBV, 256, 0, stream>>>(recE, cntE, recV, cntV,
                                                e_sd, erecip, e_vert,
                                                v_sd, vrecip, v_edge);

    const int gridM = (N_NODES + 63) / 64;              // 782
    const int gEdge = (N_EDGES * 16 + 255) / 256;       // 1563
    const int gVert = (N_NODES * 16 + 255) / 256;       // 3125

    const ushort* h = xb;
    for (int depth = 0; depth < 2; ++depth) {
        mlp_fused<<<gridM, 256, 0, stream>>>(h, W1b, b1, W2b, b2, Wub, bu, m2b, ub, N_NODES);
        // e_feat[e] = erecip[e] * sum m2[v in e]
        gather_rows<<<gEdge, 256, 0, stream>>>(
            m2b, e_sd, e_vert, erecip, nullptr, e_feat, nullptr, nullptr, nullptr, N_EDGES);
        if (depth == 0) {
            // h1[v] = relu(u[v] + vrecip[v] * sum e_feat[e in v])
            gather_rows<<<gVert, 256, 0, stream>>>(
                e_feat, v_sd, v_edge, vrecip, ub, hA, nullptr, nullptr, nullptr, N_NODES);
            h = hA;
        } else {
            // final: fused head -> out = log_softmax(relu(u+agg) @ Wa^T + ba)
            gather_rows<<<gVert, 256, 0, stream>>>(
                e_feat, v_sd, v_edge, vrecip, ub, nullptr, Wa, ba, out, N_NODES);
        }
    }
}

// Round 12
// 260.927 us; speedup vs baseline: 17.3334x; 1.0334x over previous
//
#include <hip/hip_runtime.h>
#include <hip/hip_bf16.h>
#include <math.h>

#define N_NODES 50000
#define N_EDGES 25000
#define NNZ     600000
#define D       128
#define H       256

#define BW    98            // bucket width (segments per bucket)
#define NBE   256           // ceil(25000/98)
#define NBV   511           // ceil(50000/98)
#define CAPE  3072          // per-bucket record capacity, E (mean 2352, sd 48)
#define CAPV  1536          // per-bucket record capacity, V (mean 1176, sd 34)
#define CHUNK 4096          // COO items per block in place

typedef short short8 __attribute__((ext_vector_type(8)));
typedef float floatx4 __attribute__((ext_vector_type(4)));

__device__ inline ushort f2bf(float f) {              // RNE fp32 -> bf16
    uint u = __float_as_uint(f);
    u += 0x7FFF + ((u >> 16) & 1);
    return (ushort)(u >> 16);
}
__device__ inline float bflo(uint u) { return __uint_as_float(u << 16); }
__device__ inline float bfhi(uint u) { return __uint_as_float(u & 0xffff0000u); }

// ---------------------------------------------------------------- convert (weights only)
__global__ void convert_weights(const float* __restrict__ W1, ushort* __restrict__ W1b,
                                const float* __restrict__ W2, ushort* __restrict__ W2b,
                                const float* __restrict__ Wu, ushort* __restrict__ Wub) {
    const int n1 = H * D / 4;
    const int n2 = D * H / 4;
    const int nu = D * D / 4;
    int j = blockIdx.x * blockDim.x + threadIdx.x;
    const float* src; ushort* dst;
    if (j < n1)                { src = W1; dst = W1b; }
    else if ((j -= n1) < n2)   { src = W2; dst = W2b; }
    else if ((j -= n2) < nu)   { src = Wu; dst = Wub; }
    else return;
    float4 v = ((const float4*)src)[j];
    ushort4 o;
    o.x = f2bf(v.x); o.y = f2bf(v.y); o.z = f2bf(v.z); o.w = f2bf(v.w);
    ((ushort4*)dst)[j] = o;
}

// ---------------------------------------------------------------- bucketed CSR build
__global__ void bucket_place(const int* __restrict__ v_idx, const int* __restrict__ e_idx,
                             int* __restrict__ cntE, int* __restrict__ cntV,
                             int2* __restrict__ recE, int2* __restrict__ recV) {
    __shared__ int hE[NBE], hV[NBV];     // histogram, then reused as LDS cursor
    __shared__ int rE[NBE], rV[NBV];     // reserved base-within-bucket
    for (int i = threadIdx.x; i < NBE; i += 256) hE[i] = 0;
    for (int i = threadIdx.x; i < NBV; i += 256) hV[i] = 0;
    __syncthreads();
    int base = blockIdx.x * CHUNK;
    int end  = min(base + CHUNK, NNZ);
    int myE[16], myV[16];
    #pragma unroll
    for (int j = 0; j < 16; ++j) {
        int i = base + threadIdx.x + j * 256;
        myE[j] = -1; myV[j] = -1;
        if (i < end) {
            myE[j] = e_idx[i];
            myV[j] = v_idx[i];
            atomicAdd(&hE[myE[j] / BW], 1);
            atomicAdd(&hV[myV[j] / BW], 1);
        }
    }
    __syncthreads();
    for (int i = threadIdx.x; i < NBE; i += 256) {
        int c = hE[i];
        rE[i] = c ? atomicAdd(&cntE[i], c) : 0;
    }
    for (int i = threadIdx.x; i < NBV; i += 256) {
        int c = hV[i];
        rV[i] = c ? atomicAdd(&cntV[i], c) : 0;
    }
    __syncthreads();
    for (int i = threadIdx.x; i < NBE; i += 256) hE[i] = 0;
    for (int i = threadIdx.x; i < NBV; i += 256) hV[i] = 0;
    __syncthreads();
    #pragma unroll
    for (int j = 0; j < 16; ++j) {
        if (myE[j] >= 0) {
            int bk = myE[j] / BW;
            int p = rE[bk] + atomicAdd(&hE[bk], 1);
            recE[(size_t)bk * CAPE + p] = make_int2(myE[j], myV[j]);
            bk = myV[j] / BW;
            p = rV[bk] + atomicAdd(&hV[bk], 1);
            recV[(size_t)bk * CAPV + p] = make_int2(myV[j], myE[j]);
        }
    }
}

// one block per bucket -> per-segment {start,count} descriptors + recip + adjacency
__global__ void bucket_final(const int2* __restrict__ recE, const int* __restrict__ cntE,
                             const int2* __restrict__ recV, const int* __restrict__ cntV,
                             int2* __restrict__ e_sd, float* __restrict__ erecip, int* __restrict__ e_vert,
                             int2* __restrict__ v_sd, float* __restrict__ vrecip, int* __restrict__ v_edge) {
    __shared__ int hist[BW], scn[BW], cur[BW];
    const bool eSide = blockIdx.x < NBE;
    const int b = eSide ? blockIdx.x : blockIdx.x - NBE;
    const int cap   = eSide ? CAPE : CAPV;
    const int2* rec = (eSide ? recE : recV) + (size_t)b * cap;
    const int cnt   = (eSide ? cntE : cntV)[b];
    const int nseg  = eSide ? N_EDGES : N_NODES;
    int2* sd        = eSide ? e_sd : v_sd;
    float* recip    = eSide ? erecip : vrecip;
    int* outv       = (eSide ? e_vert : v_edge) + (size_t)b * cap;
    const int k0 = b * BW;

    for (int i = threadIdx.x; i < BW; i += 256) hist[i] = 0;
    __syncthreads();
    for (int i = threadIdx.x; i < cnt; i += 256)
        atomicAdd(&hist[rec[i].x - k0], 1);
    __syncthreads();

    if (threadIdx.x < 64) {
        int lane = threadIdx.x;
        int v0 = hist[lane];
        int a = v0;
        #pragma unroll
        for (int d = 1; d < 64; d <<= 1) {
            int u = __shfl_up(a, d, 64);
            if (lane >= d) a += u;
        }
        scn[lane] = a - v0;
        int tot0 = __shfl(a, 63, 64);
        int v1 = (lane < BW - 64) ? hist[64 + lane] : 0;
        int a1 = v1;
        #pragma unroll
        for (int d = 1; d < 64; d <<= 1) {
            int u = __shfl_up(a1, d, 64);
            if (lane >= d) a1 += u;
        }
        if (lane < BW - 64) scn[64 + lane] = tot0 + a1 - v1;
    }
    __syncthreads();

    const int gbase = b * cap;
    for (int i = threadIdx.x; i < BW; i += 256) {
        int seg = k0 + i;
        if (seg < nseg) {
            sd[seg] = make_int2(gbase + scn[i], hist[i]);
            recip[seg] = 1.0f / (float)max(hist[i], 1);
        }
        cur[i] = scn[i];
    }
    __syncthreads();
    for (int i = threadIdx.x; i < cnt; i += 256) {
        int2 r = rec[i];
        int p = atomicAdd(&cur[r.x - k0], 1);
        outv[p] = r.y;
    }
}

// ---------------------------------------------------------------- gather (one segment per 16-lane quarter)
__global__ void gather_rows(const ushort* __restrict__ src,
                            const int2* __restrict__ sd,
                            const int* __restrict__ list,
                            const float* __restrict__ recip,
                            const ushort* __restrict__ uadd,
                            ushort* __restrict__ outbuf,
                            const float* __restrict__ Wa,
                            const float* __restrict__ ba,
                            float* __restrict__ headout,
                            int nseg) {
    long long gtid = (long long)blockIdx.x * blockDim.x + threadIdx.x;
    int seg = (int)(gtid >> 4);           // one segment per 16 lanes
    int ql  = threadIdx.x & 15;           // feature group: 8 features at ql*8
    if (seg >= nseg) return;
    int2 dsc = sd[seg];
    int s = dsc.x, cnt = dsc.y;
    const ushort* sp = src + ql * 8;

    float f0 = 0.f, f1 = 0.f, f2 = 0.f, f3 = 0.f;
    float f4 = 0.f, f5 = 0.f, f6 = 0.f, f7 = 0.f;

    int p = 0;
    for (; p + 4 <= cnt; p += 4) {
        int r0 = list[s + p + 0];
        int r1 = list[s + p + 1];
        int r2 = list[s + p + 2];
        int r3 = list[s + p + 3];
        uint4 t0 = *(const uint4*)(sp + (size_t)r0 * D);
        uint4 t1 = *(const uint4*)(sp + (size_t)r1 * D);
        uint4 t2 = *(const uint4*)(sp + (size_t)r2 * D);
        uint4 t3 = *(const uint4*)(sp + (size_t)r3 * D);
        f0 += bflo(t0.x) + bflo(t1.x) + bflo(t2.x) + bflo(t3.x);
        f1 += bfhi(t0.x) + bfhi(t1.x) + bfhi(t2.x) + bfhi(t3.x);
        f2 += bflo(t0.y) + bflo(t1.y) + bflo(t2.y) + bflo(t3.y);
        f3 += bfhi(t0.y) + bfhi(t1.y) + bfhi(t2.y) + bfhi(t3.y);
        f4 += bflo(t0.z) + bflo(t1.z) + bflo(t2.z) + bflo(t3.z);
        f5 += bfhi(t0.z) + bfhi(t1.z) + bfhi(t2.z) + bfhi(t3.z);
        f6 += bflo(t0.w) + bflo(t1.w) + bflo(t2.w) + bflo(t3.w);
        f7 += bfhi(t0.w) + bfhi(t1.w) + bfhi(t2.w) + bfhi(t3.w);
    }
    for (; p < cnt; ++p) {
        int r0 = list[s + p];
        uint4 t0 = *(const uint4*)(sp + (size_t)r0 * D);
        f0 += bflo(t0.x);  f1 += bfhi(t0.x);
        f2 += bflo(t0.y);  f3 += bfhi(t0.y);
        f4 += bflo(t0.z);  f5 += bfhi(t0.z);
        f6 += bflo(t0.w);  f7 += bfhi(t0.w);
    }

    float rc = recip[seg];
    f0 *= rc; f1 *= rc; f2 *= rc; f3 *= rc;
    f4 *= rc; f5 *= rc; f6 *= rc; f7 *= rc;
    if (uadd) {
        uint4 uv = *(const uint4*)(uadd + (size_t)seg * D + ql * 8);
        f0 = fmaxf(f0 + bflo(uv.x), 0.f);  f1 = fmaxf(f1 + bfhi(uv.x), 0.f);
        f2 = fmaxf(f2 + bflo(uv.y), 0.f);  f3 = fmaxf(f3 + bfhi(uv.y), 0.f);
        f4 = fmaxf(f4 + bflo(uv.z), 0.f);  f5 = fmaxf(f5 + bfhi(uv.z), 0.f);
        f6 = fmaxf(f6 + bflo(uv.w), 0.f);  f7 = fmaxf(f7 + bfhi(uv.w), 0.f);
    }
    if (headout) {
        float av[4];
        #pragma unroll
        for (int j = 0; j < 4; ++j) {
            const float* wr = Wa + j * D + ql * 8;
            float4 wA = *(const float4*)wr;
            float4 wB = *(const float4*)(wr + 4);
            float pj = f0 * wA.x + f1 * wA.y + f2 * wA.z + f3 * wA.w
                     + f4 * wB.x + f5 * wB.y + f6 * wB.z + f7 * wB.w;
            pj += __shfl_xor(pj, 1, 64);
            pj += __shfl_xor(pj, 2, 64);
            pj += __shfl_xor(pj, 4, 64);
            pj += __shfl_xor(pj, 8, 64);
            av[j] = pj + ba[j];
        }
        if (ql == 0) {
            float mx = fmaxf(fmaxf(av[0], av[1]), fmaxf(av[2], av[3]));
            float se = expf(av[0] - mx) + expf(av[1] - mx)
                     + expf(av[2] - mx) + expf(av[3] - mx);
            float lse = mx + logf(se);
            float4 o = make_float4(av[0] - lse, av[1] - lse, av[2] - lse, av[3] - lse);
            *(float4*)(headout + (size_t)seg * 4) = o;
        }
    } else {
        uint4 o;
        o.x = ((uint)f2bf(f1) << 16) | (uint)f2bf(f0);
        o.y = ((uint)f2bf(f3) << 16) | (uint)f2bf(f2);
        o.z = ((uint)f2bf(f5) << 16) | (uint)f2bf(f4);
        o.w = ((uint)f2bf(f7) << 16) | (uint)f2bf(f6);
        *(uint4*)(outbuf + (size_t)seg * D + ql * 8) = o;
    }
}

// ---------------------------------------------------------------- fused MLP + Wu (128-row blocks)
// m2 = relu(relu(h@W1^T+b1)@W2^T+b2) and u = h@Wu^T+bu per 128-row block.
// LDS 70 KB -> 2 blocks/CU; grid 391 co-resident in one round.
// Epilogue transposes use the R7-R9-proven block-barriered Cs pattern
// (64x68 shared slab unioned with m1c): write -> sync -> read -> sync.
// A input may be fp32 (depth 0, converts in staging) or bf16.
__launch_bounds__(256, 2)
__global__ void mlp_fused(const void* __restrict__ Aptr, int a_fp32,
                          const ushort* __restrict__ W1b, // [256,128] bf16
                          const float* __restrict__ b1,
                          const ushort* __restrict__ W2b, // [128,256] bf16
                          const float* __restrict__ b2,
                          const ushort* __restrict__ Wub, // [128,128] bf16
                          const float* __restrict__ bu,
                          ushort* __restrict__ m2out,     // [M,128] bf16
                          ushort* __restrict__ uout,      // [M,128] bf16
                          int M) {
    __shared__ ushort Af[128][136];                // 34816 B
    __shared__ __align__(16) char Pbuf[18432];     // weight panel buffer
    __shared__ __align__(16) char UB[18432];       // m1c / Cs union
    ushort* P = (ushort*)Pbuf;
    ushort (*m1c)[72] = (ushort(*)[72])UB;
    float (*Cs)[68] = (float(*)[68])UB;            // 64x68 fp32 = 17408 B

    const int tid = threadIdx.x;
    const int w = tid >> 6, lane = tid & 63;
    const int quad = lane >> 4, mrow = lane & 15;
    const int rowBase = blockIdx.x * 128;
    const int orow = tid >> 2;                     // 0..63 epilogue read row
    const int c0   = (tid & 3) << 4;               // epilogue read col group

    // ---- stage A tile (128x128), fp32 or bf16 source ----
    #pragma unroll
    for (int r = 0; r < 8; ++r) {
        int idx = tid + r * 256;          // 0..2047
        int row = idx >> 4;               // 0..127
        int c   = (idx & 15) << 3;        // 0,8,...,120
        uint4 av = make_uint4(0, 0, 0, 0);
        if (rowBase + row < M) {
            if (a_fp32) {
                const float* ap = (const float*)Aptr + (size_t)(rowBase + row) * D + c;
                float4 va = *(const float4*)ap;
                float4 vb = *(const float4*)(ap + 4);
                av.x = ((uint)f2bf(va.y) << 16) | (uint)f2bf(va.x);
                av.y = ((uint)f2bf(va.w) << 16) | (uint)f2bf(va.z);
                av.z = ((uint)f2bf(vb.y) << 16) | (uint)f2bf(vb.x);
                av.w = ((uint)f2bf(vb.w) << 16) | (uint)f2bf(vb.z);
            } else {
                av = *(const uint4*)((const ushort*)Aptr + (size_t)(rowBase + row) * D + c);
            }
        }
        *(uint4*)&Af[row][c] = av;
    }

    // ---- phase C: u = Af @ Wu^T + bu (no relu) ----
    for (int n0 = 0; n0 < D; n0 += 64) {
        __syncthreads();
        #pragma unroll
        for (int r = 0; r < 4; ++r) {
            int idx = tid + r * 256;
            int row = idx >> 4;
            int c   = (idx & 15) << 3;
            *(uint4*)&P[row * 136 + c] = *(const uint4*)(Wub + (size_t)(n0 + row) * D + c);
        }
        __syncthreads();
        #pragma unroll
        for (int rg = 0; rg < 2; ++rg) {
            floatx4 acc[4] = {{0,0,0,0},{0,0,0,0},{0,0,0,0},{0,0,0,0}};
            #pragma unroll
            for (int k0 = 0; k0 < D; k0 += 32) {
                short8 af = *(const short8*)&Af[rg * 64 + w * 16 + mrow][k0 + quad * 8];
                #pragma unroll
                for (int t = 0; t < 4; ++t) {
                    short8 bfr = *(const short8*)&P[(t * 16 + mrow) * 136 + k0 + quad * 8];
                    acc[t] = __builtin_amdgcn_mfma_f32_16x16x32_bf16(af, bfr, acc[t], 0, 0, 0);
                }
            }
            __syncthreads();   // prior Cs reads (or other waves' MFMA) done
            #pragma unroll
            for (int t = 0; t < 4; ++t)
                #pragma unroll
                for (int r = 0; r < 4; ++r)
                    Cs[w * 16 + quad * 4 + r][t * 16 + mrow] = acc[t][r];
            __syncthreads();
            int grow = rowBase + rg * 64 + orow;
            if (grow < M) {
                union { ushort u16[16]; uint4 u4[2]; } ov;
                #pragma unroll
                for (int j4 = 0; j4 < 4; ++j4) {
                    float4 cv = *(const float4*)&Cs[orow][c0 + j4 * 4];
                    float4 bb = *(const float4*)(bu + n0 + c0 + j4 * 4);
                    ov.u16[j4 * 4 + 0] = f2bf(cv.x + bb.x);
                    ov.u16[j4 * 4 + 1] = f2bf(cv.y + bb.y);
                    ov.u16[j4 * 4 + 2] = f2bf(cv.z + bb.z);
                    ov.u16[j4 * 4 + 3] = f2bf(cv.w + bb.w);
                }
                ushort* cp = uout + (size_t)grow * D + n0 + c0;
                *(uint4*)cp = ov.u4[0];
                *(uint4*)(cp + 8) = ov.u4[1];
            }
            __syncthreads();   // reads done before next round's Cs overwrite
        }
    }

    // ---- interleaved phase A/B over 64-col m1 chunks ----
    floatx4 acc2[2][8] = {};
    for (int kc = 0; kc < 4; ++kc) {
        __syncthreads();
        #pragma unroll
        for (int r = 0; r < 4; ++r) {
            int idx = tid + r * 256;
            int row = idx >> 4;
            int c   = (idx & 15) << 3;
            *(uint4*)&P[row * 136 + c] = *(const uint4*)(W1b + (size_t)(kc * 64 + row) * D + c);
        }
        __syncthreads();
        #pragma unroll
        for (int rg = 0; rg < 2; ++rg) {
            floatx4 acc1[4] = {{0,0,0,0},{0,0,0,0},{0,0,0,0},{0,0,0,0}};
            #pragma unroll
            for (int k0 = 0; k0 < D; k0 += 32) {
                short8 af = *(const short8*)&Af[rg * 64 + w * 16 + mrow][k0 + quad * 8];
                #pragma unroll
                for (int t = 0; t < 4; ++t) {
                    short8 bfr = *(const short8*)&P[(t * 16 + mrow) * 136 + k0 + quad * 8];
                    acc1[t] = __builtin_amdgcn_mfma_f32_16x16x32_bf16(af, bfr, acc1[t], 0, 0, 0);
                }
            }
            #pragma unroll
            for (int t = 0; t < 4; ++t) {
                float bb = b1[kc * 64 + t * 16 + mrow];
                #pragma unroll
                for (int r = 0; r < 4; ++r)
                    m1c[rg * 64 + w * 16 + quad * 4 + r][t * 16 + mrow] =
                        f2bf(fmaxf(acc1[t][r] + bb, 0.f));
            }
        }
        __syncthreads();   // all waves done reading W1 panel + m1c written
        #pragma unroll
        for (int r = 0; r < 4; ++r) {
            int idx = tid + r * 256;      // 0..1023
            int row = idx >> 3;           // 0..127
            int c8  = (idx & 7) << 3;     // 0..56
            *(uint4*)&P[row * 72 + c8] = *(const uint4*)(W2b + (size_t)row * H + kc * 64 + c8);
        }
        __syncthreads();
        #pragma unroll
        for (int rg = 0; rg < 2; ++rg) {
            #pragma unroll
            for (int k0 = 0; k0 < 64; k0 += 32) {
                short8 af = *(const short8*)&m1c[rg * 64 + w * 16 + mrow][k0 + quad * 8];
                #pragma unroll
                for (int t2 = 0; t2 < 8; ++t2) {
                    short8 bfr = *(const short8*)&P[(t2 * 16 + mrow) * 72 + k0 + quad * 8];
                    acc2[rg][t2] = __builtin_amdgcn_mfma_f32_16x16x32_bf16(af, bfr, acc2[rg][t2], 0, 0, 0);
                }
            }
        }
    }

    // ---- m2 epilogue (block-barriered Cs rounds) ----
    #pragma unroll
    for (int rg = 0; rg < 2; ++rg) {
        #pragma unroll
        for (int hh = 0; hh < 2; ++hh) {
            __syncthreads();   // m1c reads (first round) / Cs reads (later) done
            #pragma unroll
            for (int t = 0; t < 4; ++t)
                #pragma unroll
                for (int r = 0; r < 4; ++r)
                    Cs[w * 16 + quad * 4 + r][t * 16 + mrow] = acc2[rg][hh * 4 + t][r];
            __syncthreads();
            int grow = rowBase + rg * 64 + orow;
            if (grow < M) {
                union { ushort u16[16]; uint4 u4[2]; } ov;
                #pragma unroll
                for (int j4 = 0; j4 < 4; ++j4) {
                    float4 cv = *(const float4*)&Cs[orow][c0 + j4 * 4];
                    float4 bb = *(const float4*)(b2 + hh * 64 + c0 + j4 * 4);
                    ov.u16[j4 * 4 + 0] = f2bf(fmaxf(cv.x + bb.x, 0.f));
                    ov.u16[j4 * 4 + 1] = f2bf(fmaxf(cv.y + bb.y, 0.f));
                    ov.u16[j4 * 4 + 2] = f2bf(fmaxf(cv.z + bb.z, 0.f));
                    ov.u16[j4 * 4 + 3] = f2bf(fmaxf(cv.w + bb.w, 0.f));
                }
                ushort* cp = m2out + (size_t)grow * D + hh * 64 + c0;
                *(uint4*)cp = ov.u4[0];
                *(uint4*)(cp + 8) = ov.u4[1];
            }
        }
    }
}

// ---------------------------------------------------------------- launch
extern "C" void kernel_launch(void* const* d_in, const int* in_sizes, int n_in,
                              void* d_out, int out_size, void* d_ws, size_t ws_size,
                              hipStream_t stream) {
    const float* x     = (const float*)d_in[0];
    const int*   v_idx = (const int*)d_in[1];
    const int*   e_idx = (const int*)d_in[2];
    const float* W1    = (const float*)d_in[3];
    const float* b1    = (const float*)d_in[4];
    const float* W2    = (const float*)d_in[5];
    const float* b2    = (const float*)d_in[6];
    const float* Wu    = (const float*)d_in[7];
    const float* bu    = (const float*)d_in[8];
    const float* Wa    = (const float*)d_in[9];
    const float* ba    = (const float*)d_in[10];
    float* out = (float*)d_out;

    char* wsp = (char*)d_ws;
    auto alloc = [&](size_t bytes) -> char* {
        char* p = wsp;
        wsp += (bytes + 255) & ~(size_t)255;
        return p;
    };

    ushort* hA     = (ushort*)alloc((size_t)N_NODES * D * 2);
    ushort* m2b    = (ushort*)alloc((size_t)N_NODES * D * 2);
    ushort* ub     = (ushort*)alloc((size_t)N_NODES * D * 2);
    ushort* e_feat = (ushort*)alloc((size_t)N_EDGES * D * 2);
    ushort* W1b    = (ushort*)alloc((size_t)H * D * 2);
    ushort* W2b    = (ushort*)alloc((size_t)D * H * 2);
    ushort* Wub    = (ushort*)alloc((size_t)D * D * 2);
    int*    e_vert = (int*)alloc((size_t)NBE * CAPE * 4);
    int*    v_edge = (int*)alloc((size_t)NBV * CAPV * 4);
    int2*   recE   = (int2*)alloc((size_t)NBE * CAPE * 8);
    int2*   recV   = (int2*)alloc((size_t)NBV * CAPV * 8);
    int*    cntE   = (int*)alloc((size_t)(NBE + NBV) * 4);   // one memset covers both
    int*    cntV   = cntE + NBE;
    int2*   e_sd   = (int2*)alloc((size_t)N_EDGES * 8);
    int2*   v_sd   = (int2*)alloc((size_t)N_NODES * 8);
    float*  erecip = (float*)alloc((size_t)N_EDGES * 4);
    float*  vrecip = (float*)alloc((size_t)N_NODES * 4);

    const int cooBlocks = (NNZ + CHUNK - 1) / CHUNK;   // 147
    const int convTotal = H * D / 4 + D * H / 4 + D * D / 4;

    convert_weights<<<(convTotal + 255) / 256, 256, 0, stream>>>(
        W1, W1b, W2, W2b, Wu, Wub);

    // ---- bucketed CSR build (single placement pass, padded buckets) ----
    hipMemsetAsync(cntE, 0, (size_t)(NBE + NBV) * 4, stream);
    bucket_place<<<cooBlocks, 256, 0, stream>>>(v_idx, e_idx, cntE, cntV, recE, recV);
    bucket_final<<<NBE + NBV, 256, 0, stream>>>(recE, cntE, recV, cntV,
                                                e_sd, erecip, e_vert,
                                                v_sd, vrecip, v_edge);

    const int gridM = (N_NODES + 127) / 128;            // 391
    const int gEdge = (N_EDGES * 16 + 255) / 256;       // 1563
    const int gVert = (N_NODES * 16 + 255) / 256;       // 3125

    const void* h = x;
    int h_fp32 = 1;
    for (int depth = 0; depth < 2; ++depth) {
        mlp_fused<<<gridM, 256, 0, stream>>>(h, h_fp32, W1b, b1, W2b, b2, Wub, bu,
                                             m2b, ub, N_NODES);
        // e_feat[e] = erecip[e] * sum m2[v in e]
        gather_rows<<<gEdge, 256, 0, stream>>>(
            m2b, e_sd, e_vert, erecip, nullptr, e_feat, nullptr, nullptr, nullptr, N_EDGES);
        if (depth == 0) {
            // h1[v] = relu(u[v] + vrecip[v] * sum e_feat[e in v])
            gather_rows<<<gVert, 256, 0, stream>>>(
                e_feat, v_sd, v_edge, vrecip, ub, hA, nullptr, nullptr, nullptr, N_NODES);
            h = hA;
            h_fp32 = 0;
        } else {
            // final: fused head -> out = log_softmax(relu(u+agg) @ Wa^T + ba)
            gather_rows<<<gVert, 256, 0, stream>>>(
                e_feat, v_sd, v_edge, vrecip, ub, nullptr, Wa, ba, out, N_NODES);
        }
    }
}